// Round 1
// baseline (1788.400 us; speedup 1.0000x reference)
//
#include <hip/hip_runtime.h>
#include <hip/hip_bf16.h>
#include <cstdint>
#include <cstddef>

#define D_MODEL 1024
#define D_STATE 16
#define D_INNER 2048
#define DT_RANK 64
#define BATCH 2
#define SEQLEN 2048
#define BL (BATCH*SEQLEN)
#define NPROJ 96

typedef __hip_bfloat16 bf16;
using f32x4 = __attribute__((ext_vector_type(4))) float;
using s16x8 = __attribute__((ext_vector_type(8))) short;

__device__ __forceinline__ unsigned short f2bf(float f) {
  union { float f; unsigned int u; } v; v.f = f;
  unsigned int r = v.u + 0x7fffu + ((v.u >> 16) & 1u);
  return (unsigned short)(r >> 16);
}

__device__ __forceinline__ void async16(const void* g, void* l) {
  __builtin_amdgcn_global_load_lds(
      (const __attribute__((address_space(1))) void*)g,
      (__attribute__((address_space(3))) void*)l,
      16, 0, 0);
}

// ---------------------------------------------------------------------------
// fp32 -> bf16 cast (RNE), 4 elems/thread
// ---------------------------------------------------------------------------
__global__ __launch_bounds__(256) void cast_bf16_k(
    const float* __restrict__ in, bf16* __restrict__ out, int n4)
{
  const int i = blockIdx.x * 256 + threadIdx.x;
  if (i < n4) {
    const float4 v = *reinterpret_cast<const float4*>(&in[(size_t)i * 4]);
    ushort4 o;
    o.x = f2bf(v.x); o.y = f2bf(v.y); o.z = f2bf(v.z); o.w = f2bf(v.w);
    *reinterpret_cast<ushort4*>(&out[(size_t)i * 4]) = o;
  }
}

// ---------------------------------------------------------------------------
// bf16 MFMA GEMM: C[M,N] = A[M,K] * B[N,K]^T, fp32 out.
// 128x128 tile, BK=32, 4 waves (2x2), each wave 64x64 = 4x4 frags of 16x16x32.
// global_load_lds width-16 staging into linear LDS (m97 structure).
// Output split: col < N0 -> C0 (stride N0), else C1 (stride N-N0).
// Requires M%128==0, N%128==0, K%32==0; N0 a multiple of 128.
// ---------------------------------------------------------------------------
__global__ __launch_bounds__(256) void gemm_bf16_mfma(
    const bf16* __restrict__ A, const bf16* __restrict__ B,
    float* __restrict__ C0, float* __restrict__ C1,
    int M, int N, int K, int N0)
{
  __shared__ __align__(16) bf16 As[128 * 32];
  __shared__ __align__(16) bf16 Bs[128 * 32];
  const int tid  = threadIdx.x;
  const int lane = tid & 63;
  const int wave = tid >> 6;
  const int wr = wave >> 1, wc = wave & 1;
  const int bx = blockIdx.x, by = blockIdx.y;

  // staging: chunk c covers LDS bytes [c*1024, c*1024+1024), lane l -> +l*16
  // i.e. rows 16c + l/4, col elems (l%4)*8 of the [128][32] tile.
  const int srow = lane >> 2;
  const int scol = (lane & 3) * 8;
  const int c0 = wave * 2, c1 = wave * 2 + 1;
  const bf16* gA0 = A + (size_t)(by * 128 + c0 * 16 + srow) * K + scol;
  const bf16* gA1 = A + (size_t)(by * 128 + c1 * 16 + srow) * K + scol;
  const bf16* gB0 = B + (size_t)(bx * 128 + c0 * 16 + srow) * K + scol;
  const bf16* gB1 = B + (size_t)(bx * 128 + c1 * 16 + srow) * K + scol;
  bf16* lA0 = &As[c0 * 512];
  bf16* lA1 = &As[c1 * 512];
  bf16* lB0 = &Bs[c0 * 512];
  bf16* lB1 = &Bs[c1 * 512];

  f32x4 acc[4][4] = {};

  const int lrow = lane & 15;
  const int lkb  = (lane >> 4) * 8;

  for (int ks = 0; ks < K; ks += 32) {
    async16(gA0 + ks, lA0);
    async16(gA1 + ks, lA1);
    async16(gB0 + ks, lB0);
    async16(gB1 + ks, lB1);
    __syncthreads();   // drains vmcnt -> tiles visible to all waves
    s16x8 af[4], bfr[4];
#pragma unroll
    for (int i = 0; i < 4; ++i) {
      af[i]  = *reinterpret_cast<const s16x8*>(&As[(wr * 64 + i * 16 + lrow) * 32 + lkb]);
      bfr[i] = *reinterpret_cast<const s16x8*>(&Bs[(wc * 64 + i * 16 + lrow) * 32 + lkb]);
    }
#pragma unroll
    for (int i = 0; i < 4; ++i)
#pragma unroll
      for (int j = 0; j < 4; ++j)
        acc[i][j] = __builtin_amdgcn_mfma_f32_16x16x32_bf16(af[i], bfr[j], acc[i][j], 0, 0, 0);
    __syncthreads();   // all reads done before next overwrite
  }

  const int N1 = N - N0;
#pragma unroll
  for (int i = 0; i < 4; ++i) {
    const int row0 = by * 128 + wr * 64 + i * 16 + (lane >> 4) * 4;
#pragma unroll
    for (int j = 0; j < 4; ++j) {
      const int col = bx * 128 + wc * 64 + j * 16 + (lane & 15);
      const f32x4 v = acc[i][j];
      if (col < N0) {
        float* p = C0 + (size_t)row0 * N0 + col;
#pragma unroll
        for (int r = 0; r < 4; ++r) p[(size_t)r * N0] = v[r];
      } else {
        float* p = C1 + (size_t)row0 * N1 + (col - N0);
#pragma unroll
        for (int r = 0; r < 4; ++r) p[(size_t)r * N1] = v[r];
      }
    }
  }
}

// ---------------------------------------------------------------------------
// causal depthwise conv (width 4) + bias + SiLU.  x,u: (B, L, D_INNER)
// ---------------------------------------------------------------------------
__global__ __launch_bounds__(256) void conv_silu_k(
    const float* __restrict__ x, const float* __restrict__ cw,
    const float* __restrict__ cb, float* __restrict__ u)
{
  const int idx = blockIdx.x * 256 + threadIdx.x;
  const int d  = idx & (D_INNER - 1);
  const int bl = idx >> 11;
  const int l  = bl & (SEQLEN - 1);
  const float4 w = *reinterpret_cast<const float4*>(&cw[d * 4]);
  const float* xp = x + (size_t)bl * D_INNER + d;
  float acc = cb[d] + w.w * xp[0];
  if (l >= 1) acc += w.z * xp[-D_INNER];
  if (l >= 2) acc += w.y * xp[-2 * D_INNER];
  if (l >= 3) acc += w.x * xp[-3 * D_INNER];
  u[idx] = acc / (1.f + __expf(-acc));
}

// ---------------------------------------------------------------------------
// x_dbl = U (BL x D_INNER) * x_proj_w (96 x D_INNER)^T -> (BL x 96), fp32.
// ---------------------------------------------------------------------------
__global__ __launch_bounds__(256) void gemm2_xproj(
    const float* __restrict__ U, const float* __restrict__ W,
    float* __restrict__ out)
{
  __shared__ __align__(16) float uT[32][34];
  __shared__ __align__(16) float wT[32][98];
  const int t = threadIdx.x;
  const int m0 = blockIdx.x * 32;
  const int tx = t & 15;        // n-group: cols 6*tx .. 6*tx+5
  const int ty = t >> 4;        // m-pair:  rows 2*ty, 2*ty+1
  const int sr = t >> 3;        // 0..31
  const int sk = (t & 7) * 4;   // 0,4,..,28
  float acc[2][6] = {};
  for (int ks = 0; ks < D_INNER; ks += 32) {
    const float4 v = *reinterpret_cast<const float4*>(&U[(size_t)(m0 + sr) * D_INNER + ks + sk]);
    uT[sk + 0][sr] = v.x; uT[sk + 1][sr] = v.y; uT[sk + 2][sr] = v.z; uT[sk + 3][sr] = v.w;
#pragma unroll
    for (int p = 0; p < 3; ++p) {
      const int n = sr + p * 32;
      const float4 wv = *reinterpret_cast<const float4*>(&W[(size_t)n * D_INNER + ks + sk]);
      wT[sk + 0][n] = wv.x; wT[sk + 1][n] = wv.y; wT[sk + 2][n] = wv.z; wT[sk + 3][n] = wv.w;
    }
    __syncthreads();
#pragma unroll
    for (int kk = 0; kk < 32; ++kk) {
      const float2 a  = *reinterpret_cast<const float2*>(&uT[kk][ty * 2]);
      const float2 b0 = *reinterpret_cast<const float2*>(&wT[kk][tx * 6]);
      const float2 b1 = *reinterpret_cast<const float2*>(&wT[kk][tx * 6 + 2]);
      const float2 b2 = *reinterpret_cast<const float2*>(&wT[kk][tx * 6 + 4]);
      acc[0][0] += a.x * b0.x; acc[0][1] += a.x * b0.y;
      acc[0][2] += a.x * b1.x; acc[0][3] += a.x * b1.y;
      acc[0][4] += a.x * b2.x; acc[0][5] += a.x * b2.y;
      acc[1][0] += a.y * b0.x; acc[1][1] += a.y * b0.y;
      acc[1][2] += a.y * b1.x; acc[1][3] += a.y * b1.y;
      acc[1][4] += a.y * b2.x; acc[1][5] += a.y * b2.y;
    }
    __syncthreads();
  }
#pragma unroll
  for (int i = 0; i < 2; ++i)
#pragma unroll
    for (int j = 0; j < 6; ++j)
      out[(size_t)(m0 + ty * 2 + i) * NPROJ + tx * 6 + j] = acc[i][j];
}

// ---------------------------------------------------------------------------
// delta = softplus( dt_r (BL x 64) * dt_proj_w (D_INNER x 64)^T + b ), fp32.
// ---------------------------------------------------------------------------
__device__ __forceinline__ float softplusf(float x) {
  return (x > 20.f) ? x : log1pf(__expf(x));
}

__global__ __launch_bounds__(256) void gemm3_delta(
    const float* __restrict__ xdbl, const float* __restrict__ Wdt,
    const float* __restrict__ bdt, float* __restrict__ delta)
{
  __shared__ __align__(16) float aT[64][68];
  __shared__ __align__(16) float bT[64][68];
  const int t = threadIdx.x;
  const int n0 = blockIdx.x * 64;
  const int m0 = blockIdx.y * 64;
  const int sr = t >> 2;            // 0..63
  const int sk0 = (t & 3) * 16;     // 0,16,32,48
#pragma unroll
  for (int p = 0; p < 4; ++p) {
    const int kk = sk0 + p * 4;
    const float4 av = *reinterpret_cast<const float4*>(&xdbl[(size_t)(m0 + sr) * NPROJ + kk]);
    aT[kk + 0][sr] = av.x; aT[kk + 1][sr] = av.y; aT[kk + 2][sr] = av.z; aT[kk + 3][sr] = av.w;
    const float4 bv = *reinterpret_cast<const float4*>(&Wdt[(size_t)(n0 + sr) * DT_RANK + kk]);
    bT[kk + 0][sr] = bv.x; bT[kk + 1][sr] = bv.y; bT[kk + 2][sr] = bv.z; bT[kk + 3][sr] = bv.w;
  }
  __syncthreads();
  const int tx = t & 15, ty = t >> 4;
  float acc[4][4] = {};
#pragma unroll
  for (int kk = 0; kk < 64; ++kk) {
    const float4 a = *reinterpret_cast<const float4*>(&aT[kk][ty * 4]);
    const float4 b = *reinterpret_cast<const float4*>(&bT[kk][tx * 4]);
    acc[0][0] += a.x * b.x; acc[0][1] += a.x * b.y; acc[0][2] += a.x * b.z; acc[0][3] += a.x * b.w;
    acc[1][0] += a.y * b.x; acc[1][1] += a.y * b.y; acc[1][2] += a.y * b.z; acc[1][3] += a.y * b.w;
    acc[2][0] += a.z * b.x; acc[2][1] += a.z * b.y; acc[2][2] += a.z * b.z; acc[2][3] += a.z * b.w;
    acc[3][0] += a.w * b.x; acc[3][1] += a.w * b.y; acc[3][2] += a.w * b.z; acc[3][3] += a.w * b.w;
  }
#pragma unroll
  for (int i = 0; i < 4; ++i) {
    const int m = m0 + ty * 4 + i;
#pragma unroll
    for (int j = 0; j < 4; ++j) {
      const int n = n0 + tx * 4 + j;
      delta[(size_t)m * D_INNER + n] = softplusf(acc[i][j] + bdt[n]);
    }
  }
}

// ---------------------------------------------------------------------------
// selective scan: 16 lanes per (b,d) chain, one state n per lane.
// ---------------------------------------------------------------------------
__global__ __launch_bounds__(256) void scan_k(
    const float* __restrict__ delta, const float* __restrict__ u,
    const float* __restrict__ z, const float* __restrict__ xdbl,
    const float* __restrict__ A_log, const float* __restrict__ Dvec,
    bf16* __restrict__ y)
{
  const int t = threadIdx.x;
  const int chain = blockIdx.x * 16 + (t >> 4);
  const int n = t & 15;
  const int b = chain >> 11;              // D_INNER = 2048 chains per batch
  const int d = chain & (D_INNER - 1);

  const float a  = -__expf(A_log[d * D_STATE + n]);
  const float Dd = Dvec[d];
  float s = 0.f;

  const size_t base = (size_t)b * SEQLEN * D_INNER + d;
  const float* dp = delta + base;
  const float* up = u + base;
  const float* zp = z + base;
  const float* xb = xdbl + (size_t)b * SEQLEN * NPROJ + DT_RANK + n;  // B at +0, C at +16
  unsigned short* yp = reinterpret_cast<unsigned short*>(y) + base;

  float dl = dp[0], ul = up[0], Bv = xb[0], Cv = xb[D_STATE];
  for (int l = 0; l < SEQLEN; ++l) {
    const int ln = (l + 1 < SEQLEN) ? l + 1 : l;     // prefetch next step
    const size_t o = (size_t)ln * D_INNER;
    const float dln = dp[o];
    const float uln = up[o];
    const float Bvn = xb[(size_t)ln * NPROJ];
    const float Cvn = xb[(size_t)ln * NPROJ + D_STATE];

    const float dA = __expf(dl * a);
    s = s * dA + (dl * ul) * Bv;
    float p = s * Cv;
    p += __shfl_xor(p, 1, 16);
    p += __shfl_xor(p, 2, 16);
    p += __shfl_xor(p, 4, 16);
    p += __shfl_xor(p, 8, 16);
    if (n == 0) {
      const float zl = zp[(size_t)l * D_INNER];
      const float yv = (p + Dd * ul) * (zl / (1.f + __expf(-zl)));
      yp[(size_t)l * D_INNER] = f2bf(yv);
    }
    dl = dln; ul = uln; Bv = Bvn; Cv = Cvn;
  }
}

// ---------------------------------------------------------------------------
extern "C" void kernel_launch(void* const* d_in, const int* in_sizes, int n_in,
                              void* d_out, int out_size, void* d_ws, size_t ws_size,
                              hipStream_t stream)
{
  (void)in_sizes; (void)n_in; (void)out_size; (void)ws_size;
  const float* hidden    = (const float*)d_in[0];
  const float* in_projw  = (const float*)d_in[1];
  const float* conv_w    = (const float*)d_in[2];
  const float* conv_b    = (const float*)d_in[3];
  const float* x_projw   = (const float*)d_in[4];
  const float* dt_projw  = (const float*)d_in[5];
  const float* dt_projb  = (const float*)d_in[6];
  const float* A_log     = (const float*)d_in[7];
  const float* Dvec      = (const float*)d_in[8];
  const float* out_projw = (const float*)d_in[9];
  float* out = (float*)d_out;

  char* ws = (char*)d_ws;
  size_t off = 0;
  auto alloc = [&](size_t bytes) -> void* {
    void* p = ws + off;
    off += (bytes + 255) & ~(size_t)255;
    return p;
  };
  float* x    = (float*)alloc((size_t)BL * D_INNER * 4);
  float* zbuf = (float*)alloc((size_t)BL * D_INNER * 4);
  float* ubuf = (float*)alloc((size_t)BL * D_INNER * 4);
  float* dbuf = (float*)alloc((size_t)BL * D_INNER * 4);
  float* xdbl = (float*)alloc((size_t)BL * NPROJ * 4);
  bf16* hbf   = (bf16*)alloc((size_t)BL * D_MODEL * 2);
  bf16* w1bf  = (bf16*)alloc((size_t)2 * D_INNER * D_MODEL * 2);
  bf16* w4bf  = (bf16*)alloc((size_t)D_MODEL * D_INNER * 2);
  bf16* ybf   = (bf16*)x;   // alias: x is dead after conv; scan writes y here

  // casts to bf16 (RNE)
  cast_bf16_k<<<BL * D_MODEL / 4 / 256, 256, 0, stream>>>(hidden, hbf, BL * D_MODEL / 4);
  cast_bf16_k<<<2 * D_INNER * D_MODEL / 4 / 256, 256, 0, stream>>>(in_projw, w1bf, 2 * D_INNER * D_MODEL / 4);
  cast_bf16_k<<<D_MODEL * D_INNER / 4 / 256, 256, 0, stream>>>(out_projw, w4bf, D_MODEL * D_INNER / 4);

  // in_proj: xz = hidden * in_proj_w^T, split into x | z.  N = 2*D_INNER.
  gemm_bf16_mfma<<<dim3((2 * D_INNER) / 128, BL / 128), 256, 0, stream>>>(
      hbf, w1bf, x, zbuf, BL, 2 * D_INNER, D_MODEL, D_INNER);

  conv_silu_k<<<BL * D_INNER / 256, 256, 0, stream>>>(x, conv_w, conv_b, ubuf);
  gemm2_xproj<<<BL / 32, 256, 0, stream>>>(ubuf, x_projw, xdbl);
  gemm3_delta<<<dim3(D_INNER / 64, BL / 64), 256, 0, stream>>>(xdbl, dt_projw, dt_projb, dbuf);
  scan_k<<<(BATCH * D_INNER) / 16, 256, 0, stream>>>(dbuf, ubuf, zbuf, xdbl, A_log, Dvec, ybf);

  // out_proj: out = y_gated * out_proj_w^T.  N = D_MODEL, no split.
  gemm_bf16_mfma<<<dim3(D_MODEL / 128, BL / 128), 256, 0, stream>>>(
      ybf, w4bf, out, out, BL, D_MODEL, D_INNER, D_MODEL);
}

// Round 2
// 869.970 us; speedup vs baseline: 2.0557x; 2.0557x over previous
//
#include <hip/hip_runtime.h>
#include <hip/hip_bf16.h>
#include <cstdint>
#include <cstddef>

#define D_MODEL 1024
#define D_STATE 16
#define D_INNER 2048
#define DT_RANK 64
#define BATCH 2
#define SEQLEN 2048
#define BL (BATCH*SEQLEN)
#define NPROJ 96
#define NCHUNK 64
#define CLEN 32   // NCHUNK * CLEN == SEQLEN

static_assert(NCHUNK * CLEN == SEQLEN, "chunking");
static_assert((size_t)BATCH * NCHUNK * D_INNER * D_STATE == (size_t)BL * D_MODEL,
              "init aliases d_out exactly");

typedef __hip_bfloat16 bf16;
using f32x4 = __attribute__((ext_vector_type(4))) float;
using s16x8 = __attribute__((ext_vector_type(8))) short;

__device__ __forceinline__ unsigned short f2bf(float f) {
  union { float f; unsigned int u; } v; v.f = f;
  unsigned int r = v.u + 0x7fffu + ((v.u >> 16) & 1u);
  return (unsigned short)(r >> 16);
}

__device__ __forceinline__ void async16(const void* g, void* l) {
  __builtin_amdgcn_global_load_lds(
      (const __attribute__((address_space(1))) void*)g,
      (__attribute__((address_space(3))) void*)l,
      16, 0, 0);
}

// ---------------------------------------------------------------------------
// fp32 -> bf16 cast (RNE), 4 elems/thread
// ---------------------------------------------------------------------------
__global__ __launch_bounds__(256) void cast_bf16_k(
    const float* __restrict__ in, bf16* __restrict__ out, int n4)
{
  const int i = blockIdx.x * 256 + threadIdx.x;
  if (i < n4) {
    const float4 v = *reinterpret_cast<const float4*>(&in[(size_t)i * 4]);
    ushort4 o;
    o.x = f2bf(v.x); o.y = f2bf(v.y); o.z = f2bf(v.z); o.w = f2bf(v.w);
    *reinterpret_cast<ushort4*>(&out[(size_t)i * 4]) = o;
  }
}

// ---------------------------------------------------------------------------
// bf16 MFMA GEMM: C[M,N] = A[M,K] * B[N,K]^T, fp32 out (m97 structure).
// ---------------------------------------------------------------------------
__global__ __launch_bounds__(256) void gemm_bf16_mfma(
    const bf16* __restrict__ A, const bf16* __restrict__ B,
    float* __restrict__ C0, float* __restrict__ C1,
    int M, int N, int K, int N0)
{
  __shared__ __align__(16) bf16 As[128 * 32];
  __shared__ __align__(16) bf16 Bs[128 * 32];
  const int tid  = threadIdx.x;
  const int lane = tid & 63;
  const int wave = tid >> 6;
  const int wr = wave >> 1, wc = wave & 1;
  const int bx = blockIdx.x, by = blockIdx.y;

  const int srow = lane >> 2;
  const int scol = (lane & 3) * 8;
  const int c0 = wave * 2, c1 = wave * 2 + 1;
  const bf16* gA0 = A + (size_t)(by * 128 + c0 * 16 + srow) * K + scol;
  const bf16* gA1 = A + (size_t)(by * 128 + c1 * 16 + srow) * K + scol;
  const bf16* gB0 = B + (size_t)(bx * 128 + c0 * 16 + srow) * K + scol;
  const bf16* gB1 = B + (size_t)(bx * 128 + c1 * 16 + srow) * K + scol;
  bf16* lA0 = &As[c0 * 512];
  bf16* lA1 = &As[c1 * 512];
  bf16* lB0 = &Bs[c0 * 512];
  bf16* lB1 = &Bs[c1 * 512];

  f32x4 acc[4][4] = {};

  const int lrow = lane & 15;
  const int lkb  = (lane >> 4) * 8;

  for (int ks = 0; ks < K; ks += 32) {
    async16(gA0 + ks, lA0);
    async16(gA1 + ks, lA1);
    async16(gB0 + ks, lB0);
    async16(gB1 + ks, lB1);
    __syncthreads();
    s16x8 af[4], bfr[4];
#pragma unroll
    for (int i = 0; i < 4; ++i) {
      af[i]  = *reinterpret_cast<const s16x8*>(&As[(wr * 64 + i * 16 + lrow) * 32 + lkb]);
      bfr[i] = *reinterpret_cast<const s16x8*>(&Bs[(wc * 64 + i * 16 + lrow) * 32 + lkb]);
    }
#pragma unroll
    for (int i = 0; i < 4; ++i)
#pragma unroll
      for (int j = 0; j < 4; ++j)
        acc[i][j] = __builtin_amdgcn_mfma_f32_16x16x32_bf16(af[i], bfr[j], acc[i][j], 0, 0, 0);
    __syncthreads();
  }

  const int N1 = N - N0;
#pragma unroll
  for (int i = 0; i < 4; ++i) {
    const int row0 = by * 128 + wr * 64 + i * 16 + (lane >> 4) * 4;
#pragma unroll
    for (int j = 0; j < 4; ++j) {
      const int col = bx * 128 + wc * 64 + j * 16 + (lane & 15);
      const f32x4 v = acc[i][j];
      if (col < N0) {
        float* p = C0 + (size_t)row0 * N0 + col;
#pragma unroll
        for (int r = 0; r < 4; ++r) p[(size_t)r * N0] = v[r];
      } else {
        float* p = C1 + (size_t)row0 * N1 + (col - N0);
#pragma unroll
        for (int r = 0; r < 4; ++r) p[(size_t)r * N1] = v[r];
      }
    }
  }
}

// ---------------------------------------------------------------------------
// causal depthwise conv (width 4) + bias + SiLU.  x,u: (B, L, D_INNER)
// ---------------------------------------------------------------------------
__global__ __launch_bounds__(256) void conv_silu_k(
    const float* __restrict__ x, const float* __restrict__ cw,
    const float* __restrict__ cb, float* __restrict__ u)
{
  const int idx = blockIdx.x * 256 + threadIdx.x;
  const int d  = idx & (D_INNER - 1);
  const int bl = idx >> 11;
  const int l  = bl & (SEQLEN - 1);
  const float4 w = *reinterpret_cast<const float4*>(&cw[d * 4]);
  const float* xp = x + (size_t)bl * D_INNER + d;
  float acc = cb[d] + w.w * xp[0];
  if (l >= 1) acc += w.z * xp[-D_INNER];
  if (l >= 2) acc += w.y * xp[-2 * D_INNER];
  if (l >= 3) acc += w.x * xp[-3 * D_INNER];
  u[idx] = acc / (1.f + __expf(-acc));
}

// ---------------------------------------------------------------------------
// x_dbl = U (BL x D_INNER) * x_proj_w (96 x D_INNER)^T -> (BL x 96), fp32.
// ---------------------------------------------------------------------------
__global__ __launch_bounds__(256) void gemm2_xproj(
    const float* __restrict__ U, const float* __restrict__ W,
    float* __restrict__ out)
{
  __shared__ __align__(16) float uT[32][34];
  __shared__ __align__(16) float wT[32][98];
  const int t = threadIdx.x;
  const int m0 = blockIdx.x * 32;
  const int tx = t & 15;
  const int ty = t >> 4;
  const int sr = t >> 3;
  const int sk = (t & 7) * 4;
  float acc[2][6] = {};
  for (int ks = 0; ks < D_INNER; ks += 32) {
    const float4 v = *reinterpret_cast<const float4*>(&U[(size_t)(m0 + sr) * D_INNER + ks + sk]);
    uT[sk + 0][sr] = v.x; uT[sk + 1][sr] = v.y; uT[sk + 2][sr] = v.z; uT[sk + 3][sr] = v.w;
#pragma unroll
    for (int p = 0; p < 3; ++p) {
      const int n = sr + p * 32;
      const float4 wv = *reinterpret_cast<const float4*>(&W[(size_t)n * D_INNER + ks + sk]);
      wT[sk + 0][n] = wv.x; wT[sk + 1][n] = wv.y; wT[sk + 2][n] = wv.z; wT[sk + 3][n] = wv.w;
    }
    __syncthreads();
#pragma unroll
    for (int kk = 0; kk < 32; ++kk) {
      const float2 a  = *reinterpret_cast<const float2*>(&uT[kk][ty * 2]);
      const float2 b0 = *reinterpret_cast<const float2*>(&wT[kk][tx * 6]);
      const float2 b1 = *reinterpret_cast<const float2*>(&wT[kk][tx * 6 + 2]);
      const float2 b2 = *reinterpret_cast<const float2*>(&wT[kk][tx * 6 + 4]);
      acc[0][0] += a.x * b0.x; acc[0][1] += a.x * b0.y;
      acc[0][2] += a.x * b1.x; acc[0][3] += a.x * b1.y;
      acc[0][4] += a.x * b2.x; acc[0][5] += a.x * b2.y;
      acc[1][0] += a.y * b0.x; acc[1][1] += a.y * b0.y;
      acc[1][2] += a.y * b1.x; acc[1][3] += a.y * b1.y;
      acc[1][4] += a.y * b2.x; acc[1][5] += a.y * b2.y;
    }
    __syncthreads();
  }
#pragma unroll
  for (int i = 0; i < 2; ++i)
#pragma unroll
    for (int j = 0; j < 6; ++j)
      out[(size_t)(m0 + ty * 2 + i) * NPROJ + tx * 6 + j] = acc[i][j];
}

// ---------------------------------------------------------------------------
// delta = softplus( dt_r (BL x 64) * dt_proj_w (D_INNER x 64)^T + b ), fp32.
// ---------------------------------------------------------------------------
__device__ __forceinline__ float softplusf(float x) {
  return (x > 20.f) ? x : log1pf(__expf(x));
}

__global__ __launch_bounds__(256) void gemm3_delta(
    const float* __restrict__ xdbl, const float* __restrict__ Wdt,
    const float* __restrict__ bdt, float* __restrict__ delta)
{
  __shared__ __align__(16) float aT[64][68];
  __shared__ __align__(16) float bT[64][68];
  const int t = threadIdx.x;
  const int n0 = blockIdx.x * 64;
  const int m0 = blockIdx.y * 64;
  const int sr = t >> 2;
  const int sk0 = (t & 3) * 16;
#pragma unroll
  for (int p = 0; p < 4; ++p) {
    const int kk = sk0 + p * 4;
    const float4 av = *reinterpret_cast<const float4*>(&xdbl[(size_t)(m0 + sr) * NPROJ + kk]);
    aT[kk + 0][sr] = av.x; aT[kk + 1][sr] = av.y; aT[kk + 2][sr] = av.z; aT[kk + 3][sr] = av.w;
    const float4 bv = *reinterpret_cast<const float4*>(&Wdt[(size_t)(n0 + sr) * DT_RANK + kk]);
    bT[kk + 0][sr] = bv.x; bT[kk + 1][sr] = bv.y; bT[kk + 2][sr] = bv.z; bT[kk + 3][sr] = bv.w;
  }
  __syncthreads();
  const int tx = t & 15, ty = t >> 4;
  float acc[4][4] = {};
#pragma unroll
  for (int kk = 0; kk < 64; ++kk) {
    const float4 a = *reinterpret_cast<const float4*>(&aT[kk][ty * 4]);
    const float4 b = *reinterpret_cast<const float4*>(&bT[kk][tx * 4]);
    acc[0][0] += a.x * b.x; acc[0][1] += a.x * b.y; acc[0][2] += a.x * b.z; acc[0][3] += a.x * b.w;
    acc[1][0] += a.y * b.x; acc[1][1] += a.y * b.y; acc[1][2] += a.y * b.z; acc[1][3] += a.y * b.w;
    acc[2][0] += a.z * b.x; acc[2][1] += a.z * b.y; acc[2][2] += a.z * b.z; acc[2][3] += a.z * b.w;
    acc[3][0] += a.w * b.x; acc[3][1] += a.w * b.y; acc[3][2] += a.w * b.z; acc[3][3] += a.w * b.w;
  }
#pragma unroll
  for (int i = 0; i < 4; ++i) {
    const int m = m0 + ty * 4 + i;
#pragma unroll
    for (int j = 0; j < 4; ++j) {
      const int n = n0 + tx * 4 + j;
      delta[(size_t)m * D_INNER + n] = softplusf(acc[i][j] + bdt[n]);
    }
  }
}

// ---------------------------------------------------------------------------
// Chunked selective scan, 3 phases.  Group = (b, chunk, d), 16 lanes = states.
// gid = (b*NCHUNK + c)*D_INNER + d  (consecutive gid -> consecutive d).
// P,S,init layout: ((b*NCHUNK + c)*D_INNER + d)*16 + n   (block writes 1KB contig)
// ---------------------------------------------------------------------------
__global__ __launch_bounds__(256) void scan_p1(
    const float* __restrict__ delta, const float* __restrict__ u,
    const float* __restrict__ xdbl, const float* __restrict__ A_log,
    float* __restrict__ P, float* __restrict__ S)
{
  const int t = threadIdx.x;
  const int gid = blockIdx.x * 16 + (t >> 4);
  const int n = t & 15;
  const int d = gid & (D_INNER - 1);
  const int c = (gid >> 11) & (NCHUNK - 1);
  const int b = gid >> 17;

  const float a = -__expf(A_log[d * D_STATE + n]);
  float s = 0.f, Pp = 1.f;

  const size_t rbase = (size_t)(b * SEQLEN + c * CLEN);
  const float* dp = delta + rbase * D_INNER + d;
  const float* up = u + rbase * D_INNER + d;
  const float* xb = xdbl + rbase * NPROJ + DT_RANK + n;

#pragma unroll 8
  for (int l = 0; l < CLEN; ++l) {
    const float dl = dp[(size_t)l * D_INNER];
    const float ul = up[(size_t)l * D_INNER];
    const float Bv = xb[(size_t)l * NPROJ];
    const float dA = __expf(dl * a);
    s = s * dA + (dl * ul) * Bv;
    Pp *= dA;
  }
  const size_t o = (size_t)gid * 16 + n;
  P[o] = Pp;
  S[o] = s;
}

__global__ __launch_bounds__(256) void scan_p2(
    const float* __restrict__ P, const float* __restrict__ S,
    float* __restrict__ init)
{
  // lane = (b, d, n): gid = b*(D_INNER*16) + d*16 + n
  const int gid = blockIdx.x * 256 + threadIdx.x;
  const int b = gid >> 15;
  const int dn = gid & (D_INNER * 16 - 1);  // d*16 + n

  float carry = 0.f;
#pragma unroll 8
  for (int c = 0; c < NCHUNK; ++c) {
    const size_t o = ((size_t)(b * NCHUNK + c) * D_INNER) * 16 + dn;
    init[o] = carry;
    carry = carry * P[o] + S[o];
  }
}

__global__ __launch_bounds__(256) void scan_p3(
    const float* __restrict__ delta, const float* __restrict__ u,
    const float* __restrict__ z, const float* __restrict__ xdbl,
    const float* __restrict__ A_log, const float* __restrict__ Dvec,
    const float* __restrict__ init, bf16* __restrict__ y)
{
  const int t = threadIdx.x;
  const int gid = blockIdx.x * 16 + (t >> 4);
  const int n = t & 15;
  const int d = gid & (D_INNER - 1);
  const int c = (gid >> 11) & (NCHUNK - 1);
  const int b = gid >> 17;

  const float a  = -__expf(A_log[d * D_STATE + n]);
  const float Dd = Dvec[d];
  float s = init[(size_t)gid * 16 + n];

  const size_t rbase = (size_t)(b * SEQLEN + c * CLEN);
  const float* dp = delta + rbase * D_INNER + d;
  const float* up = u + rbase * D_INNER + d;
  const float* zp = z + rbase * D_INNER + d;
  const float* xb = xdbl + rbase * NPROJ + DT_RANK + n;
  unsigned short* yp = reinterpret_cast<unsigned short*>(y) + rbase * D_INNER + d;

#pragma unroll 4
  for (int l = 0; l < CLEN; ++l) {
    const float dl = dp[(size_t)l * D_INNER];
    const float ul = up[(size_t)l * D_INNER];
    const float Bv = xb[(size_t)l * NPROJ];
    const float Cv = xb[(size_t)l * NPROJ + D_STATE];
    const float dA = __expf(dl * a);
    s = s * dA + (dl * ul) * Bv;
    float p = s * Cv;
    p += __shfl_xor(p, 1, 16);
    p += __shfl_xor(p, 2, 16);
    p += __shfl_xor(p, 4, 16);
    p += __shfl_xor(p, 8, 16);
    if (n == 0) {
      const float zl = zp[(size_t)l * D_INNER];
      const float yv = (p + Dd * ul) * (zl / (1.f + __expf(-zl)));
      yp[(size_t)l * D_INNER] = f2bf(yv);
    }
  }
}

// ---------------------------------------------------------------------------
extern "C" void kernel_launch(void* const* d_in, const int* in_sizes, int n_in,
                              void* d_out, int out_size, void* d_ws, size_t ws_size,
                              hipStream_t stream)
{
  (void)in_sizes; (void)n_in; (void)out_size; (void)ws_size;
  const float* hidden    = (const float*)d_in[0];
  const float* in_projw  = (const float*)d_in[1];
  const float* conv_w    = (const float*)d_in[2];
  const float* conv_b    = (const float*)d_in[3];
  const float* x_projw   = (const float*)d_in[4];
  const float* dt_projw  = (const float*)d_in[5];
  const float* dt_projb  = (const float*)d_in[6];
  const float* A_log     = (const float*)d_in[7];
  const float* Dvec      = (const float*)d_in[8];
  const float* out_projw = (const float*)d_in[9];
  float* out = (float*)d_out;

  char* ws = (char*)d_ws;
  size_t off = 0;
  auto alloc = [&](size_t bytes) -> void* {
    void* p = ws + off;
    off += (bytes + 255) & ~(size_t)255;
    return p;
  };
  float* x    = (float*)alloc((size_t)BL * D_INNER * 4);
  float* zbuf = (float*)alloc((size_t)BL * D_INNER * 4);
  float* ubuf = (float*)alloc((size_t)BL * D_INNER * 4);
  float* dbuf = (float*)alloc((size_t)BL * D_INNER * 4);
  float* xdbl = (float*)alloc((size_t)BL * NPROJ * 4);
  bf16* hbf   = (bf16*)alloc((size_t)BL * D_MODEL * 2);
  bf16* w1bf  = (bf16*)alloc((size_t)2 * D_INNER * D_MODEL * 2);
  bf16* w4bf  = (bf16*)alloc((size_t)D_MODEL * D_INNER * 2);
  float* Sbuf = (float*)alloc((size_t)BATCH * NCHUNK * D_INNER * D_STATE * 4);
  bf16* ybf   = (bf16*)x;      // x dead after conv; scan_p3 writes y here
  float* Pbuf = (float*)hbf;   // hbf+w1bf dead after GEMM1; 8.39+8.39 = 16.78 MB = |P|
  float* init = out;           // d_out dead until final GEMM overwrites it

  // casts to bf16 (RNE)
  cast_bf16_k<<<BL * D_MODEL / 4 / 256, 256, 0, stream>>>(hidden, hbf, BL * D_MODEL / 4);
  cast_bf16_k<<<2 * D_INNER * D_MODEL / 4 / 256, 256, 0, stream>>>(in_projw, w1bf, 2 * D_INNER * D_MODEL / 4);
  cast_bf16_k<<<D_MODEL * D_INNER / 4 / 256, 256, 0, stream>>>(out_projw, w4bf, D_MODEL * D_INNER / 4);

  // in_proj: xz = hidden * in_proj_w^T -> x | z
  gemm_bf16_mfma<<<dim3((2 * D_INNER) / 128, BL / 128), 256, 0, stream>>>(
      hbf, w1bf, x, zbuf, BL, 2 * D_INNER, D_MODEL, D_INNER);

  conv_silu_k<<<BL * D_INNER / 256, 256, 0, stream>>>(x, conv_w, conv_b, ubuf);
  gemm2_xproj<<<BL / 32, 256, 0, stream>>>(ubuf, x_projw, xdbl);
  gemm3_delta<<<dim3(D_INNER / 64, BL / 64), 256, 0, stream>>>(xdbl, dt_projw, dt_projb, dbuf);

  // chunked selective scan (hbf/w1bf dead from here -> Pbuf alias valid)
  const int ngroups = BATCH * NCHUNK * D_INNER;          // 262144
  scan_p1<<<ngroups / 16, 256, 0, stream>>>(dbuf, ubuf, xdbl, A_log, Pbuf, Sbuf);
  scan_p2<<<(BATCH * D_INNER * D_STATE) / 256, 256, 0, stream>>>(Pbuf, Sbuf, init);
  scan_p3<<<ngroups / 16, 256, 0, stream>>>(dbuf, ubuf, zbuf, xdbl, A_log, Dvec, init, ybf);

  // out_proj: out = y_gated * out_proj_w^T
  gemm_bf16_mfma<<<dim3(D_MODEL / 128, BL / 128), 256, 0, stream>>>(
      ybf, w4bf, out, out, BL, D_MODEL, D_INNER, D_MODEL);
}

// Round 3
// 593.004 us; speedup vs baseline: 3.0158x; 1.4671x over previous
//
#include <hip/hip_runtime.h>
#include <hip/hip_bf16.h>
#include <cstdint>
#include <cstddef>

#define D_MODEL 1024
#define D_STATE 16
#define D_INNER 2048
#define DT_RANK 64
#define BATCH 2
#define SEQLEN 2048
#define BL (BATCH*SEQLEN)
#define NPROJ 96
#define NCHUNK 64
#define CLEN 32   // NCHUNK * CLEN == SEQLEN

static_assert(NCHUNK * CLEN == SEQLEN, "chunking");
static_assert((size_t)BATCH * NCHUNK * D_INNER * D_STATE == (size_t)BL * D_MODEL,
              "init aliases d_out exactly");

typedef __hip_bfloat16 bf16;
using f32x4 = __attribute__((ext_vector_type(4))) float;
using s16x8 = __attribute__((ext_vector_type(8))) short;

__device__ __forceinline__ unsigned short f2bf(float f) {
  union { float f; unsigned int u; } v; v.f = f;
  unsigned int r = v.u + 0x7fffu + ((v.u >> 16) & 1u);
  return (unsigned short)(r >> 16);
}

__device__ __forceinline__ void async16(const void* g, void* l) {
  __builtin_amdgcn_global_load_lds(
      (const __attribute__((address_space(1))) void*)g,
      (__attribute__((address_space(3))) void*)l,
      16, 0, 0);
}

// ---------------------------------------------------------------------------
// fp32 -> bf16 cast (RNE), 4 elems/thread
// ---------------------------------------------------------------------------
__global__ __launch_bounds__(256) void cast_bf16_k(
    const float* __restrict__ in, bf16* __restrict__ out, int n4)
{
  const int i = blockIdx.x * 256 + threadIdx.x;
  if (i < n4) {
    const float4 v = *reinterpret_cast<const float4*>(&in[(size_t)i * 4]);
    ushort4 o;
    o.x = f2bf(v.x); o.y = f2bf(v.y); o.z = f2bf(v.z); o.w = f2bf(v.w);
    *reinterpret_cast<ushort4*>(&out[(size_t)i * 4]) = o;
  }
}

// ---------------------------------------------------------------------------
// bf16 MFMA GEMM: C[M,N] = A[M,K] * B[N,K]^T, fp32 out (m97 structure).
// ---------------------------------------------------------------------------
__global__ __launch_bounds__(256) void gemm_bf16_mfma(
    const bf16* __restrict__ A, const bf16* __restrict__ B,
    float* __restrict__ C0, float* __restrict__ C1,
    int M, int N, int K, int N0)
{
  __shared__ __align__(16) bf16 As[128 * 32];
  __shared__ __align__(16) bf16 Bs[128 * 32];
  const int tid  = threadIdx.x;
  const int lane = tid & 63;
  const int wave = tid >> 6;
  const int wr = wave >> 1, wc = wave & 1;
  const int bx = blockIdx.x, by = blockIdx.y;

  const int srow = lane >> 2;
  const int scol = (lane & 3) * 8;
  const int c0 = wave * 2, c1 = wave * 2 + 1;
  const bf16* gA0 = A + (size_t)(by * 128 + c0 * 16 + srow) * K + scol;
  const bf16* gA1 = A + (size_t)(by * 128 + c1 * 16 + srow) * K + scol;
  const bf16* gB0 = B + (size_t)(bx * 128 + c0 * 16 + srow) * K + scol;
  const bf16* gB1 = B + (size_t)(bx * 128 + c1 * 16 + srow) * K + scol;
  bf16* lA0 = &As[c0 * 512];
  bf16* lA1 = &As[c1 * 512];
  bf16* lB0 = &Bs[c0 * 512];
  bf16* lB1 = &Bs[c1 * 512];

  f32x4 acc[4][4] = {};

  const int lrow = lane & 15;
  const int lkb  = (lane >> 4) * 8;

  for (int ks = 0; ks < K; ks += 32) {
    async16(gA0 + ks, lA0);
    async16(gA1 + ks, lA1);
    async16(gB0 + ks, lB0);
    async16(gB1 + ks, lB1);
    __syncthreads();
    s16x8 af[4], bfr[4];
#pragma unroll
    for (int i = 0; i < 4; ++i) {
      af[i]  = *reinterpret_cast<const s16x8*>(&As[(wr * 64 + i * 16 + lrow) * 32 + lkb]);
      bfr[i] = *reinterpret_cast<const s16x8*>(&Bs[(wc * 64 + i * 16 + lrow) * 32 + lkb]);
    }
#pragma unroll
    for (int i = 0; i < 4; ++i)
#pragma unroll
      for (int j = 0; j < 4; ++j)
        acc[i][j] = __builtin_amdgcn_mfma_f32_16x16x32_bf16(af[i], bfr[j], acc[i][j], 0, 0, 0);
    __syncthreads();
  }

  const int N1 = N - N0;
#pragma unroll
  for (int i = 0; i < 4; ++i) {
    const int row0 = by * 128 + wr * 64 + i * 16 + (lane >> 4) * 4;
#pragma unroll
    for (int j = 0; j < 4; ++j) {
      const int col = bx * 128 + wc * 64 + j * 16 + (lane & 15);
      const f32x4 v = acc[i][j];
      if (col < N0) {
        float* p = C0 + (size_t)row0 * N0 + col;
#pragma unroll
        for (int r = 0; r < 4; ++r) p[(size_t)r * N0] = v[r];
      } else {
        float* p = C1 + (size_t)row0 * N1 + (col - N0);
#pragma unroll
        for (int r = 0; r < 4; ++r) p[(size_t)r * N1] = v[r];
      }
    }
  }
}

// ---------------------------------------------------------------------------
// causal depthwise conv (width 4) + bias + SiLU.  x,u: (B, L, D_INNER)
// ---------------------------------------------------------------------------
__global__ __launch_bounds__(256) void conv_silu_k(
    const float* __restrict__ x, const float* __restrict__ cw,
    const float* __restrict__ cb, float* __restrict__ u)
{
  const int idx = blockIdx.x * 256 + threadIdx.x;
  const int d  = idx & (D_INNER - 1);
  const int bl = idx >> 11;
  const int l  = bl & (SEQLEN - 1);
  const float4 w = *reinterpret_cast<const float4*>(&cw[d * 4]);
  const float* xp = x + (size_t)bl * D_INNER + d;
  float acc = cb[d] + w.w * xp[0];
  if (l >= 1) acc += w.z * xp[-D_INNER];
  if (l >= 2) acc += w.y * xp[-2 * D_INNER];
  if (l >= 3) acc += w.x * xp[-3 * D_INNER];
  u[idx] = acc / (1.f + __expf(-acc));
}

// ---------------------------------------------------------------------------
// x_dbl = U (BL x D_INNER) * x_proj_w (96 x D_INNER)^T -> (BL x 96), fp32.
// ---------------------------------------------------------------------------
__global__ __launch_bounds__(256) void gemm2_xproj(
    const float* __restrict__ U, const float* __restrict__ W,
    float* __restrict__ out)
{
  __shared__ __align__(16) float uT[32][34];
  __shared__ __align__(16) float wT[32][98];
  const int t = threadIdx.x;
  const int m0 = blockIdx.x * 32;
  const int tx = t & 15;
  const int ty = t >> 4;
  const int sr = t >> 3;
  const int sk = (t & 7) * 4;
  float acc[2][6] = {};
  for (int ks = 0; ks < D_INNER; ks += 32) {
    const float4 v = *reinterpret_cast<const float4*>(&U[(size_t)(m0 + sr) * D_INNER + ks + sk]);
    uT[sk + 0][sr] = v.x; uT[sk + 1][sr] = v.y; uT[sk + 2][sr] = v.z; uT[sk + 3][sr] = v.w;
#pragma unroll
    for (int p = 0; p < 3; ++p) {
      const int n = sr + p * 32;
      const float4 wv = *reinterpret_cast<const float4*>(&W[(size_t)n * D_INNER + ks + sk]);
      wT[sk + 0][n] = wv.x; wT[sk + 1][n] = wv.y; wT[sk + 2][n] = wv.z; wT[sk + 3][n] = wv.w;
    }
    __syncthreads();
#pragma unroll
    for (int kk = 0; kk < 32; ++kk) {
      const float2 a  = *reinterpret_cast<const float2*>(&uT[kk][ty * 2]);
      const float2 b0 = *reinterpret_cast<const float2*>(&wT[kk][tx * 6]);
      const float2 b1 = *reinterpret_cast<const float2*>(&wT[kk][tx * 6 + 2]);
      const float2 b2 = *reinterpret_cast<const float2*>(&wT[kk][tx * 6 + 4]);
      acc[0][0] += a.x * b0.x; acc[0][1] += a.x * b0.y;
      acc[0][2] += a.x * b1.x; acc[0][3] += a.x * b1.y;
      acc[0][4] += a.x * b2.x; acc[0][5] += a.x * b2.y;
      acc[1][0] += a.y * b0.x; acc[1][1] += a.y * b0.y;
      acc[1][2] += a.y * b1.x; acc[1][3] += a.y * b1.y;
      acc[1][4] += a.y * b2.x; acc[1][5] += a.y * b2.y;
    }
    __syncthreads();
  }
#pragma unroll
  for (int i = 0; i < 2; ++i)
#pragma unroll
    for (int j = 0; j < 6; ++j)
      out[(size_t)(m0 + ty * 2 + i) * NPROJ + tx * 6 + j] = acc[i][j];
}

// ---------------------------------------------------------------------------
// delta = softplus( xdbl[:, :64] (BL x 64) * dt_proj_w (D_INNER x 64)^T + b )
// Rewritten r3: block 256 thr, tile 128m x 64n, K=64 staged once.
// Thread: 8m x 4n f32x4 accumulators; float4 stores (write-amp fix);
// #pragma unroll 4 caps VGPR (r2 failure: full-unroll hoisting -> 256 VGPR,
// 1 wave/SIMD, 6x write amplification via scalar strided stores).
// ---------------------------------------------------------------------------
__device__ __forceinline__ float softplusf(float x) {
  return (x > 20.f) ? x : log1pf(__expf(x));
}

__global__ __launch_bounds__(256) void gemm3_delta(
    const float* __restrict__ xdbl, const float* __restrict__ Wdt,
    const float* __restrict__ bdt, float* __restrict__ delta)
{
  __shared__ __align__(16) float aT[64][132];  // [k][m], pad 132 (conflict-free)
  __shared__ __align__(16) float bT[64][68];   // [k][n]
  const int t = threadIdx.x;
  const int n0 = blockIdx.x * 64;
  const int m0 = blockIdx.y * 128;

  // stage A: rows m0..m0+127, k 0..63 (xdbl row stride NPROJ, dt_r = cols 0..63)
  {
    const int r  = t & 127;
    const int k0 = (t >> 7) * 32;     // 0 or 32
    const float* src = xdbl + (size_t)(m0 + r) * NPROJ + k0;
#pragma unroll
    for (int p = 0; p < 8; ++p) {
      const float4 v = *reinterpret_cast<const float4*>(&src[p * 4]);
      aT[k0 + p * 4 + 0][r] = v.x;
      aT[k0 + p * 4 + 1][r] = v.y;
      aT[k0 + p * 4 + 2][r] = v.z;
      aT[k0 + p * 4 + 3][r] = v.w;
    }
  }
  // stage B: rows n0..n0+63, k 0..63 (Wdt row stride DT_RANK=64)
  {
    const int r  = t & 63;
    const int k0 = (t >> 6) * 16;     // 0,16,32,48
    const float* src = Wdt + (size_t)(n0 + r) * DT_RANK + k0;
#pragma unroll
    for (int p = 0; p < 4; ++p) {
      const float4 v = *reinterpret_cast<const float4*>(&src[p * 4]);
      bT[k0 + p * 4 + 0][r] = v.x;
      bT[k0 + p * 4 + 1][r] = v.y;
      bT[k0 + p * 4 + 2][r] = v.z;
      bT[k0 + p * 4 + 3][r] = v.w;
    }
  }
  __syncthreads();

  const int tx = t & 15;   // n quad: cols n0 + tx*4 .. +3
  const int ty = t >> 4;   // m octet: rows m0 + ty*8 .. +7
  f32x4 acc[8] = {};
#pragma unroll 4
  for (int kk = 0; kk < 64; ++kk) {
    const f32x4 a0 = *reinterpret_cast<const f32x4*>(&aT[kk][ty * 8]);
    const f32x4 a1 = *reinterpret_cast<const f32x4*>(&aT[kk][ty * 8 + 4]);
    const f32x4 b  = *reinterpret_cast<const f32x4*>(&bT[kk][tx * 4]);
    acc[0] += a0.x * b;  acc[1] += a0.y * b;
    acc[2] += a0.z * b;  acc[3] += a0.w * b;
    acc[4] += a1.x * b;  acc[5] += a1.y * b;
    acc[6] += a1.z * b;  acc[7] += a1.w * b;
  }

  const float4 bias = *reinterpret_cast<const float4*>(&bdt[n0 + tx * 4]);
#pragma unroll
  for (int i = 0; i < 8; ++i) {
    const int m = m0 + ty * 8 + i;
    float4 o;
    o.x = softplusf(acc[i].x + bias.x);
    o.y = softplusf(acc[i].y + bias.y);
    o.z = softplusf(acc[i].z + bias.z);
    o.w = softplusf(acc[i].w + bias.w);
    *reinterpret_cast<float4*>(&delta[(size_t)m * D_INNER + n0 + tx * 4]) = o;
  }
}

// ---------------------------------------------------------------------------
// Chunked selective scan, 3 phases.  Group = (b, chunk, d), 16 lanes = states.
// ---------------------------------------------------------------------------
__global__ __launch_bounds__(256) void scan_p1(
    const float* __restrict__ delta, const float* __restrict__ u,
    const float* __restrict__ xdbl, const float* __restrict__ A_log,
    float* __restrict__ P, float* __restrict__ S)
{
  const int t = threadIdx.x;
  const int gid = blockIdx.x * 16 + (t >> 4);
  const int n = t & 15;
  const int d = gid & (D_INNER - 1);
  const int c = (gid >> 11) & (NCHUNK - 1);
  const int b = gid >> 17;

  const float a = -__expf(A_log[d * D_STATE + n]);
  float s = 0.f, Pp = 1.f;

  const size_t rbase = (size_t)(b * SEQLEN + c * CLEN);
  const float* dp = delta + rbase * D_INNER + d;
  const float* up = u + rbase * D_INNER + d;
  const float* xb = xdbl + rbase * NPROJ + DT_RANK + n;

#pragma unroll 8
  for (int l = 0; l < CLEN; ++l) {
    const float dl = dp[(size_t)l * D_INNER];
    const float ul = up[(size_t)l * D_INNER];
    const float Bv = xb[(size_t)l * NPROJ];
    const float dA = __expf(dl * a);
    s = s * dA + (dl * ul) * Bv;
    Pp *= dA;
  }
  const size_t o = (size_t)gid * 16 + n;
  P[o] = Pp;
  S[o] = s;
}

__global__ __launch_bounds__(256) void scan_p2(
    const float* __restrict__ P, const float* __restrict__ S,
    float* __restrict__ init)
{
  const int gid = blockIdx.x * 256 + threadIdx.x;
  const int b = gid >> 15;
  const int dn = gid & (D_INNER * 16 - 1);

  float carry = 0.f;
#pragma unroll 8
  for (int c = 0; c < NCHUNK; ++c) {
    const size_t o = ((size_t)(b * NCHUNK + c) * D_INNER) * 16 + dn;
    init[o] = carry;
    carry = carry * P[o] + S[o];
  }
}

__global__ __launch_bounds__(256) void scan_p3(
    const float* __restrict__ delta, const float* __restrict__ u,
    const float* __restrict__ z, const float* __restrict__ xdbl,
    const float* __restrict__ A_log, const float* __restrict__ Dvec,
    const float* __restrict__ init, bf16* __restrict__ y)
{
  const int t = threadIdx.x;
  const int gid = blockIdx.x * 16 + (t >> 4);
  const int n = t & 15;
  const int d = gid & (D_INNER - 1);
  const int c = (gid >> 11) & (NCHUNK - 1);
  const int b = gid >> 17;

  const float a  = -__expf(A_log[d * D_STATE + n]);
  const float Dd = Dvec[d];
  float s = init[(size_t)gid * 16 + n];

  const size_t rbase = (size_t)(b * SEQLEN + c * CLEN);
  const float* dp = delta + rbase * D_INNER + d;
  const float* up = u + rbase * D_INNER + d;
  const float* zp = z + rbase * D_INNER + d;
  const float* xb = xdbl + rbase * NPROJ + DT_RANK + n;
  unsigned short* yp = reinterpret_cast<unsigned short*>(y) + rbase * D_INNER + d;

#pragma unroll 4
  for (int l = 0; l < CLEN; ++l) {
    const float dl = dp[(size_t)l * D_INNER];
    const float ul = up[(size_t)l * D_INNER];
    const float Bv = xb[(size_t)l * NPROJ];
    const float Cv = xb[(size_t)l * NPROJ + D_STATE];
    const float dA = __expf(dl * a);
    s = s * dA + (dl * ul) * Bv;
    float p = s * Cv;
    p += __shfl_xor(p, 1, 16);
    p += __shfl_xor(p, 2, 16);
    p += __shfl_xor(p, 4, 16);
    p += __shfl_xor(p, 8, 16);
    if (n == 0) {
      const float zl = zp[(size_t)l * D_INNER];
      const float yv = (p + Dd * ul) * (zl / (1.f + __expf(-zl)));
      yp[(size_t)l * D_INNER] = f2bf(yv);
    }
  }
}

// ---------------------------------------------------------------------------
extern "C" void kernel_launch(void* const* d_in, const int* in_sizes, int n_in,
                              void* d_out, int out_size, void* d_ws, size_t ws_size,
                              hipStream_t stream)
{
  (void)in_sizes; (void)n_in; (void)out_size; (void)ws_size;
  const float* hidden    = (const float*)d_in[0];
  const float* in_projw  = (const float*)d_in[1];
  const float* conv_w    = (const float*)d_in[2];
  const float* conv_b    = (const float*)d_in[3];
  const float* x_projw   = (const float*)d_in[4];
  const float* dt_projw  = (const float*)d_in[5];
  const float* dt_projb  = (const float*)d_in[6];
  const float* A_log     = (const float*)d_in[7];
  const float* Dvec      = (const float*)d_in[8];
  const float* out_projw = (const float*)d_in[9];
  float* out = (float*)d_out;

  char* ws = (char*)d_ws;
  size_t off = 0;
  auto alloc = [&](size_t bytes) -> void* {
    void* p = ws + off;
    off += (bytes + 255) & ~(size_t)255;
    return p;
  };
  float* x    = (float*)alloc((size_t)BL * D_INNER * 4);
  float* zbuf = (float*)alloc((size_t)BL * D_INNER * 4);
  float* ubuf = (float*)alloc((size_t)BL * D_INNER * 4);
  float* dbuf = (float*)alloc((size_t)BL * D_INNER * 4);
  float* xdbl = (float*)alloc((size_t)BL * NPROJ * 4);
  bf16* hbf   = (bf16*)alloc((size_t)BL * D_MODEL * 2);
  bf16* w1bf  = (bf16*)alloc((size_t)2 * D_INNER * D_MODEL * 2);
  bf16* w4bf  = (bf16*)alloc((size_t)D_MODEL * D_INNER * 2);
  float* Sbuf = (float*)alloc((size_t)BATCH * NCHUNK * D_INNER * D_STATE * 4);
  bf16* ybf   = (bf16*)x;      // x dead after conv; scan_p3 writes y here
  float* Pbuf = (float*)hbf;   // hbf+w1bf dead after GEMM1; 16.78 MB = |P|
  float* init = out;           // d_out dead until final GEMM overwrites it

  // casts to bf16 (RNE)
  cast_bf16_k<<<BL * D_MODEL / 4 / 256, 256, 0, stream>>>(hidden, hbf, BL * D_MODEL / 4);
  cast_bf16_k<<<2 * D_INNER * D_MODEL / 4 / 256, 256, 0, stream>>>(in_projw, w1bf, 2 * D_INNER * D_MODEL / 4);
  cast_bf16_k<<<D_MODEL * D_INNER / 4 / 256, 256, 0, stream>>>(out_projw, w4bf, D_MODEL * D_INNER / 4);

  // in_proj: xz = hidden * in_proj_w^T -> x | z
  gemm_bf16_mfma<<<dim3((2 * D_INNER) / 128, BL / 128), 256, 0, stream>>>(
      hbf, w1bf, x, zbuf, BL, 2 * D_INNER, D_MODEL, D_INNER);

  conv_silu_k<<<BL * D_INNER / 256, 256, 0, stream>>>(x, conv_w, conv_b, ubuf);
  gemm2_xproj<<<BL / 32, 256, 0, stream>>>(ubuf, x_projw, xdbl);
  gemm3_delta<<<dim3(D_INNER / 64, BL / 128), 256, 0, stream>>>(xdbl, dt_projw, dt_projb, dbuf);

  // chunked selective scan (hbf/w1bf dead from here -> Pbuf alias valid)
  const int ngroups = BATCH * NCHUNK * D_INNER;          // 262144
  scan_p1<<<ngroups / 16, 256, 0, stream>>>(dbuf, ubuf, xdbl, A_log, Pbuf, Sbuf);
  scan_p2<<<(BATCH * D_INNER * D_STATE) / 256, 256, 0, stream>>>(Pbuf, Sbuf, init);
  scan_p3<<<ngroups / 16, 256, 0, stream>>>(dbuf, ubuf, zbuf, xdbl, A_log, Dvec, init, ybf);

  // out_proj: out = y_gated * out_proj_w^T
  gemm_bf16_mfma<<<dim3(D_MODEL / 128, BL / 128), 256, 0, stream>>>(
      ybf, w4bf, out, out, BL, D_MODEL, D_INNER, D_MODEL);
}

// Round 4
// 405.149 us; speedup vs baseline: 4.4142x; 1.4637x over previous
//
#include <hip/hip_runtime.h>
#include <hip/hip_bf16.h>
#include <cstdint>
#include <cstddef>

#define D_MODEL 1024
#define D_STATE 16
#define D_INNER 2048
#define DT_RANK 64
#define BATCH 2
#define SEQLEN 2048
#define BL (BATCH*SEQLEN)
#define NPROJ 96
#define NCHUNK 64
#define CLEN 32   // NCHUNK * CLEN == SEQLEN

static_assert(NCHUNK * CLEN == SEQLEN, "chunking");
static_assert((size_t)D_STATE * BATCH * NCHUNK * D_INNER == (size_t)BL * D_MODEL,
              "init aliases d_out exactly");

typedef __hip_bfloat16 bf16;
using f32x4 = __attribute__((ext_vector_type(4))) float;
using s16x8 = __attribute__((ext_vector_type(8))) short;

__device__ __forceinline__ unsigned short f2bf(float f) {
  union { float f; unsigned int u; } v; v.f = f;
  unsigned int r = v.u + 0x7fffu + ((v.u >> 16) & 1u);
  return (unsigned short)(r >> 16);
}

__device__ __forceinline__ void async16(const void* g, void* l) {
  __builtin_amdgcn_global_load_lds(
      (const __attribute__((address_space(1))) void*)g,
      (__attribute__((address_space(3))) void*)l,
      16, 0, 0);
}

// ---------------------------------------------------------------------------
// fp32 -> bf16 cast (RNE), 4 elems/thread
// ---------------------------------------------------------------------------
__global__ __launch_bounds__(256) void cast_bf16_k(
    const float* __restrict__ in, bf16* __restrict__ out, int n4)
{
  const int i = blockIdx.x * 256 + threadIdx.x;
  if (i < n4) {
    const float4 v = *reinterpret_cast<const float4*>(&in[(size_t)i * 4]);
    ushort4 o;
    o.x = f2bf(v.x); o.y = f2bf(v.y); o.z = f2bf(v.z); o.w = f2bf(v.w);
    *reinterpret_cast<ushort4*>(&out[(size_t)i * 4]) = o;
  }
}

// ---------------------------------------------------------------------------
// bf16 MFMA GEMM: C[M,N] = A[M,K] * B[N,K]^T, fp32 out (m97 structure).
// ---------------------------------------------------------------------------
__global__ __launch_bounds__(256) void gemm_bf16_mfma(
    const bf16* __restrict__ A, const bf16* __restrict__ B,
    float* __restrict__ C0, float* __restrict__ C1,
    int M, int N, int K, int N0)
{
  __shared__ __align__(16) bf16 As[128 * 32];
  __shared__ __align__(16) bf16 Bs[128 * 32];
  const int tid  = threadIdx.x;
  const int lane = tid & 63;
  const int wave = tid >> 6;
  const int wr = wave >> 1, wc = wave & 1;
  const int bx = blockIdx.x, by = blockIdx.y;

  const int srow = lane >> 2;
  const int scol = (lane & 3) * 8;
  const int c0 = wave * 2, c1 = wave * 2 + 1;
  const bf16* gA0 = A + (size_t)(by * 128 + c0 * 16 + srow) * K + scol;
  const bf16* gA1 = A + (size_t)(by * 128 + c1 * 16 + srow) * K + scol;
  const bf16* gB0 = B + (size_t)(bx * 128 + c0 * 16 + srow) * K + scol;
  const bf16* gB1 = B + (size_t)(bx * 128 + c1 * 16 + srow) * K + scol;
  bf16* lA0 = &As[c0 * 512];
  bf16* lA1 = &As[c1 * 512];
  bf16* lB0 = &Bs[c0 * 512];
  bf16* lB1 = &Bs[c1 * 512];

  f32x4 acc[4][4] = {};

  const int lrow = lane & 15;
  const int lkb  = (lane >> 4) * 8;

  for (int ks = 0; ks < K; ks += 32) {
    async16(gA0 + ks, lA0);
    async16(gA1 + ks, lA1);
    async16(gB0 + ks, lB0);
    async16(gB1 + ks, lB1);
    __syncthreads();
    s16x8 af[4], bfr[4];
#pragma unroll
    for (int i = 0; i < 4; ++i) {
      af[i]  = *reinterpret_cast<const s16x8*>(&As[(wr * 64 + i * 16 + lrow) * 32 + lkb]);
      bfr[i] = *reinterpret_cast<const s16x8*>(&Bs[(wc * 64 + i * 16 + lrow) * 32 + lkb]);
    }
#pragma unroll
    for (int i = 0; i < 4; ++i)
#pragma unroll
      for (int j = 0; j < 4; ++j)
        acc[i][j] = __builtin_amdgcn_mfma_f32_16x16x32_bf16(af[i], bfr[j], acc[i][j], 0, 0, 0);
    __syncthreads();
  }

  const int N1 = N - N0;
#pragma unroll
  for (int i = 0; i < 4; ++i) {
    const int row0 = by * 128 + wr * 64 + i * 16 + (lane >> 4) * 4;
#pragma unroll
    for (int j = 0; j < 4; ++j) {
      const int col = bx * 128 + wc * 64 + j * 16 + (lane & 15);
      const f32x4 v = acc[i][j];
      if (col < N0) {
        float* p = C0 + (size_t)row0 * N0 + col;
#pragma unroll
        for (int r = 0; r < 4; ++r) p[(size_t)r * N0] = v[r];
      } else {
        float* p = C1 + (size_t)row0 * N1 + (col - N0);
#pragma unroll
        for (int r = 0; r < 4; ++r) p[(size_t)r * N1] = v[r];
      }
    }
  }
}

// ---------------------------------------------------------------------------
// causal depthwise conv (width 4) + bias + SiLU.  x,u: (B, L, D_INNER)
// ---------------------------------------------------------------------------
__global__ __launch_bounds__(256) void conv_silu_k(
    const float* __restrict__ x, const float* __restrict__ cw,
    const float* __restrict__ cb, float* __restrict__ u)
{
  const int idx = blockIdx.x * 256 + threadIdx.x;
  const int d  = idx & (D_INNER - 1);
  const int bl = idx >> 11;
  const int l  = bl & (SEQLEN - 1);
  const float4 w = *reinterpret_cast<const float4*>(&cw[d * 4]);
  const float* xp = x + (size_t)bl * D_INNER + d;
  float acc = cb[d] + w.w * xp[0];
  if (l >= 1) acc += w.z * xp[-D_INNER];
  if (l >= 2) acc += w.y * xp[-2 * D_INNER];
  if (l >= 3) acc += w.x * xp[-3 * D_INNER];
  u[idx] = acc / (1.f + __expf(-acc));
}

// ---------------------------------------------------------------------------
// x_dbl = U (BL x D_INNER) * x_proj_w (96 x D_INNER)^T -> (BL x 96), fp32.
// ---------------------------------------------------------------------------
__global__ __launch_bounds__(256) void gemm2_xproj(
    const float* __restrict__ U, const float* __restrict__ W,
    float* __restrict__ out)
{
  __shared__ __align__(16) float uT[32][34];
  __shared__ __align__(16) float wT[32][98];
  const int t = threadIdx.x;
  const int m0 = blockIdx.x * 32;
  const int tx = t & 15;
  const int ty = t >> 4;
  const int sr = t >> 3;
  const int sk = (t & 7) * 4;
  float acc[2][6] = {};
  for (int ks = 0; ks < D_INNER; ks += 32) {
    const float4 v = *reinterpret_cast<const float4*>(&U[(size_t)(m0 + sr) * D_INNER + ks + sk]);
    uT[sk + 0][sr] = v.x; uT[sk + 1][sr] = v.y; uT[sk + 2][sr] = v.z; uT[sk + 3][sr] = v.w;
#pragma unroll
    for (int p = 0; p < 3; ++p) {
      const int n = sr + p * 32;
      const float4 wv = *reinterpret_cast<const float4*>(&W[(size_t)n * D_INNER + ks + sk]);
      wT[sk + 0][n] = wv.x; wT[sk + 1][n] = wv.y; wT[sk + 2][n] = wv.z; wT[sk + 3][n] = wv.w;
    }
    __syncthreads();
#pragma unroll
    for (int kk = 0; kk < 32; ++kk) {
      const float2 a  = *reinterpret_cast<const float2*>(&uT[kk][ty * 2]);
      const float2 b0 = *reinterpret_cast<const float2*>(&wT[kk][tx * 6]);
      const float2 b1 = *reinterpret_cast<const float2*>(&wT[kk][tx * 6 + 2]);
      const float2 b2 = *reinterpret_cast<const float2*>(&wT[kk][tx * 6 + 4]);
      acc[0][0] += a.x * b0.x; acc[0][1] += a.x * b0.y;
      acc[0][2] += a.x * b1.x; acc[0][3] += a.x * b1.y;
      acc[0][4] += a.x * b2.x; acc[0][5] += a.x * b2.y;
      acc[1][0] += a.y * b0.x; acc[1][1] += a.y * b0.y;
      acc[1][2] += a.y * b1.x; acc[1][3] += a.y * b1.y;
      acc[1][4] += a.y * b2.x; acc[1][5] += a.y * b2.y;
    }
    __syncthreads();
  }
#pragma unroll
  for (int i = 0; i < 2; ++i)
#pragma unroll
    for (int j = 0; j < 6; ++j)
      out[(size_t)(m0 + ty * 2 + i) * NPROJ + tx * 6 + j] = acc[i][j];
}

// ---------------------------------------------------------------------------
// delta = softplus( xdbl[:, :64] * dt_proj_w^T + b )  (r3 structure, working)
// ---------------------------------------------------------------------------
__device__ __forceinline__ float softplusf(float x) {
  return (x > 20.f) ? x : log1pf(__expf(x));
}

__global__ __launch_bounds__(256) void gemm3_delta(
    const float* __restrict__ xdbl, const float* __restrict__ Wdt,
    const float* __restrict__ bdt, float* __restrict__ delta)
{
  __shared__ __align__(16) float aT[64][132];
  __shared__ __align__(16) float bT[64][68];
  const int t = threadIdx.x;
  const int n0 = blockIdx.x * 64;
  const int m0 = blockIdx.y * 128;

  {
    const int r  = t & 127;
    const int k0 = (t >> 7) * 32;
    const float* src = xdbl + (size_t)(m0 + r) * NPROJ + k0;
#pragma unroll
    for (int p = 0; p < 8; ++p) {
      const float4 v = *reinterpret_cast<const float4*>(&src[p * 4]);
      aT[k0 + p * 4 + 0][r] = v.x;
      aT[k0 + p * 4 + 1][r] = v.y;
      aT[k0 + p * 4 + 2][r] = v.z;
      aT[k0 + p * 4 + 3][r] = v.w;
    }
  }
  {
    const int r  = t & 63;
    const int k0 = (t >> 6) * 16;
    const float* src = Wdt + (size_t)(n0 + r) * DT_RANK + k0;
#pragma unroll
    for (int p = 0; p < 4; ++p) {
      const float4 v = *reinterpret_cast<const float4*>(&src[p * 4]);
      bT[k0 + p * 4 + 0][r] = v.x;
      bT[k0 + p * 4 + 1][r] = v.y;
      bT[k0 + p * 4 + 2][r] = v.z;
      bT[k0 + p * 4 + 3][r] = v.w;
    }
  }
  __syncthreads();

  const int tx = t & 15;
  const int ty = t >> 4;
  f32x4 acc[8] = {};
#pragma unroll 4
  for (int kk = 0; kk < 64; ++kk) {
    const f32x4 a0 = *reinterpret_cast<const f32x4*>(&aT[kk][ty * 8]);
    const f32x4 a1 = *reinterpret_cast<const f32x4*>(&aT[kk][ty * 8 + 4]);
    const f32x4 b  = *reinterpret_cast<const f32x4*>(&bT[kk][tx * 4]);
    acc[0] += a0.x * b;  acc[1] += a0.y * b;
    acc[2] += a0.z * b;  acc[3] += a0.w * b;
    acc[4] += a1.x * b;  acc[5] += a1.y * b;
    acc[6] += a1.z * b;  acc[7] += a1.w * b;
  }

  const float4 bias = *reinterpret_cast<const float4*>(&bdt[n0 + tx * 4]);
#pragma unroll
  for (int i = 0; i < 8; ++i) {
    const int m = m0 + ty * 8 + i;
    float4 o;
    o.x = softplusf(acc[i].x + bias.x);
    o.y = softplusf(acc[i].y + bias.y);
    o.z = softplusf(acc[i].z + bias.z);
    o.w = softplusf(acc[i].w + bias.w);
    *reinterpret_cast<float4*>(&delta[(size_t)m * D_INNER + n0 + tx * 4]) = o;
  }
}

// ---------------------------------------------------------------------------
// Chunked selective scan, 3 phases — r4 layout: lane = d, 16 states in VGPRs.
// (r3 failure: 16-lane-per-chain layout -> 4 serial ds_bpermute + divergent
//  epilogue per step = latency chain; 16x replicated loads/exp.)
// P/S/init are plane-major: idx = ((n*BATCH + b)*NCHUNK + c)*D_INNER + d
// so every access in p1/p2/p3 is stride-1 coalesced.
// ---------------------------------------------------------------------------
__global__ __launch_bounds__(256) void scan_p1(
    const float* __restrict__ delta, const float* __restrict__ u,
    const float* __restrict__ xdbl, const float* __restrict__ A_log,
    float* __restrict__ P, float* __restrict__ S)
{
  const int t = threadIdx.x;
  const int d = ((blockIdx.x & 7) << 8) + t;
  const int c = (blockIdx.x >> 3) & (NCHUNK - 1);
  const int b = blockIdx.x >> 9;

  float a[D_STATE];
  {
    const f32x4* ap = reinterpret_cast<const f32x4*>(&A_log[d * D_STATE]);
#pragma unroll
    for (int q = 0; q < 4; ++q) {
      const f32x4 v = ap[q];
      a[4 * q + 0] = -__expf(v.x); a[4 * q + 1] = -__expf(v.y);
      a[4 * q + 2] = -__expf(v.z); a[4 * q + 3] = -__expf(v.w);
    }
  }

  float s[D_STATE] = {};
  float sumdl = 0.f;

  const size_t rbase = (size_t)(b * SEQLEN + c * CLEN);
  const float* dp = delta + rbase * D_INNER + d;
  const float* up = u     + rbase * D_INNER + d;
  const float* xr = xdbl  + rbase * NPROJ + DT_RANK;   // wave-uniform

  for (int l = 0; l < CLEN; ++l) {
    const float dl = dp[(size_t)l * D_INNER];
    const float ul = up[(size_t)l * D_INNER];
    const float du = dl * ul;
    sumdl += dl;
    const float* Brow = xr + (size_t)l * NPROJ;
#pragma unroll
    for (int n = 0; n < D_STATE; ++n)
      s[n] = s[n] * __expf(dl * a[n]) + du * Brow[n];
  }

  const size_t plane = (size_t)BATCH * NCHUNK * D_INNER;
  const size_t pbase = ((size_t)b * NCHUNK + c) * D_INNER + d;
#pragma unroll
  for (int n = 0; n < D_STATE; ++n) {
    P[n * plane + pbase] = __expf(sumdl * a[n]);
    S[n * plane + pbase] = s[n];
  }
}

__global__ __launch_bounds__(256) void scan_p2(
    const float* __restrict__ P, const float* __restrict__ S,
    float* __restrict__ init)
{
  const int gid = blockIdx.x * 256 + threadIdx.x;   // ((n*BATCH+b), d)
  const int d  = gid & (D_INNER - 1);
  const int nb = gid >> 11;

  float carry = 0.f;
#pragma unroll 8
  for (int c = 0; c < NCHUNK; ++c) {
    const size_t o = ((size_t)nb * NCHUNK + c) * D_INNER + d;
    init[o] = carry;
    carry = carry * P[o] + S[o];
  }
}

__global__ __launch_bounds__(256) void scan_p3(
    const float* __restrict__ delta, const float* __restrict__ u,
    const float* __restrict__ z, const float* __restrict__ xdbl,
    const float* __restrict__ A_log, const float* __restrict__ Dvec,
    const float* __restrict__ init, bf16* __restrict__ y)
{
  const int t = threadIdx.x;
  const int d = ((blockIdx.x & 7) << 8) + t;
  const int c = (blockIdx.x >> 3) & (NCHUNK - 1);
  const int b = blockIdx.x >> 9;

  float a[D_STATE];
  {
    const f32x4* ap = reinterpret_cast<const f32x4*>(&A_log[d * D_STATE]);
#pragma unroll
    for (int q = 0; q < 4; ++q) {
      const f32x4 v = ap[q];
      a[4 * q + 0] = -__expf(v.x); a[4 * q + 1] = -__expf(v.y);
      a[4 * q + 2] = -__expf(v.z); a[4 * q + 3] = -__expf(v.w);
    }
  }
  const float Dd = Dvec[d];

  const size_t plane = (size_t)BATCH * NCHUNK * D_INNER;
  const size_t pbase = ((size_t)b * NCHUNK + c) * D_INNER + d;
  float s[D_STATE];
#pragma unroll
  for (int n = 0; n < D_STATE; ++n)
    s[n] = init[n * plane + pbase];

  const size_t rbase = (size_t)(b * SEQLEN + c * CLEN);
  const float* dp = delta + rbase * D_INNER + d;
  const float* up = u     + rbase * D_INNER + d;
  const float* zp = z     + rbase * D_INNER + d;
  const float* xr = xdbl  + rbase * NPROJ + DT_RANK;   // B at +0, C at +16
  unsigned short* yp = reinterpret_cast<unsigned short*>(y) + rbase * D_INNER + d;

  for (int l = 0; l < CLEN; ++l) {
    const float dl = dp[(size_t)l * D_INNER];
    const float ul = up[(size_t)l * D_INNER];
    const float zl = zp[(size_t)l * D_INNER];
    const float du = dl * ul;
    const float* Brow = xr + (size_t)l * NPROJ;
    float y0 = 0.f, y1 = 0.f, y2 = 0.f, y3 = 0.f;
#pragma unroll
    for (int q = 0; q < 4; ++q) {
      float p0 = 0.f;
#pragma unroll
      for (int j = 0; j < 4; ++j) {
        const int n = q * 4 + j;
        s[n] = s[n] * __expf(dl * a[n]) + du * Brow[n];
        p0 += s[n] * Brow[D_STATE + n];
      }
      if (q == 0) y0 = p0; else if (q == 1) y1 = p0;
      else if (q == 2) y2 = p0; else y3 = p0;
    }
    const float yv = ((y0 + y1) + (y2 + y3) + Dd * ul) * (zl / (1.f + __expf(-zl)));
    yp[(size_t)l * D_INNER] = f2bf(yv);
  }
}

// ---------------------------------------------------------------------------
extern "C" void kernel_launch(void* const* d_in, const int* in_sizes, int n_in,
                              void* d_out, int out_size, void* d_ws, size_t ws_size,
                              hipStream_t stream)
{
  (void)in_sizes; (void)n_in; (void)out_size; (void)ws_size;
  const float* hidden    = (const float*)d_in[0];
  const float* in_projw  = (const float*)d_in[1];
  const float* conv_w    = (const float*)d_in[2];
  const float* conv_b    = (const float*)d_in[3];
  const float* x_projw   = (const float*)d_in[4];
  const float* dt_projw  = (const float*)d_in[5];
  const float* dt_projb  = (const float*)d_in[6];
  const float* A_log     = (const float*)d_in[7];
  const float* Dvec      = (const float*)d_in[8];
  const float* out_projw = (const float*)d_in[9];
  float* out = (float*)d_out;

  char* ws = (char*)d_ws;
  size_t off = 0;
  auto alloc = [&](size_t bytes) -> void* {
    void* p = ws + off;
    off += (bytes + 255) & ~(size_t)255;
    return p;
  };
  float* x    = (float*)alloc((size_t)BL * D_INNER * 4);
  float* zbuf = (float*)alloc((size_t)BL * D_INNER * 4);
  float* ubuf = (float*)alloc((size_t)BL * D_INNER * 4);
  float* dbuf = (float*)alloc((size_t)BL * D_INNER * 4);
  float* xdbl = (float*)alloc((size_t)BL * NPROJ * 4);
  bf16* hbf   = (bf16*)alloc((size_t)BL * D_MODEL * 2);
  bf16* w1bf  = (bf16*)alloc((size_t)2 * D_INNER * D_MODEL * 2);
  bf16* w4bf  = (bf16*)alloc((size_t)D_MODEL * D_INNER * 2);
  float* Sbuf = (float*)alloc((size_t)D_STATE * BATCH * NCHUNK * D_INNER * 4);
  bf16* ybf   = (bf16*)x;      // x dead after conv; scan_p3 writes y here
  float* Pbuf = (float*)hbf;   // hbf+w1bf dead after GEMM1; 16.78 MB = |P|
  float* init = out;           // d_out dead until final GEMM overwrites it

  // casts to bf16 (RNE)
  cast_bf16_k<<<BL * D_MODEL / 4 / 256, 256, 0, stream>>>(hidden, hbf, BL * D_MODEL / 4);
  cast_bf16_k<<<2 * D_INNER * D_MODEL / 4 / 256, 256, 0, stream>>>(in_projw, w1bf, 2 * D_INNER * D_MODEL / 4);
  cast_bf16_k<<<D_MODEL * D_INNER / 4 / 256, 256, 0, stream>>>(out_projw, w4bf, D_MODEL * D_INNER / 4);

  // in_proj: xz = hidden * in_proj_w^T -> x | z
  gemm_bf16_mfma<<<dim3((2 * D_INNER) / 128, BL / 128), 256, 0, stream>>>(
      hbf, w1bf, x, zbuf, BL, 2 * D_INNER, D_MODEL, D_INNER);

  conv_silu_k<<<BL * D_INNER / 256, 256, 0, stream>>>(x, conv_w, conv_b, ubuf);
  gemm2_xproj<<<BL / 32, 256, 0, stream>>>(ubuf, x_projw, xdbl);
  gemm3_delta<<<dim3(D_INNER / 64, BL / 128), 256, 0, stream>>>(xdbl, dt_projw, dt_projb, dbuf);

  // chunked selective scan (lane-per-d layout)
  const int nblk = BATCH * NCHUNK * (D_INNER / 256);     // 1024
  scan_p1<<<nblk, 256, 0, stream>>>(dbuf, ubuf, xdbl, A_log, Pbuf, Sbuf);
  scan_p2<<<(BATCH * D_INNER * D_STATE) / 256, 256, 0, stream>>>(Pbuf, Sbuf, init);
  scan_p3<<<nblk, 256, 0, stream>>>(dbuf, ubuf, zbuf, xdbl, A_log, Dvec, init, ybf);

  // out_proj: out = y_gated * out_proj_w^T
  gemm_bf16_mfma<<<dim3(D_MODEL / 128, BL / 128), 256, 0, stream>>>(
      ybf, w4bf, out, out, BL, D_MODEL, D_INNER, D_MODEL);
}

// Round 5
// 300.945 us; speedup vs baseline: 5.9426x; 1.3463x over previous
//
#include <hip/hip_runtime.h>
#include <hip/hip_bf16.h>
#include <cstdint>
#include <cstddef>

#define D_MODEL 1024
#define D_STATE 16
#define D_INNER 2048
#define DT_RANK 64
#define BATCH 2
#define SEQLEN 2048
#define BL (BATCH*SEQLEN)
#define NPROJ 96
#define NCHUNK 64
#define CLEN 32   // NCHUNK * CLEN == SEQLEN
#define G2_KSLICE 8
#define G2_KLEN (D_INNER / G2_KSLICE)   // 256

static_assert(NCHUNK * CLEN == SEQLEN, "chunking");
static_assert((size_t)D_STATE * BATCH * NCHUNK * D_INNER == (size_t)BL * D_MODEL,
              "init aliases d_out exactly");
// Cpart aliases hbf+w1bf (both dead after gemm1): byte sizes must match
static_assert((size_t)G2_KSLICE * BL * 128 * 4 ==
              (size_t)BL * D_MODEL * 2 + (size_t)2 * D_INNER * D_MODEL * 2,
              "Cpart alias fits exactly");

typedef __hip_bfloat16 bf16;
using f32x4 = __attribute__((ext_vector_type(4))) float;
using s16x8 = __attribute__((ext_vector_type(8))) short;

__device__ __forceinline__ unsigned short f2bf(float f) {
  union { float f; unsigned int u; } v; v.f = f;
  unsigned int r = v.u + 0x7fffu + ((v.u >> 16) & 1u);
  return (unsigned short)(r >> 16);
}

__device__ __forceinline__ void async16(const void* g, void* l) {
  __builtin_amdgcn_global_load_lds(
      (const __attribute__((address_space(1))) void*)g,
      (__attribute__((address_space(3))) void*)l,
      16, 0, 0);
}

// ---------------------------------------------------------------------------
// fp32 -> bf16 cast (RNE), 4 elems/thread
// ---------------------------------------------------------------------------
__global__ __launch_bounds__(256) void cast_bf16_k(
    const float* __restrict__ in, bf16* __restrict__ out, int n4)
{
  const int i = blockIdx.x * 256 + threadIdx.x;
  if (i < n4) {
    const float4 v = *reinterpret_cast<const float4*>(&in[(size_t)i * 4]);
    ushort4 o;
    o.x = f2bf(v.x); o.y = f2bf(v.y); o.z = f2bf(v.z); o.w = f2bf(v.w);
    *reinterpret_cast<ushort4*>(&out[(size_t)i * 4]) = o;
  }
}

// ---------------------------------------------------------------------------
// x_proj_w (96 x 2048) -> bf16 padded to 128 rows (zeros beyond row 95)
// ---------------------------------------------------------------------------
__global__ __launch_bounds__(256) void cast_pad_w(
    const float* __restrict__ W, bf16* __restrict__ wpad)
{
  const int i = blockIdx.x * 256 + threadIdx.x;   // over 128*2048/4 = 65536
  const int n  = i >> 9;          // row (2048/4 = 512 groups per row)
  const int k4 = i & 511;
  ushort4 o = {0, 0, 0, 0};
  if (n < NPROJ) {
    const float4 v = *reinterpret_cast<const float4*>(&W[(size_t)n * D_INNER + k4 * 4]);
    o.x = f2bf(v.x); o.y = f2bf(v.y); o.z = f2bf(v.z); o.w = f2bf(v.w);
  }
  *reinterpret_cast<ushort4*>(&wpad[(size_t)n * D_INNER + k4 * 4]) = o;
}

// ---------------------------------------------------------------------------
// bf16 MFMA GEMM: C[M,N] = A[M,K] * B[N,K]^T, fp32 out (m97 structure).
// ---------------------------------------------------------------------------
__global__ __launch_bounds__(256) void gemm_bf16_mfma(
    const bf16* __restrict__ A, const bf16* __restrict__ B,
    float* __restrict__ C0, float* __restrict__ C1,
    int M, int N, int K, int N0)
{
  __shared__ __align__(16) bf16 As[128 * 32];
  __shared__ __align__(16) bf16 Bs[128 * 32];
  const int tid  = threadIdx.x;
  const int lane = tid & 63;
  const int wave = tid >> 6;
  const int wr = wave >> 1, wc = wave & 1;
  const int bx = blockIdx.x, by = blockIdx.y;

  const int srow = lane >> 2;
  const int scol = (lane & 3) * 8;
  const int c0 = wave * 2, c1 = wave * 2 + 1;
  const bf16* gA0 = A + (size_t)(by * 128 + c0 * 16 + srow) * K + scol;
  const bf16* gA1 = A + (size_t)(by * 128 + c1 * 16 + srow) * K + scol;
  const bf16* gB0 = B + (size_t)(bx * 128 + c0 * 16 + srow) * K + scol;
  const bf16* gB1 = B + (size_t)(bx * 128 + c1 * 16 + srow) * K + scol;
  bf16* lA0 = &As[c0 * 512];
  bf16* lA1 = &As[c1 * 512];
  bf16* lB0 = &Bs[c0 * 512];
  bf16* lB1 = &Bs[c1 * 512];

  f32x4 acc[4][4] = {};

  const int lrow = lane & 15;
  const int lkb  = (lane >> 4) * 8;

  for (int ks = 0; ks < K; ks += 32) {
    async16(gA0 + ks, lA0);
    async16(gA1 + ks, lA1);
    async16(gB0 + ks, lB0);
    async16(gB1 + ks, lB1);
    __syncthreads();
    s16x8 af[4], bfr[4];
#pragma unroll
    for (int i = 0; i < 4; ++i) {
      af[i]  = *reinterpret_cast<const s16x8*>(&As[(wr * 64 + i * 16 + lrow) * 32 + lkb]);
      bfr[i] = *reinterpret_cast<const s16x8*>(&Bs[(wc * 64 + i * 16 + lrow) * 32 + lkb]);
    }
#pragma unroll
    for (int i = 0; i < 4; ++i)
#pragma unroll
      for (int j = 0; j < 4; ++j)
        acc[i][j] = __builtin_amdgcn_mfma_f32_16x16x32_bf16(af[i], bfr[j], acc[i][j], 0, 0, 0);
    __syncthreads();
  }

  const int N1 = N - N0;
#pragma unroll
  for (int i = 0; i < 4; ++i) {
    const int row0 = by * 128 + wr * 64 + i * 16 + (lane >> 4) * 4;
#pragma unroll
    for (int j = 0; j < 4; ++j) {
      const int col = bx * 128 + wc * 64 + j * 16 + (lane & 15);
      const f32x4 v = acc[i][j];
      if (col < N0) {
        float* p = C0 + (size_t)row0 * N0 + col;
#pragma unroll
        for (int r = 0; r < 4; ++r) p[(size_t)r * N0] = v[r];
      } else {
        float* p = C1 + (size_t)row0 * N1 + (col - N0);
#pragma unroll
        for (int r = 0; r < 4; ++r) p[(size_t)r * N1] = v[r];
      }
    }
  }
}

// ---------------------------------------------------------------------------
// gemm2 rewrite (r5): x_dbl partials = ubf (BLx2048) * wpad(128x2048)^T.
// Split-K 8x256, grid (8,32) = 256 blocks (r4 failure: 128-block grid ->
// 5.7% occupancy, latency-bound 137us). Fixed-order reduce keeps determinism.
// ---------------------------------------------------------------------------
__global__ __launch_bounds__(256) void gemm2_mfma(
    const bf16* __restrict__ A, const bf16* __restrict__ B,
    float* __restrict__ Cpart)
{
  __shared__ __align__(16) bf16 As[128 * 32];
  __shared__ __align__(16) bf16 Bs[128 * 32];
  const int tid  = threadIdx.x;
  const int lane = tid & 63;
  const int wave = tid >> 6;
  const int wr = wave >> 1, wc = wave & 1;
  const int kz = blockIdx.x, by = blockIdx.y;

  const int srow = lane >> 2;
  const int scol = (lane & 3) * 8;
  const int c0 = wave * 2, c1 = wave * 2 + 1;
  const int kbase = kz * G2_KLEN;
  const bf16* gA0 = A + (size_t)(by * 128 + c0 * 16 + srow) * D_INNER + kbase + scol;
  const bf16* gA1 = A + (size_t)(by * 128 + c1 * 16 + srow) * D_INNER + kbase + scol;
  const bf16* gB0 = B + (size_t)(c0 * 16 + srow) * D_INNER + kbase + scol;
  const bf16* gB1 = B + (size_t)(c1 * 16 + srow) * D_INNER + kbase + scol;
  bf16* lA0 = &As[c0 * 512];
  bf16* lA1 = &As[c1 * 512];
  bf16* lB0 = &Bs[c0 * 512];
  bf16* lB1 = &Bs[c1 * 512];

  f32x4 acc[4][4] = {};
  const int lrow = lane & 15;
  const int lkb  = (lane >> 4) * 8;

  for (int ks = 0; ks < G2_KLEN; ks += 32) {
    async16(gA0 + ks, lA0);
    async16(gA1 + ks, lA1);
    async16(gB0 + ks, lB0);
    async16(gB1 + ks, lB1);
    __syncthreads();
    s16x8 af[4], bfr[4];
#pragma unroll
    for (int i = 0; i < 4; ++i) {
      af[i]  = *reinterpret_cast<const s16x8*>(&As[(wr * 64 + i * 16 + lrow) * 32 + lkb]);
      bfr[i] = *reinterpret_cast<const s16x8*>(&Bs[(wc * 64 + i * 16 + lrow) * 32 + lkb]);
    }
#pragma unroll
    for (int i = 0; i < 4; ++i)
#pragma unroll
      for (int j = 0; j < 4; ++j)
        acc[i][j] = __builtin_amdgcn_mfma_f32_16x16x32_bf16(af[i], bfr[j], acc[i][j], 0, 0, 0);
    __syncthreads();
  }

  float* Cz = Cpart + (size_t)kz * BL * 128;
#pragma unroll
  for (int i = 0; i < 4; ++i) {
    const int row0 = by * 128 + wr * 64 + i * 16 + (lane >> 4) * 4;
#pragma unroll
    for (int j = 0; j < 4; ++j) {
      const int col = wc * 64 + j * 16 + (lane & 15);
      const f32x4 v = acc[i][j];
      float* p = Cz + (size_t)row0 * 128 + col;
#pragma unroll
      for (int r = 0; r < 4; ++r) p[(size_t)r * 128] = v[r];
    }
  }
}

// xdbl[m][n<96] = sum_z Cpart[z][m][n]; fixed order (deterministic)
__global__ __launch_bounds__(256) void reduce_xdbl(
    const float* __restrict__ Cpart, float* __restrict__ xdbl)
{
  const int i = blockIdx.x * 256 + threadIdx.x;   // over BL*24
  const int m = i / 24;
  const int g = i - m * 24;
  f32x4 s = {};
#pragma unroll
  for (int z = 0; z < G2_KSLICE; ++z)
    s += *reinterpret_cast<const f32x4*>(&Cpart[((size_t)z * BL + m) * 128 + g * 4]);
  *reinterpret_cast<f32x4*>(&xdbl[(size_t)m * NPROJ + g * 4]) = s;
}

// ---------------------------------------------------------------------------
// causal depthwise conv (width 4) + bias + SiLU; emits fp32 u and bf16 ubf.
// ---------------------------------------------------------------------------
__global__ __launch_bounds__(256) void conv_silu_k(
    const float* __restrict__ x, const float* __restrict__ cw,
    const float* __restrict__ cb, float* __restrict__ u,
    bf16* __restrict__ ubf)
{
  const int idx = blockIdx.x * 256 + threadIdx.x;
  const int d  = idx & (D_INNER - 1);
  const int bl = idx >> 11;
  const int l  = bl & (SEQLEN - 1);
  const float4 w = *reinterpret_cast<const float4*>(&cw[d * 4]);
  const float* xp = x + (size_t)bl * D_INNER + d;
  float acc = cb[d] + w.w * xp[0];
  if (l >= 1) acc += w.z * xp[-D_INNER];
  if (l >= 2) acc += w.y * xp[-2 * D_INNER];
  if (l >= 3) acc += w.x * xp[-3 * D_INNER];
  const float val = acc / (1.f + __expf(-acc));
  u[idx] = val;
  reinterpret_cast<unsigned short*>(ubf)[idx] = f2bf(val);
}

// ---------------------------------------------------------------------------
// delta = softplus( xdbl[:, :64] * dt_proj_w^T + b )  (r3 structure, working)
// ---------------------------------------------------------------------------
__device__ __forceinline__ float softplusf(float x) {
  return (x > 20.f) ? x : log1pf(__expf(x));
}

__global__ __launch_bounds__(256) void gemm3_delta(
    const float* __restrict__ xdbl, const float* __restrict__ Wdt,
    const float* __restrict__ bdt, float* __restrict__ delta)
{
  __shared__ __align__(16) float aT[64][132];
  __shared__ __align__(16) float bT[64][68];
  const int t = threadIdx.x;
  const int n0 = blockIdx.x * 64;
  const int m0 = blockIdx.y * 128;

  {
    const int r  = t & 127;
    const int k0 = (t >> 7) * 32;
    const float* src = xdbl + (size_t)(m0 + r) * NPROJ + k0;
#pragma unroll
    for (int p = 0; p < 8; ++p) {
      const float4 v = *reinterpret_cast<const float4*>(&src[p * 4]);
      aT[k0 + p * 4 + 0][r] = v.x;
      aT[k0 + p * 4 + 1][r] = v.y;
      aT[k0 + p * 4 + 2][r] = v.z;
      aT[k0 + p * 4 + 3][r] = v.w;
    }
  }
  {
    const int r  = t & 63;
    const int k0 = (t >> 6) * 16;
    const float* src = Wdt + (size_t)(n0 + r) * DT_RANK + k0;
#pragma unroll
    for (int p = 0; p < 4; ++p) {
      const float4 v = *reinterpret_cast<const float4*>(&src[p * 4]);
      bT[k0 + p * 4 + 0][r] = v.x;
      bT[k0 + p * 4 + 1][r] = v.y;
      bT[k0 + p * 4 + 2][r] = v.z;
      bT[k0 + p * 4 + 3][r] = v.w;
    }
  }
  __syncthreads();

  const int tx = t & 15;
  const int ty = t >> 4;
  f32x4 acc[8] = {};
#pragma unroll 4
  for (int kk = 0; kk < 64; ++kk) {
    const f32x4 a0 = *reinterpret_cast<const f32x4*>(&aT[kk][ty * 8]);
    const f32x4 a1 = *reinterpret_cast<const f32x4*>(&aT[kk][ty * 8 + 4]);
    const f32x4 b  = *reinterpret_cast<const f32x4*>(&bT[kk][tx * 4]);
    acc[0] += a0.x * b;  acc[1] += a0.y * b;
    acc[2] += a0.z * b;  acc[3] += a0.w * b;
    acc[4] += a1.x * b;  acc[5] += a1.y * b;
    acc[6] += a1.z * b;  acc[7] += a1.w * b;
  }

  const float4 bias = *reinterpret_cast<const float4*>(&bdt[n0 + tx * 4]);
#pragma unroll
  for (int i = 0; i < 8; ++i) {
    const int m = m0 + ty * 8 + i;
    float4 o;
    o.x = softplusf(acc[i].x + bias.x);
    o.y = softplusf(acc[i].y + bias.y);
    o.z = softplusf(acc[i].z + bias.z);
    o.w = softplusf(acc[i].w + bias.w);
    *reinterpret_cast<float4*>(&delta[(size_t)m * D_INNER + n0 + tx * 4]) = o;
  }
}

// ---------------------------------------------------------------------------
// Chunked selective scan, 3 phases — lane = d, 16 states in VGPRs (r4).
// P/S/init plane-major: idx = ((n*BATCH + b)*NCHUNK + c)*D_INNER + d
// ---------------------------------------------------------------------------
__global__ __launch_bounds__(256) void scan_p1(
    const float* __restrict__ delta, const float* __restrict__ u,
    const float* __restrict__ xdbl, const float* __restrict__ A_log,
    float* __restrict__ P, float* __restrict__ S)
{
  const int t = threadIdx.x;
  const int d = ((blockIdx.x & 7) << 8) + t;
  const int c = (blockIdx.x >> 3) & (NCHUNK - 1);
  const int b = blockIdx.x >> 9;

  float a[D_STATE];
  {
    const f32x4* ap = reinterpret_cast<const f32x4*>(&A_log[d * D_STATE]);
#pragma unroll
    for (int q = 0; q < 4; ++q) {
      const f32x4 v = ap[q];
      a[4 * q + 0] = -__expf(v.x); a[4 * q + 1] = -__expf(v.y);
      a[4 * q + 2] = -__expf(v.z); a[4 * q + 3] = -__expf(v.w);
    }
  }

  float s[D_STATE] = {};
  float sumdl = 0.f;

  const size_t rbase = (size_t)(b * SEQLEN + c * CLEN);
  const float* dp = delta + rbase * D_INNER + d;
  const float* up = u     + rbase * D_INNER + d;
  const float* xr = xdbl  + rbase * NPROJ + DT_RANK;

  for (int l = 0; l < CLEN; ++l) {
    const float dl = dp[(size_t)l * D_INNER];
    const float ul = up[(size_t)l * D_INNER];
    const float du = dl * ul;
    sumdl += dl;
    const float* Brow = xr + (size_t)l * NPROJ;
#pragma unroll
    for (int n = 0; n < D_STATE; ++n)
      s[n] = s[n] * __expf(dl * a[n]) + du * Brow[n];
  }

  const size_t plane = (size_t)BATCH * NCHUNK * D_INNER;
  const size_t pbase = ((size_t)b * NCHUNK + c) * D_INNER + d;
#pragma unroll
  for (int n = 0; n < D_STATE; ++n) {
    P[n * plane + pbase] = __expf(sumdl * a[n]);
    S[n * plane + pbase] = s[n];
  }
}

__global__ __launch_bounds__(256) void scan_p2(
    const float* __restrict__ P, const float* __restrict__ S,
    float* __restrict__ init)
{
  const int gid = blockIdx.x * 256 + threadIdx.x;
  const int d  = gid & (D_INNER - 1);
  const int nb = gid >> 11;

  float carry = 0.f;
#pragma unroll 8
  for (int c = 0; c < NCHUNK; ++c) {
    const size_t o = ((size_t)nb * NCHUNK + c) * D_INNER + d;
    init[o] = carry;
    carry = carry * P[o] + S[o];
  }
}

__global__ __launch_bounds__(256) void scan_p3(
    const float* __restrict__ delta, const float* __restrict__ u,
    const float* __restrict__ z, const float* __restrict__ xdbl,
    const float* __restrict__ A_log, const float* __restrict__ Dvec,
    const float* __restrict__ init, bf16* __restrict__ y)
{
  const int t = threadIdx.x;
  const int d = ((blockIdx.x & 7) << 8) + t;
  const int c = (blockIdx.x >> 3) & (NCHUNK - 1);
  const int b = blockIdx.x >> 9;

  float a[D_STATE];
  {
    const f32x4* ap = reinterpret_cast<const f32x4*>(&A_log[d * D_STATE]);
#pragma unroll
    for (int q = 0; q < 4; ++q) {
      const f32x4 v = ap[q];
      a[4 * q + 0] = -__expf(v.x); a[4 * q + 1] = -__expf(v.y);
      a[4 * q + 2] = -__expf(v.z); a[4 * q + 3] = -__expf(v.w);
    }
  }
  const float Dd = Dvec[d];

  const size_t plane = (size_t)BATCH * NCHUNK * D_INNER;
  const size_t pbase = ((size_t)b * NCHUNK + c) * D_INNER + d;
  float s[D_STATE];
#pragma unroll
  for (int n = 0; n < D_STATE; ++n)
    s[n] = init[n * plane + pbase];

  const size_t rbase = (size_t)(b * SEQLEN + c * CLEN);
  const float* dp = delta + rbase * D_INNER + d;
  const float* up = u     + rbase * D_INNER + d;
  const float* zp = z     + rbase * D_INNER + d;
  const float* xr = xdbl  + rbase * NPROJ + DT_RANK;
  unsigned short* yp = reinterpret_cast<unsigned short*>(y) + rbase * D_INNER + d;

  for (int l = 0; l < CLEN; ++l) {
    const float dl = dp[(size_t)l * D_INNER];
    const float ul = up[(size_t)l * D_INNER];
    const float zl = zp[(size_t)l * D_INNER];
    const float du = dl * ul;
    const float* Brow = xr + (size_t)l * NPROJ;
    float y0 = 0.f, y1 = 0.f, y2 = 0.f, y3 = 0.f;
#pragma unroll
    for (int q = 0; q < 4; ++q) {
      float p0 = 0.f;
#pragma unroll
      for (int j = 0; j < 4; ++j) {
        const int n = q * 4 + j;
        s[n] = s[n] * __expf(dl * a[n]) + du * Brow[n];
        p0 += s[n] * Brow[D_STATE + n];
      }
      if (q == 0) y0 = p0; else if (q == 1) y1 = p0;
      else if (q == 2) y2 = p0; else y3 = p0;
    }
    const float yv = ((y0 + y1) + (y2 + y3) + Dd * ul) * (zl / (1.f + __expf(-zl)));
    yp[(size_t)l * D_INNER] = f2bf(yv);
  }
}

// ---------------------------------------------------------------------------
extern "C" void kernel_launch(void* const* d_in, const int* in_sizes, int n_in,
                              void* d_out, int out_size, void* d_ws, size_t ws_size,
                              hipStream_t stream)
{
  (void)in_sizes; (void)n_in; (void)out_size; (void)ws_size;
  const float* hidden    = (const float*)d_in[0];
  const float* in_projw  = (const float*)d_in[1];
  const float* conv_w    = (const float*)d_in[2];
  const float* conv_b    = (const float*)d_in[3];
  const float* x_projw   = (const float*)d_in[4];
  const float* dt_projw  = (const float*)d_in[5];
  const float* dt_projb  = (const float*)d_in[6];
  const float* A_log     = (const float*)d_in[7];
  const float* Dvec      = (const float*)d_in[8];
  const float* out_projw = (const float*)d_in[9];
  float* out = (float*)d_out;

  char* ws = (char*)d_ws;
  size_t off = 0;
  auto alloc = [&](size_t bytes) -> void* {
    void* p = ws + off;
    off += (bytes + 255) & ~(size_t)255;
    return p;
  };
  float* x    = (float*)alloc((size_t)BL * D_INNER * 4);
  float* zbuf = (float*)alloc((size_t)BL * D_INNER * 4);
  float* ubuf = (float*)alloc((size_t)BL * D_INNER * 4);
  float* dbuf = (float*)alloc((size_t)BL * D_INNER * 4);
  float* xdbl = (float*)alloc((size_t)BL * NPROJ * 4);
  bf16* hbf   = (bf16*)alloc((size_t)BL * D_MODEL * 2);
  bf16* w1bf  = (bf16*)alloc((size_t)2 * D_INNER * D_MODEL * 2);
  bf16* w4bf  = (bf16*)alloc((size_t)D_MODEL * D_INNER * 2);
  float* Sbuf = (float*)alloc((size_t)D_STATE * BATCH * NCHUNK * D_INNER * 4);
  bf16* ubf   = (bf16*)alloc((size_t)BL * D_INNER * 2);
  bf16* wpad  = (bf16*)alloc((size_t)128 * D_INNER * 2);
  bf16* ybf   = (bf16*)x;       // x dead after conv; scan_p3 writes y here
  float* Cpart = (float*)hbf;   // hbf+w1bf dead after gemm1; 16.78 MB exact
  float* Pbuf  = (float*)hbf;   // same region, reused later (after reduce)
  float* init  = out;           // d_out dead until final GEMM overwrites it

  // casts to bf16 (RNE)
  cast_bf16_k<<<BL * D_MODEL / 4 / 256, 256, 0, stream>>>(hidden, hbf, BL * D_MODEL / 4);
  cast_bf16_k<<<2 * D_INNER * D_MODEL / 4 / 256, 256, 0, stream>>>(in_projw, w1bf, 2 * D_INNER * D_MODEL / 4);
  cast_bf16_k<<<D_MODEL * D_INNER / 4 / 256, 256, 0, stream>>>(out_projw, w4bf, D_MODEL * D_INNER / 4);
  cast_pad_w<<<128 * D_INNER / 4 / 256, 256, 0, stream>>>(x_projw, wpad);

  // in_proj: xz = hidden * in_proj_w^T -> x | z
  gemm_bf16_mfma<<<dim3((2 * D_INNER) / 128, BL / 128), 256, 0, stream>>>(
      hbf, w1bf, x, zbuf, BL, 2 * D_INNER, D_MODEL, D_INNER);

  conv_silu_k<<<BL * D_INNER / 256, 256, 0, stream>>>(x, conv_w, conv_b, ubuf, ubf);

  // x_proj: split-K MFMA + deterministic reduce (hbf/w1bf dead -> Cpart alias)
  gemm2_mfma<<<dim3(G2_KSLICE, BL / 128), 256, 0, stream>>>(ubf, wpad, Cpart);
  reduce_xdbl<<<BL * 24 / 256, 256, 0, stream>>>(Cpart, xdbl);

  gemm3_delta<<<dim3(D_INNER / 64, BL / 128), 256, 0, stream>>>(xdbl, dt_projw, dt_projb, dbuf);

  // chunked selective scan (lane-per-d layout); Pbuf reuses Cpart region
  const int nblk = BATCH * NCHUNK * (D_INNER / 256);     // 1024
  scan_p1<<<nblk, 256, 0, stream>>>(dbuf, ubuf, xdbl, A_log, Pbuf, Sbuf);
  scan_p2<<<(BATCH * D_INNER * D_STATE) / 256, 256, 0, stream>>>(Pbuf, Sbuf, init);
  scan_p3<<<nblk, 256, 0, stream>>>(dbuf, ubuf, zbuf, xdbl, A_log, Dvec, init, ybf);

  // out_proj: out = y_gated * out_proj_w^T
  gemm_bf16_mfma<<<dim3(D_MODEL / 128, BL / 128), 256, 0, stream>>>(
      ybf, w4bf, out, out, BL, D_MODEL, D_INNER, D_MODEL);
}

// Round 6
// 278.871 us; speedup vs baseline: 6.4130x; 1.0792x over previous
//
#include <hip/hip_runtime.h>
#include <hip/hip_bf16.h>
#include <cstdint>
#include <cstddef>

#define D_MODEL 1024
#define D_STATE 16
#define D_INNER 2048
#define DT_RANK 64
#define BATCH 2
#define SEQLEN 2048
#define BL (BATCH*SEQLEN)
#define NPROJ 96
#define NCHUNK 64
#define CLEN 32   // NCHUNK * CLEN == SEQLEN
#define G2_KSLICE 8
#define G2_KLEN (D_INNER / G2_KSLICE)   // 256

static_assert(NCHUNK * CLEN == SEQLEN, "chunking");
static_assert((size_t)D_STATE * BATCH * NCHUNK * D_INNER == (size_t)BL * D_MODEL,
              "init aliases d_out exactly");
static_assert((size_t)G2_KSLICE * BL * 128 * 4 ==
              (size_t)BL * D_MODEL * 2 + (size_t)2 * D_INNER * D_MODEL * 2,
              "Cpart alias fits exactly");

typedef __hip_bfloat16 bf16;
using f32x4 = __attribute__((ext_vector_type(4))) float;
using s16x8 = __attribute__((ext_vector_type(8))) short;

__device__ __forceinline__ unsigned short f2bf(float f) {
  union { float f; unsigned int u; } v; v.f = f;
  unsigned int r = v.u + 0x7fffu + ((v.u >> 16) & 1u);
  return (unsigned short)(r >> 16);
}

__device__ __forceinline__ float bf2f(unsigned short u) {
  return __uint_as_float(((unsigned int)u) << 16);
}

__device__ __forceinline__ void async16(const void* g, void* l) {
  __builtin_amdgcn_global_load_lds(
      (const __attribute__((address_space(1))) void*)g,
      (__attribute__((address_space(3))) void*)l,
      16, 0, 0);
}

// ---------------------------------------------------------------------------
// merged fp32->bf16 casts: hidden, in_proj_w, out_proj_w, x_proj_w (padded 128)
// ---------------------------------------------------------------------------
__device__ __forceinline__ void cvt4(const float* __restrict__ in,
                                     bf16* __restrict__ out, int i) {
  const float4 v = *reinterpret_cast<const float4*>(&in[(size_t)i * 4]);
  ushort4 o;
  o.x = f2bf(v.x); o.y = f2bf(v.y); o.z = f2bf(v.z); o.w = f2bf(v.w);
  *reinterpret_cast<ushort4*>(&out[(size_t)i * 4]) = o;
}

#define CAST_NH  (BL * D_MODEL / 4)
#define CAST_NW1 (2 * D_INNER * D_MODEL / 4)
#define CAST_NW4 (D_MODEL * D_INNER / 4)
#define CAST_NWP (128 * D_INNER / 4)
#define CAST_TOTAL (CAST_NH + CAST_NW1 + CAST_NW4 + CAST_NWP)
static_assert(CAST_TOTAL % 256 == 0, "cast grid");

__global__ __launch_bounds__(256) void cast_all(
    const float* __restrict__ hidden, const float* __restrict__ w1,
    const float* __restrict__ w4, const float* __restrict__ xpw,
    bf16* __restrict__ hbf, bf16* __restrict__ w1bf,
    bf16* __restrict__ w4bf, bf16* __restrict__ wpad)
{
  const int i = blockIdx.x * 256 + threadIdx.x;
  if (i < CAST_NH) {
    cvt4(hidden, hbf, i);
  } else if (i < CAST_NH + CAST_NW1) {
    cvt4(w1, w1bf, i - CAST_NH);
  } else if (i < CAST_NH + CAST_NW1 + CAST_NW4) {
    cvt4(w4, w4bf, i - CAST_NH - CAST_NW1);
  } else {
    const int j = i - CAST_NH - CAST_NW1 - CAST_NW4;   // < 65536
    const int n = j >> 9;          // padded row (0..127)
    const int k4 = j & 511;
    ushort4 o = {0, 0, 0, 0};
    if (n < NPROJ) {
      const float4 v = *reinterpret_cast<const float4*>(&xpw[(size_t)n * D_INNER + k4 * 4]);
      o.x = f2bf(v.x); o.y = f2bf(v.y); o.z = f2bf(v.z); o.w = f2bf(v.w);
    }
    *reinterpret_cast<ushort4*>(&wpad[(size_t)n * D_INNER + k4 * 4]) = o;
  }
}

// ---------------------------------------------------------------------------
// in_proj GEMM (r6): 256x256 tile, 8 waves, BK=64, double-buffered 128KB LDS,
// issue-early staging (T3 minimum-2-phase recipe), XOR-swizzled LDS
// (g ^= (r>>2)&3 on 16B units; applied to global SOURCE + READ, linear dest
// per rule #21).  C split at N0 (block-uniform since N0%256==0).
// ---------------------------------------------------------------------------
__global__ __launch_bounds__(512, 2) void gemm1_256(
    const bf16* __restrict__ A, const bf16* __restrict__ B,
    float* __restrict__ C0, float* __restrict__ C1,
    int M, int N, int K, int N0)
{
  extern __shared__ char smem[];   // A: [2dbuf][2ksub][256r][64B] = 65536
                                   // B: same at +65536; total 131072
  const int tid  = threadIdx.x;
  const int lane = tid & 63;
  const int wid  = tid >> 6;       // 0..7
  const int wr   = wid >> 2;       // 0..1  (M half)
  const int wc   = wid & 3;        // 0..3  (N quarter)
  const int m0 = blockIdx.y * 256;
  const int n0 = blockIdx.x * 256;
  const int lrow = lane & 15;
  const int kg   = lane >> 4;      // 0..3 (16B k-group)
  const int sr4  = lane >> 2;      // staging row-within-16
  const int sg   = lane & 3;       // staging 16B unit
  const int NT = K >> 6;

  f32x4 acc[8][4] = {};

  auto stage = [&](int t, int db) {
    const int kb = t * 64;
#pragma unroll
    for (int j = 0; j < 4; ++j) {
      const int ia = wid * 4 + j;            // 0..31 (2 ksub x 16 row-blocks)
      const int s = ia >> 4;
      const int r = (ia & 15) * 16 + sr4;
      const int gs = sg ^ ((r >> 2) & 3);    // inverse-swizzled source col
      async16(A + (size_t)(m0 + r) * K + kb + s * 32 + gs * 8,
              smem + db * 32768 + ia * 1024);
      async16(B + (size_t)(n0 + r) * K + kb + s * 32 + gs * 8,
              smem + 65536 + db * 32768 + ia * 1024);
    }
  };

  auto compute = [&](int db) {
    const char* ab = smem + db * 32768;
    const char* bb = ab + 65536;
    s16x8 bfr[4][2];
#pragma unroll
    for (int nf = 0; nf < 4; ++nf) {
      const int r = wc * 64 + nf * 16 + lrow;
      const int gsw = kg ^ ((r >> 2) & 3);
#pragma unroll
      for (int s = 0; s < 2; ++s)
        bfr[nf][s] = *reinterpret_cast<const s16x8*>(bb + s * 16384 + r * 64 + gsw * 16);
    }
#pragma unroll
    for (int mf = 0; mf < 8; ++mf) {
      const int r = wr * 128 + mf * 16 + lrow;
      const int gsw = kg ^ ((r >> 2) & 3);
      const s16x8 a0 = *reinterpret_cast<const s16x8*>(ab + r * 64 + gsw * 16);
      const s16x8 a1 = *reinterpret_cast<const s16x8*>(ab + 16384 + r * 64 + gsw * 16);
#pragma unroll
      for (int nf = 0; nf < 4; ++nf) {
        acc[mf][nf] = __builtin_amdgcn_mfma_f32_16x16x32_bf16(a0, bfr[nf][0], acc[mf][nf], 0, 0, 0);
        acc[mf][nf] = __builtin_amdgcn_mfma_f32_16x16x32_bf16(a1, bfr[nf][1], acc[mf][nf], 0, 0, 0);
      }
    }
  };

  stage(0, 0);
  __syncthreads();                  // drains vmcnt -> tile 0 visible
  for (int t = 0; t < NT; ++t) {
    const int db = t & 1;
    if (t + 1 < NT) stage(t + 1, db ^ 1);   // issue BEFORE compute (overlap)
    compute(db);
    __syncthreads();                // single drain+barrier per K-tile
  }

  const int N1 = N - N0;
  const bool inC0 = (n0 < N0);      // block-uniform (N0 % 256 == 0)
  float* Cb = inC0 ? C0 : C1;
  const int stride = inC0 ? N0 : N1;
  const int cb = inC0 ? n0 : (n0 - N0);
#pragma unroll
  for (int mf = 0; mf < 8; ++mf) {
    const int row0 = m0 + wr * 128 + mf * 16 + kg * 4;
#pragma unroll
    for (int nf = 0; nf < 4; ++nf) {
      const int col = cb + wc * 64 + nf * 16 + lrow;
      const f32x4 v = acc[mf][nf];
      float* p = Cb + (size_t)row0 * stride + col;
#pragma unroll
      for (int r = 0; r < 4; ++r) p[(size_t)r * stride] = v[r];
    }
  }
}

// ---------------------------------------------------------------------------
// bf16 MFMA GEMM (m97 structure) — used for out_proj (N=1024: 256-block grid
// beats a 64-block 256^2 grid).
// ---------------------------------------------------------------------------
__global__ __launch_bounds__(256) void gemm_bf16_mfma(
    const bf16* __restrict__ A, const bf16* __restrict__ B,
    float* __restrict__ C0, float* __restrict__ C1,
    int M, int N, int K, int N0)
{
  __shared__ __align__(16) bf16 As[128 * 32];
  __shared__ __align__(16) bf16 Bs[128 * 32];
  const int tid  = threadIdx.x;
  const int lane = tid & 63;
  const int wave = tid >> 6;
  const int wr = wave >> 1, wc = wave & 1;
  const int bx = blockIdx.x, by = blockIdx.y;

  const int srow = lane >> 2;
  const int scol = (lane & 3) * 8;
  const int c0 = wave * 2, c1 = wave * 2 + 1;
  const bf16* gA0 = A + (size_t)(by * 128 + c0 * 16 + srow) * K + scol;
  const bf16* gA1 = A + (size_t)(by * 128 + c1 * 16 + srow) * K + scol;
  const bf16* gB0 = B + (size_t)(bx * 128 + c0 * 16 + srow) * K + scol;
  const bf16* gB1 = B + (size_t)(bx * 128 + c1 * 16 + srow) * K + scol;
  bf16* lA0 = &As[c0 * 512];
  bf16* lA1 = &As[c1 * 512];
  bf16* lB0 = &Bs[c0 * 512];
  bf16* lB1 = &Bs[c1 * 512];

  f32x4 acc[4][4] = {};
  const int lrow = lane & 15;
  const int lkb  = (lane >> 4) * 8;

  for (int ks = 0; ks < K; ks += 32) {
    async16(gA0 + ks, lA0);
    async16(gA1 + ks, lA1);
    async16(gB0 + ks, lB0);
    async16(gB1 + ks, lB1);
    __syncthreads();
    s16x8 af[4], bfr[4];
#pragma unroll
    for (int i = 0; i < 4; ++i) {
      af[i]  = *reinterpret_cast<const s16x8*>(&As[(wr * 64 + i * 16 + lrow) * 32 + lkb]);
      bfr[i] = *reinterpret_cast<const s16x8*>(&Bs[(wc * 64 + i * 16 + lrow) * 32 + lkb]);
    }
#pragma unroll
    for (int i = 0; i < 4; ++i)
#pragma unroll
      for (int j = 0; j < 4; ++j)
        acc[i][j] = __builtin_amdgcn_mfma_f32_16x16x32_bf16(af[i], bfr[j], acc[i][j], 0, 0, 0);
    __syncthreads();
  }

  const int N1 = N - N0;
#pragma unroll
  for (int i = 0; i < 4; ++i) {
    const int row0 = by * 128 + wr * 64 + i * 16 + (lane >> 4) * 4;
#pragma unroll
    for (int j = 0; j < 4; ++j) {
      const int col = bx * 128 + wc * 64 + j * 16 + (lane & 15);
      const f32x4 v = acc[i][j];
      if (col < N0) {
        float* p = C0 + (size_t)row0 * N0 + col;
#pragma unroll
        for (int r = 0; r < 4; ++r) p[(size_t)r * N0] = v[r];
      } else {
        float* p = C1 + (size_t)row0 * N1 + (col - N0);
#pragma unroll
        for (int r = 0; r < 4; ++r) p[(size_t)r * N1] = v[r];
      }
    }
  }
}

// ---------------------------------------------------------------------------
// gemm2: x_dbl partials = ubf (BLx2048) * wpad(128x2048)^T, split-K 8x256.
// ---------------------------------------------------------------------------
__global__ __launch_bounds__(256) void gemm2_mfma(
    const bf16* __restrict__ A, const bf16* __restrict__ B,
    float* __restrict__ Cpart)
{
  __shared__ __align__(16) bf16 As[128 * 32];
  __shared__ __align__(16) bf16 Bs[128 * 32];
  const int tid  = threadIdx.x;
  const int lane = tid & 63;
  const int wave = tid >> 6;
  const int wr = wave >> 1, wc = wave & 1;
  const int kz = blockIdx.x, by = blockIdx.y;

  const int srow = lane >> 2;
  const int scol = (lane & 3) * 8;
  const int c0 = wave * 2, c1 = wave * 2 + 1;
  const int kbase = kz * G2_KLEN;
  const bf16* gA0 = A + (size_t)(by * 128 + c0 * 16 + srow) * D_INNER + kbase + scol;
  const bf16* gA1 = A + (size_t)(by * 128 + c1 * 16 + srow) * D_INNER + kbase + scol;
  const bf16* gB0 = B + (size_t)(c0 * 16 + srow) * D_INNER + kbase + scol;
  const bf16* gB1 = B + (size_t)(c1 * 16 + srow) * D_INNER + kbase + scol;
  bf16* lA0 = &As[c0 * 512];
  bf16* lA1 = &As[c1 * 512];
  bf16* lB0 = &Bs[c0 * 512];
  bf16* lB1 = &Bs[c1 * 512];

  f32x4 acc[4][4] = {};
  const int lrow = lane & 15;
  const int lkb  = (lane >> 4) * 8;

  for (int ks = 0; ks < G2_KLEN; ks += 32) {
    async16(gA0 + ks, lA0);
    async16(gA1 + ks, lA1);
    async16(gB0 + ks, lB0);
    async16(gB1 + ks, lB1);
    __syncthreads();
    s16x8 af[4], bfr[4];
#pragma unroll
    for (int i = 0; i < 4; ++i) {
      af[i]  = *reinterpret_cast<const s16x8*>(&As[(wr * 64 + i * 16 + lrow) * 32 + lkb]);
      bfr[i] = *reinterpret_cast<const s16x8*>(&Bs[(wc * 64 + i * 16 + lrow) * 32 + lkb]);
    }
#pragma unroll
    for (int i = 0; i < 4; ++i)
#pragma unroll
      for (int j = 0; j < 4; ++j)
        acc[i][j] = __builtin_amdgcn_mfma_f32_16x16x32_bf16(af[i], bfr[j], acc[i][j], 0, 0, 0);
    __syncthreads();
  }

  float* Cz = Cpart + (size_t)kz * BL * 128;
#pragma unroll
  for (int i = 0; i < 4; ++i) {
    const int row0 = by * 128 + wr * 64 + i * 16 + (lane >> 4) * 4;
#pragma unroll
    for (int j = 0; j < 4; ++j) {
      const int col = wc * 64 + j * 16 + (lane & 15);
      const f32x4 v = acc[i][j];
      float* p = Cz + (size_t)row0 * 128 + col;
#pragma unroll
      for (int r = 0; r < 4; ++r) p[(size_t)r * 128] = v[r];
    }
  }
}

__global__ __launch_bounds__(256) void reduce_xdbl(
    const float* __restrict__ Cpart, float* __restrict__ xdbl)
{
  const int i = blockIdx.x * 256 + threadIdx.x;   // over BL*24
  const int m = i / 24;
  const int g = i - m * 24;
  f32x4 s = {};
#pragma unroll
  for (int z = 0; z < G2_KSLICE; ++z)
    s += *reinterpret_cast<const f32x4*>(&Cpart[((size_t)z * BL + m) * 128 + g * 4]);
  *reinterpret_cast<f32x4*>(&xdbl[(size_t)m * NPROJ + g * 4]) = s;
}

// ---------------------------------------------------------------------------
// causal depthwise conv (width 4) + bias + SiLU -> bf16 u only (r6: fp32 u
// dropped; scans read bf16).
// ---------------------------------------------------------------------------
__global__ __launch_bounds__(256) void conv_silu_k(
    const float* __restrict__ x, const float* __restrict__ cw,
    const float* __restrict__ cb, bf16* __restrict__ ubf)
{
  const int idx = blockIdx.x * 256 + threadIdx.x;
  const int d  = idx & (D_INNER - 1);
  const int bl = idx >> 11;
  const int l  = bl & (SEQLEN - 1);
  const float4 w = *reinterpret_cast<const float4*>(&cw[d * 4]);
  const float* xp = x + (size_t)bl * D_INNER + d;
  float acc = cb[d] + w.w * xp[0];
  if (l >= 1) acc += w.z * xp[-D_INNER];
  if (l >= 2) acc += w.y * xp[-2 * D_INNER];
  if (l >= 3) acc += w.x * xp[-3 * D_INNER];
  const float val = acc / (1.f + __expf(-acc));
  reinterpret_cast<unsigned short*>(ubf)[idx] = f2bf(val);
}

// ---------------------------------------------------------------------------
// delta = softplus( xdbl[:, :64] * dt_proj_w^T + b )
// ---------------------------------------------------------------------------
__device__ __forceinline__ float softplusf(float x) {
  return (x > 20.f) ? x : log1pf(__expf(x));
}

__global__ __launch_bounds__(256) void gemm3_delta(
    const float* __restrict__ xdbl, const float* __restrict__ Wdt,
    const float* __restrict__ bdt, float* __restrict__ delta)
{
  __shared__ __align__(16) float aT[64][132];
  __shared__ __align__(16) float bT[64][68];
  const int t = threadIdx.x;
  const int n0 = blockIdx.x * 64;
  const int m0 = blockIdx.y * 128;

  {
    const int r  = t & 127;
    const int k0 = (t >> 7) * 32;
    const float* src = xdbl + (size_t)(m0 + r) * NPROJ + k0;
#pragma unroll
    for (int p = 0; p < 8; ++p) {
      const float4 v = *reinterpret_cast<const float4*>(&src[p * 4]);
      aT[k0 + p * 4 + 0][r] = v.x;
      aT[k0 + p * 4 + 1][r] = v.y;
      aT[k0 + p * 4 + 2][r] = v.z;
      aT[k0 + p * 4 + 3][r] = v.w;
    }
  }
  {
    const int r  = t & 63;
    const int k0 = (t >> 6) * 16;
    const float* src = Wdt + (size_t)(n0 + r) * DT_RANK + k0;
#pragma unroll
    for (int p = 0; p < 4; ++p) {
      const float4 v = *reinterpret_cast<const float4*>(&src[p * 4]);
      bT[k0 + p * 4 + 0][r] = v.x;
      bT[k0 + p * 4 + 1][r] = v.y;
      bT[k0 + p * 4 + 2][r] = v.z;
      bT[k0 + p * 4 + 3][r] = v.w;
    }
  }
  __syncthreads();

  const int tx = t & 15;
  const int ty = t >> 4;
  f32x4 acc[8] = {};
#pragma unroll 4
  for (int kk = 0; kk < 64; ++kk) {
    const f32x4 a0 = *reinterpret_cast<const f32x4*>(&aT[kk][ty * 8]);
    const f32x4 a1 = *reinterpret_cast<const f32x4*>(&aT[kk][ty * 8 + 4]);
    const f32x4 b  = *reinterpret_cast<const f32x4*>(&bT[kk][tx * 4]);
    acc[0] += a0.x * b;  acc[1] += a0.y * b;
    acc[2] += a0.z * b;  acc[3] += a0.w * b;
    acc[4] += a1.x * b;  acc[5] += a1.y * b;
    acc[6] += a1.z * b;  acc[7] += a1.w * b;
  }

  const float4 bias = *reinterpret_cast<const float4*>(&bdt[n0 + tx * 4]);
#pragma unroll
  for (int i = 0; i < 8; ++i) {
    const int m = m0 + ty * 8 + i;
    float4 o;
    o.x = softplusf(acc[i].x + bias.x);
    o.y = softplusf(acc[i].y + bias.y);
    o.z = softplusf(acc[i].z + bias.z);
    o.w = softplusf(acc[i].w + bias.w);
    *reinterpret_cast<float4*>(&delta[(size_t)m * D_INNER + n0 + tx * 4]) = o;
  }
}

// ---------------------------------------------------------------------------
// Chunked selective scan, 3 phases — lane = d, 16 states in VGPRs.
// u is now bf16 (ubf).  P/S/init plane-major.
// ---------------------------------------------------------------------------
__global__ __launch_bounds__(256) void scan_p1(
    const float* __restrict__ delta, const bf16* __restrict__ ubf,
    const float* __restrict__ xdbl, const float* __restrict__ A_log,
    float* __restrict__ P, float* __restrict__ S)
{
  const int t = threadIdx.x;
  const int d = ((blockIdx.x & 7) << 8) + t;
  const int c = (blockIdx.x >> 3) & (NCHUNK - 1);
  const int b = blockIdx.x >> 9;

  float a[D_STATE];
  {
    const f32x4* ap = reinterpret_cast<const f32x4*>(&A_log[d * D_STATE]);
#pragma unroll
    for (int q = 0; q < 4; ++q) {
      const f32x4 v = ap[q];
      a[4 * q + 0] = -__expf(v.x); a[4 * q + 1] = -__expf(v.y);
      a[4 * q + 2] = -__expf(v.z); a[4 * q + 3] = -__expf(v.w);
    }
  }

  float s[D_STATE] = {};
  float sumdl = 0.f;

  const size_t rbase = (size_t)(b * SEQLEN + c * CLEN);
  const float* dp = delta + rbase * D_INNER + d;
  const unsigned short* up = reinterpret_cast<const unsigned short*>(ubf) + rbase * D_INNER + d;
  const float* xr = xdbl  + rbase * NPROJ + DT_RANK;

  for (int l = 0; l < CLEN; ++l) {
    const float dl = dp[(size_t)l * D_INNER];
    const float ul = bf2f(up[(size_t)l * D_INNER]);
    const float du = dl * ul;
    sumdl += dl;
    const float* Brow = xr + (size_t)l * NPROJ;
#pragma unroll
    for (int n = 0; n < D_STATE; ++n)
      s[n] = s[n] * __expf(dl * a[n]) + du * Brow[n];
  }

  const size_t plane = (size_t)BATCH * NCHUNK * D_INNER;
  const size_t pbase = ((size_t)b * NCHUNK + c) * D_INNER + d;
#pragma unroll
  for (int n = 0; n < D_STATE; ++n) {
    P[n * plane + pbase] = __expf(sumdl * a[n]);
    S[n * plane + pbase] = s[n];
  }
}

__global__ __launch_bounds__(256) void scan_p2(
    const float* __restrict__ P, const float* __restrict__ S,
    float* __restrict__ init)
{
  const int gid = blockIdx.x * 256 + threadIdx.x;
  const int d  = gid & (D_INNER - 1);
  const int nb = gid >> 11;

  float carry = 0.f;
#pragma unroll 8
  for (int c = 0; c < NCHUNK; ++c) {
    const size_t o = ((size_t)nb * NCHUNK + c) * D_INNER + d;
    init[o] = carry;
    carry = carry * P[o] + S[o];
  }
}

__global__ __launch_bounds__(256) void scan_p3(
    const float* __restrict__ delta, const bf16* __restrict__ ubf,
    const float* __restrict__ z, const float* __restrict__ xdbl,
    const float* __restrict__ A_log, const float* __restrict__ Dvec,
    const float* __restrict__ init, bf16* __restrict__ y)
{
  const int t = threadIdx.x;
  const int d = ((blockIdx.x & 7) << 8) + t;
  const int c = (blockIdx.x >> 3) & (NCHUNK - 1);
  const int b = blockIdx.x >> 9;

  float a[D_STATE];
  {
    const f32x4* ap = reinterpret_cast<const f32x4*>(&A_log[d * D_STATE]);
#pragma unroll
    for (int q = 0; q < 4; ++q) {
      const f32x4 v = ap[q];
      a[4 * q + 0] = -__expf(v.x); a[4 * q + 1] = -__expf(v.y);
      a[4 * q + 2] = -__expf(v.z); a[4 * q + 3] = -__expf(v.w);
    }
  }
  const float Dd = Dvec[d];

  const size_t plane = (size_t)BATCH * NCHUNK * D_INNER;
  const size_t pbase = ((size_t)b * NCHUNK + c) * D_INNER + d;
  float s[D_STATE];
#pragma unroll
  for (int n = 0; n < D_STATE; ++n)
    s[n] = init[n * plane + pbase];

  const size_t rbase = (size_t)(b * SEQLEN + c * CLEN);
  const float* dp = delta + rbase * D_INNER + d;
  const unsigned short* up = reinterpret_cast<const unsigned short*>(ubf) + rbase * D_INNER + d;
  const float* zp = z     + rbase * D_INNER + d;
  const float* xr = xdbl  + rbase * NPROJ + DT_RANK;
  unsigned short* yp = reinterpret_cast<unsigned short*>(y) + rbase * D_INNER + d;

  for (int l = 0; l < CLEN; ++l) {
    const float dl = dp[(size_t)l * D_INNER];
    const float ul = bf2f(up[(size_t)l * D_INNER]);
    const float zl = zp[(size_t)l * D_INNER];
    const float du = dl * ul;
    const float* Brow = xr + (size_t)l * NPROJ;
    float y0 = 0.f, y1 = 0.f, y2 = 0.f, y3 = 0.f;
#pragma unroll
    for (int q = 0; q < 4; ++q) {
      float p0 = 0.f;
#pragma unroll
      for (int j = 0; j < 4; ++j) {
        const int n = q * 4 + j;
        s[n] = s[n] * __expf(dl * a[n]) + du * Brow[n];
        p0 += s[n] * Brow[D_STATE + n];
      }
      if (q == 0) y0 = p0; else if (q == 1) y1 = p0;
      else if (q == 2) y2 = p0; else y3 = p0;
    }
    const float yv = ((y0 + y1) + (y2 + y3) + Dd * ul) * (zl / (1.f + __expf(-zl)));
    yp[(size_t)l * D_INNER] = f2bf(yv);
  }
}

// ---------------------------------------------------------------------------
extern "C" void kernel_launch(void* const* d_in, const int* in_sizes, int n_in,
                              void* d_out, int out_size, void* d_ws, size_t ws_size,
                              hipStream_t stream)
{
  (void)in_sizes; (void)n_in; (void)out_size; (void)ws_size;
  const float* hidden    = (const float*)d_in[0];
  const float* in_projw  = (const float*)d_in[1];
  const float* conv_w    = (const float*)d_in[2];
  const float* conv_b    = (const float*)d_in[3];
  const float* x_projw   = (const float*)d_in[4];
  const float* dt_projw  = (const float*)d_in[5];
  const float* dt_projb  = (const float*)d_in[6];
  const float* A_log     = (const float*)d_in[7];
  const float* Dvec      = (const float*)d_in[8];
  const float* out_projw = (const float*)d_in[9];
  float* out = (float*)d_out;

  char* ws = (char*)d_ws;
  size_t off = 0;
  auto alloc = [&](size_t bytes) -> void* {
    void* p = ws + off;
    off += (bytes + 255) & ~(size_t)255;
    return p;
  };
  float* x    = (float*)alloc((size_t)BL * D_INNER * 4);
  float* zbuf = (float*)alloc((size_t)BL * D_INNER * 4);
  float* dbuf = (float*)alloc((size_t)BL * D_INNER * 4);
  float* xdbl = (float*)alloc((size_t)BL * NPROJ * 4);
  bf16* hbf   = (bf16*)alloc((size_t)BL * D_MODEL * 2);
  bf16* w1bf  = (bf16*)alloc((size_t)2 * D_INNER * D_MODEL * 2);
  bf16* w4bf  = (bf16*)alloc((size_t)D_MODEL * D_INNER * 2);
  float* Sbuf = (float*)alloc((size_t)D_STATE * BATCH * NCHUNK * D_INNER * 4);
  bf16* ubf   = (bf16*)alloc((size_t)BL * D_INNER * 2);
  bf16* wpad  = (bf16*)alloc((size_t)128 * D_INNER * 2);
  bf16* ybf   = (bf16*)x;       // x dead after conv; scan_p3 writes y here
  float* Cpart = (float*)hbf;   // hbf+w1bf dead after gemm1; exact fit
  float* Pbuf  = (float*)hbf;   // same region, reused after reduce
  float* init  = out;           // d_out dead until final GEMM overwrites it

  // merged casts (hidden, in_proj_w, out_proj_w, padded x_proj_w)
  cast_all<<<CAST_TOTAL / 256, 256, 0, stream>>>(
      hidden, in_projw, out_projw, x_projw, hbf, w1bf, w4bf, wpad);

  // in_proj: xz = hidden * in_proj_w^T -> x | z  (256^2 double-buffered)
  hipFuncSetAttribute(reinterpret_cast<const void*>(gemm1_256),
                      hipFuncAttributeMaxDynamicSharedMemorySize, 131072);
  gemm1_256<<<dim3((2 * D_INNER) / 256, BL / 256), 512, 131072, stream>>>(
      hbf, w1bf, x, zbuf, BL, 2 * D_INNER, D_MODEL, D_INNER);

  conv_silu_k<<<BL * D_INNER / 256, 256, 0, stream>>>(x, conv_w, conv_b, ubf);

  // x_proj: split-K MFMA + deterministic reduce (hbf/w1bf dead -> Cpart alias)
  gemm2_mfma<<<dim3(G2_KSLICE, BL / 128), 256, 0, stream>>>(ubf, wpad, Cpart);
  reduce_xdbl<<<BL * 24 / 256, 256, 0, stream>>>(Cpart, xdbl);

  gemm3_delta<<<dim3(D_INNER / 64, BL / 128), 256, 0, stream>>>(xdbl, dt_projw, dt_projb, dbuf);

  // chunked selective scan (lane-per-d layout); Pbuf reuses Cpart region
  const int nblk = BATCH * NCHUNK * (D_INNER / 256);     // 1024
  scan_p1<<<nblk, 256, 0, stream>>>(dbuf, ubf, xdbl, A_log, Pbuf, Sbuf);
  scan_p2<<<(BATCH * D_INNER * D_STATE) / 256, 256, 0, stream>>>(Pbuf, Sbuf, init);
  scan_p3<<<nblk, 256, 0, stream>>>(dbuf, ubf, zbuf, xdbl, A_log, Dvec, init, ybf);

  // out_proj: out = y_gated * out_proj_w^T  (m97 structure, 256-block grid)
  gemm_bf16_mfma<<<dim3(D_MODEL / 128, BL / 128), 256, 0, stream>>>(
      ybf, w4bf, out, out, BL, D_MODEL, D_INNER, D_MODEL);
}

// Round 7
// 252.601 us; speedup vs baseline: 7.0800x; 1.1040x over previous
//
#include <hip/hip_runtime.h>
#include <hip/hip_bf16.h>
#include <cstdint>
#include <cstddef>

#define D_MODEL 1024
#define D_STATE 16
#define D_INNER 2048
#define DT_RANK 64
#define BATCH 2
#define SEQLEN 2048
#define BL (BATCH*SEQLEN)
#define NPROJ 96
#define NCHUNK 64
#define CLEN 32   // NCHUNK * CLEN == SEQLEN
#define G2_KSLICE 8
#define G2_KLEN (D_INNER / G2_KSLICE)   // 256

static_assert(NCHUNK * CLEN == SEQLEN, "chunking");
static_assert((size_t)D_STATE * BATCH * NCHUNK * D_INNER == (size_t)BL * D_MODEL,
              "init aliases d_out exactly");
static_assert((size_t)G2_KSLICE * BL * 128 * 4 ==
              (size_t)BL * D_MODEL * 2 + (size_t)2 * D_INNER * D_MODEL * 2,
              "Cpart alias fits exactly");

typedef __hip_bfloat16 bf16;
using f32x4 = __attribute__((ext_vector_type(4))) float;
using s16x8 = __attribute__((ext_vector_type(8))) short;

__device__ __forceinline__ unsigned short f2bf(float f) {
  union { float f; unsigned int u; } v; v.f = f;
  unsigned int r = v.u + 0x7fffu + ((v.u >> 16) & 1u);
  return (unsigned short)(r >> 16);
}

__device__ __forceinline__ float bf2f(unsigned short u) {
  return __uint_as_float(((unsigned int)u) << 16);
}

__device__ __forceinline__ void async16(const void* g, void* l) {
  __builtin_amdgcn_global_load_lds(
      (const __attribute__((address_space(1))) void*)g,
      (__attribute__((address_space(3))) void*)l,
      16, 0, 0);
}

// ---------------------------------------------------------------------------
// merged fp32->bf16 casts: hidden, in_proj_w, out_proj_w, x_proj_w (padded 128)
// ---------------------------------------------------------------------------
__device__ __forceinline__ void cvt4(const float* __restrict__ in,
                                     bf16* __restrict__ out, int i) {
  const float4 v = *reinterpret_cast<const float4*>(&in[(size_t)i * 4]);
  ushort4 o;
  o.x = f2bf(v.x); o.y = f2bf(v.y); o.z = f2bf(v.z); o.w = f2bf(v.w);
  *reinterpret_cast<ushort4*>(&out[(size_t)i * 4]) = o;
}

#define CAST_NH  (BL * D_MODEL / 4)
#define CAST_NW1 (2 * D_INNER * D_MODEL / 4)
#define CAST_NW4 (D_MODEL * D_INNER / 4)
#define CAST_NWP (128 * D_INNER / 4)
#define CAST_TOTAL (CAST_NH + CAST_NW1 + CAST_NW4 + CAST_NWP)
static_assert(CAST_TOTAL % 256 == 0, "cast grid");

__global__ __launch_bounds__(256) void cast_all(
    const float* __restrict__ hidden, const float* __restrict__ w1,
    const float* __restrict__ w4, const float* __restrict__ xpw,
    bf16* __restrict__ hbf, bf16* __restrict__ w1bf,
    bf16* __restrict__ w4bf, bf16* __restrict__ wpad)
{
  const int i = blockIdx.x * 256 + threadIdx.x;
  if (i < CAST_NH) {
    cvt4(hidden, hbf, i);
  } else if (i < CAST_NH + CAST_NW1) {
    cvt4(w1, w1bf, i - CAST_NH);
  } else if (i < CAST_NH + CAST_NW1 + CAST_NW4) {
    cvt4(w4, w4bf, i - CAST_NH - CAST_NW1);
  } else {
    const int j = i - CAST_NH - CAST_NW1 - CAST_NW4;   // < 65536
    const int n = j >> 9;          // padded row (0..127)
    const int k4 = j & 511;
    ushort4 o = {0, 0, 0, 0};
    if (n < NPROJ) {
      const float4 v = *reinterpret_cast<const float4*>(&xpw[(size_t)n * D_INNER + k4 * 4]);
      o.x = f2bf(v.x); o.y = f2bf(v.y); o.z = f2bf(v.z); o.w = f2bf(v.w);
    }
    *reinterpret_cast<ushort4*>(&wpad[(size_t)n * D_INNER + k4 * 4]) = o;
  }
}

// ---------------------------------------------------------------------------
// in_proj GEMM: 256x256 tile, 8 waves, BK=64, double-buffered 128KB LDS,
// issue-early staging, XOR-swizzled LDS (verified r6).
// ---------------------------------------------------------------------------
__global__ __launch_bounds__(512, 2) void gemm1_256(
    const bf16* __restrict__ A, const bf16* __restrict__ B,
    float* __restrict__ C0, float* __restrict__ C1,
    int M, int N, int K, int N0)
{
  extern __shared__ char smem[];   // A: [2dbuf][2ksub][256r][64B] = 65536
                                   // B: same at +65536; total 131072
  const int tid  = threadIdx.x;
  const int lane = tid & 63;
  const int wid  = tid >> 6;       // 0..7
  const int wr   = wid >> 2;       // 0..1  (M half)
  const int wc   = wid & 3;        // 0..3  (N quarter)
  const int m0 = blockIdx.y * 256;
  const int n0 = blockIdx.x * 256;
  const int lrow = lane & 15;
  const int kg   = lane >> 4;      // 0..3 (16B k-group)
  const int sr4  = lane >> 2;      // staging row-within-16
  const int sg   = lane & 3;       // staging 16B unit
  const int NT = K >> 6;

  f32x4 acc[8][4] = {};

  auto stage = [&](int t, int db) {
    const int kb = t * 64;
#pragma unroll
    for (int j = 0; j < 4; ++j) {
      const int ia = wid * 4 + j;            // 0..31 (2 ksub x 16 row-blocks)
      const int s = ia >> 4;
      const int r = (ia & 15) * 16 + sr4;
      const int gs = sg ^ ((r >> 2) & 3);    // inverse-swizzled source col
      async16(A + (size_t)(m0 + r) * K + kb + s * 32 + gs * 8,
              smem + db * 32768 + ia * 1024);
      async16(B + (size_t)(n0 + r) * K + kb + s * 32 + gs * 8,
              smem + 65536 + db * 32768 + ia * 1024);
    }
  };

  auto compute = [&](int db) {
    const char* ab = smem + db * 32768;
    const char* bb = ab + 65536;
    s16x8 bfr[4][2];
#pragma unroll
    for (int nf = 0; nf < 4; ++nf) {
      const int r = wc * 64 + nf * 16 + lrow;
      const int gsw = kg ^ ((r >> 2) & 3);
#pragma unroll
      for (int s = 0; s < 2; ++s)
        bfr[nf][s] = *reinterpret_cast<const s16x8*>(bb + s * 16384 + r * 64 + gsw * 16);
    }
#pragma unroll
    for (int mf = 0; mf < 8; ++mf) {
      const int r = wr * 128 + mf * 16 + lrow;
      const int gsw = kg ^ ((r >> 2) & 3);
      const s16x8 a0 = *reinterpret_cast<const s16x8*>(ab + r * 64 + gsw * 16);
      const s16x8 a1 = *reinterpret_cast<const s16x8*>(ab + 16384 + r * 64 + gsw * 16);
#pragma unroll
      for (int nf = 0; nf < 4; ++nf) {
        acc[mf][nf] = __builtin_amdgcn_mfma_f32_16x16x32_bf16(a0, bfr[nf][0], acc[mf][nf], 0, 0, 0);
        acc[mf][nf] = __builtin_amdgcn_mfma_f32_16x16x32_bf16(a1, bfr[nf][1], acc[mf][nf], 0, 0, 0);
      }
    }
  };

  stage(0, 0);
  __syncthreads();
  for (int t = 0; t < NT; ++t) {
    const int db = t & 1;
    if (t + 1 < NT) stage(t + 1, db ^ 1);   // issue BEFORE compute (overlap)
    compute(db);
    __syncthreads();
  }

  const int N1 = N - N0;
  const bool inC0 = (n0 < N0);      // block-uniform (N0 % 256 == 0)
  float* Cb = inC0 ? C0 : C1;
  const int stride = inC0 ? N0 : N1;
  const int cb = inC0 ? n0 : (n0 - N0);
#pragma unroll
  for (int mf = 0; mf < 8; ++mf) {
    const int row0 = m0 + wr * 128 + mf * 16 + kg * 4;
#pragma unroll
    for (int nf = 0; nf < 4; ++nf) {
      const int col = cb + wc * 64 + nf * 16 + lrow;
      const f32x4 v = acc[mf][nf];
      float* p = Cb + (size_t)row0 * stride + col;
#pragma unroll
      for (int r = 0; r < 4; ++r) p[(size_t)r * stride] = v[r];
    }
  }
}

// ---------------------------------------------------------------------------
// out_proj GEMM (r7): 128x64 tile, 4 waves, BK=64, double-buffered 48KB LDS,
// issue-early staging + XOR swizzle (same 64B-row pattern as gemm1_256).
// Grid (N/64, M/128) = 512 blocks = 2/CU (r6 failure: m97 at 256 blocks =
// 1 block/CU, no TLP, barrier drain exposed -> 307 TF).
// ---------------------------------------------------------------------------
__global__ __launch_bounds__(256, 2) void gemm_out_128x64(
    const bf16* __restrict__ A, const bf16* __restrict__ B,
    float* __restrict__ C, int M, int N, int K)
{
  extern __shared__ char smem[];   // A: [2db][2ks][128r][64B] = 32768
                                   // B: [2db][2ks][ 64r][64B] = 16384 at +32768
  const int tid  = threadIdx.x;
  const int lane = tid & 63;
  const int wid  = tid >> 6;       // 0..3
  const int wr   = wid >> 1;       // 0..1 (M half: 64 rows)
  const int wc   = wid & 1;        // 0..1 (N half: 32 cols)
  const int m0 = blockIdx.y * 128;
  const int n0 = blockIdx.x * 64;
  const int lrow = lane & 15;
  const int kg   = lane >> 4;      // 0..3
  const int sr4  = lane >> 2;      // 0..15
  const int sg   = lane & 3;       // 0..3
  const int NT = K >> 6;

  f32x4 acc[4][2] = {};

  auto stage = [&](int t, int db) {
    const int kb = t * 64;
    // A: 16 chunks of 1KB (ia: ksub = ia>>3, 16-row block = ia&7)
#pragma unroll
    for (int j = 0; j < 4; ++j) {
      const int ia = wid * 4 + j;            // 0..15
      const int s = ia >> 3;
      const int r = (ia & 7) * 16 + sr4;
      const int gs = sg ^ ((r >> 2) & 3);
      async16(A + (size_t)(m0 + r) * K + kb + s * 32 + gs * 8,
              smem + db * 16384 + ia * 1024);
    }
    // B: 8 chunks of 1KB (ib: ksub = ib>>2, 16-row block = ib&3)
#pragma unroll
    for (int j = 0; j < 2; ++j) {
      const int ib = wid * 2 + j;            // 0..7
      const int s = ib >> 2;
      const int r = (ib & 3) * 16 + sr4;
      const int gs = sg ^ ((r >> 2) & 3);
      async16(B + (size_t)(n0 + r) * K + kb + s * 32 + gs * 8,
              smem + 32768 + db * 8192 + ib * 1024);
    }
  };

  auto compute = [&](int db) {
    const char* ab = smem + db * 16384;
    const char* bb = smem + 32768 + db * 8192;
    s16x8 bfr[2][2];
#pragma unroll
    for (int nf = 0; nf < 2; ++nf) {
      const int r = wc * 32 + nf * 16 + lrow;
      const int gsw = kg ^ ((r >> 2) & 3);
      bfr[nf][0] = *reinterpret_cast<const s16x8*>(bb + r * 64 + gsw * 16);
      bfr[nf][1] = *reinterpret_cast<const s16x8*>(bb + 4096 + r * 64 + gsw * 16);
    }
#pragma unroll
    for (int mf = 0; mf < 4; ++mf) {
      const int r = wr * 64 + mf * 16 + lrow;
      const int gsw = kg ^ ((r >> 2) & 3);
      const s16x8 a0 = *reinterpret_cast<const s16x8*>(ab + r * 64 + gsw * 16);
      const s16x8 a1 = *reinterpret_cast<const s16x8*>(ab + 8192 + r * 64 + gsw * 16);
#pragma unroll
      for (int nf = 0; nf < 2; ++nf) {
        acc[mf][nf] = __builtin_amdgcn_mfma_f32_16x16x32_bf16(a0, bfr[nf][0], acc[mf][nf], 0, 0, 0);
        acc[mf][nf] = __builtin_amdgcn_mfma_f32_16x16x32_bf16(a1, bfr[nf][1], acc[mf][nf], 0, 0, 0);
      }
    }
  };

  stage(0, 0);
  __syncthreads();
  for (int t = 0; t < NT; ++t) {
    const int db = t & 1;
    if (t + 1 < NT) stage(t + 1, db ^ 1);
    compute(db);
    __syncthreads();
  }

#pragma unroll
  for (int mf = 0; mf < 4; ++mf) {
    const int row0 = m0 + wr * 64 + mf * 16 + kg * 4;
#pragma unroll
    for (int nf = 0; nf < 2; ++nf) {
      const int col = n0 + wc * 32 + nf * 16 + lrow;
      const f32x4 v = acc[mf][nf];
      float* p = C + (size_t)row0 * N + col;
#pragma unroll
      for (int r = 0; r < 4; ++r) p[(size_t)r * N] = v[r];
    }
  }
}

// ---------------------------------------------------------------------------
// gemm2: x_dbl partials = ubf (BLx2048) * wpad(128x2048)^T, split-K 8x256.
// ---------------------------------------------------------------------------
__global__ __launch_bounds__(256) void gemm2_mfma(
    const bf16* __restrict__ A, const bf16* __restrict__ B,
    float* __restrict__ Cpart)
{
  __shared__ __align__(16) bf16 As[128 * 32];
  __shared__ __align__(16) bf16 Bs[128 * 32];
  const int tid  = threadIdx.x;
  const int lane = tid & 63;
  const int wave = tid >> 6;
  const int wr = wave >> 1, wc = wave & 1;
  const int kz = blockIdx.x, by = blockIdx.y;

  const int srow = lane >> 2;
  const int scol = (lane & 3) * 8;
  const int c0 = wave * 2, c1 = wave * 2 + 1;
  const int kbase = kz * G2_KLEN;
  const bf16* gA0 = A + (size_t)(by * 128 + c0 * 16 + srow) * D_INNER + kbase + scol;
  const bf16* gA1 = A + (size_t)(by * 128 + c1 * 16 + srow) * D_INNER + kbase + scol;
  const bf16* gB0 = B + (size_t)(c0 * 16 + srow) * D_INNER + kbase + scol;
  const bf16* gB1 = B + (size_t)(c1 * 16 + srow) * D_INNER + kbase + scol;
  bf16* lA0 = &As[c0 * 512];
  bf16* lA1 = &As[c1 * 512];
  bf16* lB0 = &Bs[c0 * 512];
  bf16* lB1 = &Bs[c1 * 512];

  f32x4 acc[4][4] = {};
  const int lrow = lane & 15;
  const int lkb  = (lane >> 4) * 8;

  for (int ks = 0; ks < G2_KLEN; ks += 32) {
    async16(gA0 + ks, lA0);
    async16(gA1 + ks, lA1);
    async16(gB0 + ks, lB0);
    async16(gB1 + ks, lB1);
    __syncthreads();
    s16x8 af[4], bfr[4];
#pragma unroll
    for (int i = 0; i < 4; ++i) {
      af[i]  = *reinterpret_cast<const s16x8*>(&As[(wr * 64 + i * 16 + lrow) * 32 + lkb]);
      bfr[i] = *reinterpret_cast<const s16x8*>(&Bs[(wc * 64 + i * 16 + lrow) * 32 + lkb]);
    }
#pragma unroll
    for (int i = 0; i < 4; ++i)
#pragma unroll
      for (int j = 0; j < 4; ++j)
        acc[i][j] = __builtin_amdgcn_mfma_f32_16x16x32_bf16(af[i], bfr[j], acc[i][j], 0, 0, 0);
    __syncthreads();
  }

  float* Cz = Cpart + (size_t)kz * BL * 128;
#pragma unroll
  for (int i = 0; i < 4; ++i) {
    const int row0 = by * 128 + wr * 64 + i * 16 + (lane >> 4) * 4;
#pragma unroll
    for (int j = 0; j < 4; ++j) {
      const int col = wc * 64 + j * 16 + (lane & 15);
      const f32x4 v = acc[i][j];
      float* p = Cz + (size_t)row0 * 128 + col;
#pragma unroll
      for (int r = 0; r < 4; ++r) p[(size_t)r * 128] = v[r];
    }
  }
}

__global__ __launch_bounds__(256) void reduce_xdbl(
    const float* __restrict__ Cpart, float* __restrict__ xdbl)
{
  const int i = blockIdx.x * 256 + threadIdx.x;   // over BL*24
  const int m = i / 24;
  const int g = i - m * 24;
  f32x4 s = {};
#pragma unroll
  for (int z = 0; z < G2_KSLICE; ++z)
    s += *reinterpret_cast<const f32x4*>(&Cpart[((size_t)z * BL + m) * 128 + g * 4]);
  *reinterpret_cast<f32x4*>(&xdbl[(size_t)m * NPROJ + g * 4]) = s;
}

// ---------------------------------------------------------------------------
// causal depthwise conv (width 4) + bias + SiLU -> bf16 u
// ---------------------------------------------------------------------------
__global__ __launch_bounds__(256) void conv_silu_k(
    const float* __restrict__ x, const float* __restrict__ cw,
    const float* __restrict__ cb, bf16* __restrict__ ubf)
{
  const int idx = blockIdx.x * 256 + threadIdx.x;
  const int d  = idx & (D_INNER - 1);
  const int bl = idx >> 11;
  const int l  = bl & (SEQLEN - 1);
  const float4 w = *reinterpret_cast<const float4*>(&cw[d * 4]);
  const float* xp = x + (size_t)bl * D_INNER + d;
  float acc = cb[d] + w.w * xp[0];
  if (l >= 1) acc += w.z * xp[-D_INNER];
  if (l >= 2) acc += w.y * xp[-2 * D_INNER];
  if (l >= 3) acc += w.x * xp[-3 * D_INNER];
  const float val = acc / (1.f + __expf(-acc));
  reinterpret_cast<unsigned short*>(ubf)[idx] = f2bf(val);
}

// ---------------------------------------------------------------------------
// delta = softplus( xdbl[:, :64] * dt_proj_w^T + b )
// ---------------------------------------------------------------------------
__device__ __forceinline__ float softplusf(float x) {
  return (x > 20.f) ? x : log1pf(__expf(x));
}

__global__ __launch_bounds__(256) void gemm3_delta(
    const float* __restrict__ xdbl, const float* __restrict__ Wdt,
    const float* __restrict__ bdt, float* __restrict__ delta)
{
  __shared__ __align__(16) float aT[64][132];
  __shared__ __align__(16) float bT[64][68];
  const int t = threadIdx.x;
  const int n0 = blockIdx.x * 64;
  const int m0 = blockIdx.y * 128;

  {
    const int r  = t & 127;
    const int k0 = (t >> 7) * 32;
    const float* src = xdbl + (size_t)(m0 + r) * NPROJ + k0;
#pragma unroll
    for (int p = 0; p < 8; ++p) {
      const float4 v = *reinterpret_cast<const float4*>(&src[p * 4]);
      aT[k0 + p * 4 + 0][r] = v.x;
      aT[k0 + p * 4 + 1][r] = v.y;
      aT[k0 + p * 4 + 2][r] = v.z;
      aT[k0 + p * 4 + 3][r] = v.w;
    }
  }
  {
    const int r  = t & 63;
    const int k0 = (t >> 6) * 16;
    const float* src = Wdt + (size_t)(n0 + r) * DT_RANK + k0;
#pragma unroll
    for (int p = 0; p < 4; ++p) {
      const float4 v = *reinterpret_cast<const float4*>(&src[p * 4]);
      bT[k0 + p * 4 + 0][r] = v.x;
      bT[k0 + p * 4 + 1][r] = v.y;
      bT[k0 + p * 4 + 2][r] = v.z;
      bT[k0 + p * 4 + 3][r] = v.w;
    }
  }
  __syncthreads();

  const int tx = t & 15;
  const int ty = t >> 4;
  f32x4 acc[8] = {};
#pragma unroll 4
  for (int kk = 0; kk < 64; ++kk) {
    const f32x4 a0 = *reinterpret_cast<const f32x4*>(&aT[kk][ty * 8]);
    const f32x4 a1 = *reinterpret_cast<const f32x4*>(&aT[kk][ty * 8 + 4]);
    const f32x4 b  = *reinterpret_cast<const f32x4*>(&bT[kk][tx * 4]);
    acc[0] += a0.x * b;  acc[1] += a0.y * b;
    acc[2] += a0.z * b;  acc[3] += a0.w * b;
    acc[4] += a1.x * b;  acc[5] += a1.y * b;
    acc[6] += a1.z * b;  acc[7] += a1.w * b;
  }

  const float4 bias = *reinterpret_cast<const float4*>(&bdt[n0 + tx * 4]);
#pragma unroll
  for (int i = 0; i < 8; ++i) {
    const int m = m0 + ty * 8 + i;
    float4 o;
    o.x = softplusf(acc[i].x + bias.x);
    o.y = softplusf(acc[i].y + bias.y);
    o.z = softplusf(acc[i].z + bias.z);
    o.w = softplusf(acc[i].w + bias.w);
    *reinterpret_cast<float4*>(&delta[(size_t)m * D_INNER + n0 + tx * 4]) = o;
  }
}

// ---------------------------------------------------------------------------
// Chunked selective scan, 3 phases — lane = d, 16 states in VGPRs.
// ---------------------------------------------------------------------------
__global__ __launch_bounds__(256) void scan_p1(
    const float* __restrict__ delta, const bf16* __restrict__ ubf,
    const float* __restrict__ xdbl, const float* __restrict__ A_log,
    float* __restrict__ P, float* __restrict__ S)
{
  const int t = threadIdx.x;
  const int d = ((blockIdx.x & 7) << 8) + t;
  const int c = (blockIdx.x >> 3) & (NCHUNK - 1);
  const int b = blockIdx.x >> 9;

  float a[D_STATE];
  {
    const f32x4* ap = reinterpret_cast<const f32x4*>(&A_log[d * D_STATE]);
#pragma unroll
    for (int q = 0; q < 4; ++q) {
      const f32x4 v = ap[q];
      a[4 * q + 0] = -__expf(v.x); a[4 * q + 1] = -__expf(v.y);
      a[4 * q + 2] = -__expf(v.z); a[4 * q + 3] = -__expf(v.w);
    }
  }

  float s[D_STATE] = {};
  float sumdl = 0.f;

  const size_t rbase = (size_t)(b * SEQLEN + c * CLEN);
  const float* dp = delta + rbase * D_INNER + d;
  const unsigned short* up = reinterpret_cast<const unsigned short*>(ubf) + rbase * D_INNER + d;
  const float* xr = xdbl  + rbase * NPROJ + DT_RANK;

  for (int l = 0; l < CLEN; ++l) {
    const float dl = dp[(size_t)l * D_INNER];
    const float ul = bf2f(up[(size_t)l * D_INNER]);
    const float du = dl * ul;
    sumdl += dl;
    const float* Brow = xr + (size_t)l * NPROJ;
#pragma unroll
    for (int n = 0; n < D_STATE; ++n)
      s[n] = s[n] * __expf(dl * a[n]) + du * Brow[n];
  }

  const size_t plane = (size_t)BATCH * NCHUNK * D_INNER;
  const size_t pbase = ((size_t)b * NCHUNK + c) * D_INNER + d;
#pragma unroll
  for (int n = 0; n < D_STATE; ++n) {
    P[n * plane + pbase] = __expf(sumdl * a[n]);
    S[n * plane + pbase] = s[n];
  }
}

__global__ __launch_bounds__(256) void scan_p2(
    const float* __restrict__ P, const float* __restrict__ S,
    float* __restrict__ init)
{
  const int gid = blockIdx.x * 256 + threadIdx.x;
  const int d  = gid & (D_INNER - 1);
  const int nb = gid >> 11;

  float carry = 0.f;
#pragma unroll 8
  for (int c = 0; c < NCHUNK; ++c) {
    const size_t o = ((size_t)nb * NCHUNK + c) * D_INNER + d;
    init[o] = carry;
    carry = carry * P[o] + S[o];
  }
}

__global__ __launch_bounds__(256) void scan_p3(
    const float* __restrict__ delta, const bf16* __restrict__ ubf,
    const float* __restrict__ z, const float* __restrict__ xdbl,
    const float* __restrict__ A_log, const float* __restrict__ Dvec,
    const float* __restrict__ init, bf16* __restrict__ y)
{
  const int t = threadIdx.x;
  const int d = ((blockIdx.x & 7) << 8) + t;
  const int c = (blockIdx.x >> 3) & (NCHUNK - 1);
  const int b = blockIdx.x >> 9;

  float a[D_STATE];
  {
    const f32x4* ap = reinterpret_cast<const f32x4*>(&A_log[d * D_STATE]);
#pragma unroll
    for (int q = 0; q < 4; ++q) {
      const f32x4 v = ap[q];
      a[4 * q + 0] = -__expf(v.x); a[4 * q + 1] = -__expf(v.y);
      a[4 * q + 2] = -__expf(v.z); a[4 * q + 3] = -__expf(v.w);
    }
  }
  const float Dd = Dvec[d];

  const size_t plane = (size_t)BATCH * NCHUNK * D_INNER;
  const size_t pbase = ((size_t)b * NCHUNK + c) * D_INNER + d;
  float s[D_STATE];
#pragma unroll
  for (int n = 0; n < D_STATE; ++n)
    s[n] = init[n * plane + pbase];

  const size_t rbase = (size_t)(b * SEQLEN + c * CLEN);
  const float* dp = delta + rbase * D_INNER + d;
  const unsigned short* up = reinterpret_cast<const unsigned short*>(ubf) + rbase * D_INNER + d;
  const float* zp = z     + rbase * D_INNER + d;
  const float* xr = xdbl  + rbase * NPROJ + DT_RANK;
  unsigned short* yp = reinterpret_cast<unsigned short*>(y) + rbase * D_INNER + d;

  for (int l = 0; l < CLEN; ++l) {
    const float dl = dp[(size_t)l * D_INNER];
    const float ul = bf2f(up[(size_t)l * D_INNER]);
    const float zl = zp[(size_t)l * D_INNER];
    const float du = dl * ul;
    const float* Brow = xr + (size_t)l * NPROJ;
    float y0 = 0.f, y1 = 0.f, y2 = 0.f, y3 = 0.f;
#pragma unroll
    for (int q = 0; q < 4; ++q) {
      float p0 = 0.f;
#pragma unroll
      for (int j = 0; j < 4; ++j) {
        const int n = q * 4 + j;
        s[n] = s[n] * __expf(dl * a[n]) + du * Brow[n];
        p0 += s[n] * Brow[D_STATE + n];
      }
      if (q == 0) y0 = p0; else if (q == 1) y1 = p0;
      else if (q == 2) y2 = p0; else y3 = p0;
    }
    const float yv = ((y0 + y1) + (y2 + y3) + Dd * ul) * (zl / (1.f + __expf(-zl)));
    yp[(size_t)l * D_INNER] = f2bf(yv);
  }
}

// ---------------------------------------------------------------------------
extern "C" void kernel_launch(void* const* d_in, const int* in_sizes, int n_in,
                              void* d_out, int out_size, void* d_ws, size_t ws_size,
                              hipStream_t stream)
{
  (void)in_sizes; (void)n_in; (void)out_size; (void)ws_size;
  const float* hidden    = (const float*)d_in[0];
  const float* in_projw  = (const float*)d_in[1];
  const float* conv_w    = (const float*)d_in[2];
  const float* conv_b    = (const float*)d_in[3];
  const float* x_projw   = (const float*)d_in[4];
  const float* dt_projw  = (const float*)d_in[5];
  const float* dt_projb  = (const float*)d_in[6];
  const float* A_log     = (const float*)d_in[7];
  const float* Dvec      = (const float*)d_in[8];
  const float* out_projw = (const float*)d_in[9];
  float* out = (float*)d_out;

  char* ws = (char*)d_ws;
  size_t off = 0;
  auto alloc = [&](size_t bytes) -> void* {
    void* p = ws + off;
    off += (bytes + 255) & ~(size_t)255;
    return p;
  };
  float* x    = (float*)alloc((size_t)BL * D_INNER * 4);
  float* zbuf = (float*)alloc((size_t)BL * D_INNER * 4);
  float* dbuf = (float*)alloc((size_t)BL * D_INNER * 4);
  float* xdbl = (float*)alloc((size_t)BL * NPROJ * 4);
  bf16* hbf   = (bf16*)alloc((size_t)BL * D_MODEL * 2);
  bf16* w1bf  = (bf16*)alloc((size_t)2 * D_INNER * D_MODEL * 2);
  bf16* w4bf  = (bf16*)alloc((size_t)D_MODEL * D_INNER * 2);
  float* Sbuf = (float*)alloc((size_t)D_STATE * BATCH * NCHUNK * D_INNER * 4);
  bf16* ubf   = (bf16*)alloc((size_t)BL * D_INNER * 2);
  bf16* wpad  = (bf16*)alloc((size_t)128 * D_INNER * 2);
  bf16* ybf   = (bf16*)x;       // x dead after conv; scan_p3 writes y here
  float* Cpart = (float*)hbf;   // hbf+w1bf dead after gemm1; exact fit
  float* Pbuf  = (float*)hbf;   // same region, reused after reduce
  float* init  = out;           // d_out dead until final GEMM overwrites it

  // merged casts (hidden, in_proj_w, out_proj_w, padded x_proj_w)
  cast_all<<<CAST_TOTAL / 256, 256, 0, stream>>>(
      hidden, in_projw, out_projw, x_projw, hbf, w1bf, w4bf, wpad);

  // in_proj: xz = hidden * in_proj_w^T -> x | z  (256^2 double-buffered)
  hipFuncSetAttribute(reinterpret_cast<const void*>(gemm1_256),
                      hipFuncAttributeMaxDynamicSharedMemorySize, 131072);
  gemm1_256<<<dim3((2 * D_INNER) / 256, BL / 256), 512, 131072, stream>>>(
      hbf, w1bf, x, zbuf, BL, 2 * D_INNER, D_MODEL, D_INNER);

  conv_silu_k<<<BL * D_INNER / 256, 256, 0, stream>>>(x, conv_w, conv_b, ubf);

  // x_proj: split-K MFMA + deterministic reduce (hbf/w1bf dead -> Cpart alias)
  gemm2_mfma<<<dim3(G2_KSLICE, BL / 128), 256, 0, stream>>>(ubf, wpad, Cpart);
  reduce_xdbl<<<BL * 24 / 256, 256, 0, stream>>>(Cpart, xdbl);

  gemm3_delta<<<dim3(D_INNER / 64, BL / 128), 256, 0, stream>>>(xdbl, dt_projw, dt_projb, dbuf);

  // chunked selective scan (lane-per-d layout); Pbuf reuses Cpart region
  const int nblk = BATCH * NCHUNK * (D_INNER / 256);     // 1024
  scan_p1<<<nblk, 256, 0, stream>>>(dbuf, ubf, xdbl, A_log, Pbuf, Sbuf);
  scan_p2<<<(BATCH * D_INNER * D_STATE) / 256, 256, 0, stream>>>(Pbuf, Sbuf, init);
  scan_p3<<<nblk, 256, 0, stream>>>(dbuf, ubf, zbuf, xdbl, A_log, Dvec, init, ybf);

  // out_proj: out = y_gated * out_proj_w^T  (dbuf 128x64, 512 blocks)
  hipFuncSetAttribute(reinterpret_cast<const void*>(gemm_out_128x64),
                      hipFuncAttributeMaxDynamicSharedMemorySize, 49152);
  gemm_out_128x64<<<dim3(D_MODEL / 64, BL / 128), 256, 49152, stream>>>(
      ybf, w4bf, out, BL, D_MODEL, D_INNER);
}

// Round 8
// 238.961 us; speedup vs baseline: 7.4841x; 1.0571x over previous
//
#include <hip/hip_runtime.h>
#include <hip/hip_bf16.h>
#include <cstdint>
#include <cstddef>

#define D_MODEL 1024
#define D_STATE 16
#define D_INNER 2048
#define DT_RANK 64
#define BATCH 2
#define SEQLEN 2048
#define BL (BATCH*SEQLEN)
#define NPROJ 96
#define NCHUNK 64
#define CLEN 32   // NCHUNK * CLEN == SEQLEN
#define G2_KSLICE 8
#define G2_KLEN (D_INNER / G2_KSLICE)   // 256

static_assert(NCHUNK * CLEN == SEQLEN, "chunking");
static_assert((size_t)D_STATE * BATCH * NCHUNK * D_INNER == (size_t)BL * D_MODEL,
              "init aliases d_out exactly");
static_assert((size_t)G2_KSLICE * BL * 128 * 4 ==
              (size_t)BL * D_MODEL * 2 + (size_t)2 * D_INNER * D_MODEL * 2,
              "Cpart alias fits exactly");

typedef __hip_bfloat16 bf16;
using f32x4 = __attribute__((ext_vector_type(4))) float;
using s16x8 = __attribute__((ext_vector_type(8))) short;

__device__ __forceinline__ unsigned short f2bf(float f) {
  union { float f; unsigned int u; } v; v.f = f;
  unsigned int r = v.u + 0x7fffu + ((v.u >> 16) & 1u);
  return (unsigned short)(r >> 16);
}

__device__ __forceinline__ float bf2f(unsigned short u) {
  return __uint_as_float(((unsigned int)u) << 16);
}

__device__ __forceinline__ void async16(const void* g, void* l) {
  __builtin_amdgcn_global_load_lds(
      (const __attribute__((address_space(1))) void*)g,
      (__attribute__((address_space(3))) void*)l,
      16, 0, 0);
}

// ---------------------------------------------------------------------------
// merged fp32->bf16 casts: hidden, in_proj_w, out_proj_w, x_proj_w (pad 128),
// dt_proj_w
// ---------------------------------------------------------------------------
__device__ __forceinline__ void cvt4(const float* __restrict__ in,
                                     bf16* __restrict__ out, int i) {
  const float4 v = *reinterpret_cast<const float4*>(&in[(size_t)i * 4]);
  ushort4 o;
  o.x = f2bf(v.x); o.y = f2bf(v.y); o.z = f2bf(v.z); o.w = f2bf(v.w);
  *reinterpret_cast<ushort4*>(&out[(size_t)i * 4]) = o;
}

#define CAST_NH  (BL * D_MODEL / 4)
#define CAST_NW1 (2 * D_INNER * D_MODEL / 4)
#define CAST_NW4 (D_MODEL * D_INNER / 4)
#define CAST_NWP (128 * D_INNER / 4)
#define CAST_NDT (D_INNER * DT_RANK / 4)
#define CAST_TOTAL (CAST_NH + CAST_NW1 + CAST_NW4 + CAST_NWP + CAST_NDT)
static_assert(CAST_TOTAL % 256 == 0, "cast grid");

__global__ __launch_bounds__(256) void cast_all(
    const float* __restrict__ hidden, const float* __restrict__ w1,
    const float* __restrict__ w4, const float* __restrict__ xpw,
    const float* __restrict__ wdt,
    bf16* __restrict__ hbf, bf16* __restrict__ w1bf,
    bf16* __restrict__ w4bf, bf16* __restrict__ wpad,
    bf16* __restrict__ wdtbf)
{
  const int i = blockIdx.x * 256 + threadIdx.x;
  if (i < CAST_NH) {
    cvt4(hidden, hbf, i);
  } else if (i < CAST_NH + CAST_NW1) {
    cvt4(w1, w1bf, i - CAST_NH);
  } else if (i < CAST_NH + CAST_NW1 + CAST_NW4) {
    cvt4(w4, w4bf, i - CAST_NH - CAST_NW1);
  } else if (i < CAST_NH + CAST_NW1 + CAST_NW4 + CAST_NWP) {
    const int j = i - CAST_NH - CAST_NW1 - CAST_NW4;   // < 65536
    const int n = j >> 9;          // padded row (0..127)
    const int k4 = j & 511;
    ushort4 o = {0, 0, 0, 0};
    if (n < NPROJ) {
      const float4 v = *reinterpret_cast<const float4*>(&xpw[(size_t)n * D_INNER + k4 * 4]);
      o.x = f2bf(v.x); o.y = f2bf(v.y); o.z = f2bf(v.z); o.w = f2bf(v.w);
    }
    *reinterpret_cast<ushort4*>(&wpad[(size_t)n * D_INNER + k4 * 4]) = o;
  } else {
    cvt4(wdt, wdtbf, i - CAST_NH - CAST_NW1 - CAST_NW4 - CAST_NWP);
  }
}

// ---------------------------------------------------------------------------
// in_proj GEMM: 256x256 tile, 8 waves, BK=64, double-buffered 128KB LDS,
// issue-early staging, XOR-swizzled LDS (verified r6).
// ---------------------------------------------------------------------------
__global__ __launch_bounds__(512, 2) void gemm1_256(
    const bf16* __restrict__ A, const bf16* __restrict__ B,
    float* __restrict__ C0, float* __restrict__ C1,
    int M, int N, int K, int N0)
{
  extern __shared__ char smem[];   // A: [2dbuf][2ksub][256r][64B] = 65536
                                   // B: same at +65536; total 131072
  const int tid  = threadIdx.x;
  const int lane = tid & 63;
  const int wid  = tid >> 6;       // 0..7
  const int wr   = wid >> 2;       // 0..1  (M half)
  const int wc   = wid & 3;        // 0..3  (N quarter)
  const int m0 = blockIdx.y * 256;
  const int n0 = blockIdx.x * 256;
  const int lrow = lane & 15;
  const int kg   = lane >> 4;      // 0..3 (16B k-group)
  const int sr4  = lane >> 2;      // staging row-within-16
  const int sg   = lane & 3;       // staging 16B unit
  const int NT = K >> 6;

  f32x4 acc[8][4] = {};

  auto stage = [&](int t, int db) {
    const int kb = t * 64;
#pragma unroll
    for (int j = 0; j < 4; ++j) {
      const int ia = wid * 4 + j;            // 0..31 (2 ksub x 16 row-blocks)
      const int s = ia >> 4;
      const int r = (ia & 15) * 16 + sr4;
      const int gs = sg ^ ((r >> 2) & 3);    // inverse-swizzled source col
      async16(A + (size_t)(m0 + r) * K + kb + s * 32 + gs * 8,
              smem + db * 32768 + ia * 1024);
      async16(B + (size_t)(n0 + r) * K + kb + s * 32 + gs * 8,
              smem + 65536 + db * 32768 + ia * 1024);
    }
  };

  auto compute = [&](int db) {
    const char* ab = smem + db * 32768;
    const char* bb = ab + 65536;
    s16x8 bfr[4][2];
#pragma unroll
    for (int nf = 0; nf < 4; ++nf) {
      const int r = wc * 64 + nf * 16 + lrow;
      const int gsw = kg ^ ((r >> 2) & 3);
#pragma unroll
      for (int s = 0; s < 2; ++s)
        bfr[nf][s] = *reinterpret_cast<const s16x8*>(bb + s * 16384 + r * 64 + gsw * 16);
    }
#pragma unroll
    for (int mf = 0; mf < 8; ++mf) {
      const int r = wr * 128 + mf * 16 + lrow;
      const int gsw = kg ^ ((r >> 2) & 3);
      const s16x8 a0 = *reinterpret_cast<const s16x8*>(ab + r * 64 + gsw * 16);
      const s16x8 a1 = *reinterpret_cast<const s16x8*>(ab + 16384 + r * 64 + gsw * 16);
#pragma unroll
      for (int nf = 0; nf < 4; ++nf) {
        acc[mf][nf] = __builtin_amdgcn_mfma_f32_16x16x32_bf16(a0, bfr[nf][0], acc[mf][nf], 0, 0, 0);
        acc[mf][nf] = __builtin_amdgcn_mfma_f32_16x16x32_bf16(a1, bfr[nf][1], acc[mf][nf], 0, 0, 0);
      }
    }
  };

  stage(0, 0);
  __syncthreads();
  for (int t = 0; t < NT; ++t) {
    const int db = t & 1;
    if (t + 1 < NT) stage(t + 1, db ^ 1);   // issue BEFORE compute (overlap)
    compute(db);
    __syncthreads();
  }

  const int N1 = N - N0;
  const bool inC0 = (n0 < N0);      // block-uniform (N0 % 256 == 0)
  float* Cb = inC0 ? C0 : C1;
  const int stride = inC0 ? N0 : N1;
  const int cb = inC0 ? n0 : (n0 - N0);
#pragma unroll
  for (int mf = 0; mf < 8; ++mf) {
    const int row0 = m0 + wr * 128 + mf * 16 + kg * 4;
#pragma unroll
    for (int nf = 0; nf < 4; ++nf) {
      const int col = cb + wc * 64 + nf * 16 + lrow;
      const f32x4 v = acc[mf][nf];
      float* p = Cb + (size_t)row0 * stride + col;
#pragma unroll
      for (int r = 0; r < 4; ++r) p[(size_t)r * stride] = v[r];
    }
  }
}

// ---------------------------------------------------------------------------
// out_proj GEMM: 128x64 tile, 4 waves, BK=64, double-buffered 48KB LDS,
// issue-early staging + XOR swizzle (verified r7).
// ---------------------------------------------------------------------------
__global__ __launch_bounds__(256, 2) void gemm_out_128x64(
    const bf16* __restrict__ A, const bf16* __restrict__ B,
    float* __restrict__ C, int M, int N, int K)
{
  extern __shared__ char smem[];   // A: [2db][2ks][128r][64B] = 32768
                                   // B: [2db][2ks][ 64r][64B] = 16384 at +32768
  const int tid  = threadIdx.x;
  const int lane = tid & 63;
  const int wid  = tid >> 6;       // 0..3
  const int wr   = wid >> 1;       // 0..1 (M half: 64 rows)
  const int wc   = wid & 1;        // 0..1 (N half: 32 cols)
  const int m0 = blockIdx.y * 128;
  const int n0 = blockIdx.x * 64;
  const int lrow = lane & 15;
  const int kg   = lane >> 4;      // 0..3
  const int sr4  = lane >> 2;      // 0..15
  const int sg   = lane & 3;       // 0..3
  const int NT = K >> 6;

  f32x4 acc[4][2] = {};

  auto stage = [&](int t, int db) {
    const int kb = t * 64;
#pragma unroll
    for (int j = 0; j < 4; ++j) {
      const int ia = wid * 4 + j;            // 0..15
      const int s = ia >> 3;
      const int r = (ia & 7) * 16 + sr4;
      const int gs = sg ^ ((r >> 2) & 3);
      async16(A + (size_t)(m0 + r) * K + kb + s * 32 + gs * 8,
              smem + db * 16384 + ia * 1024);
    }
#pragma unroll
    for (int j = 0; j < 2; ++j) {
      const int ib = wid * 2 + j;            // 0..7
      const int s = ib >> 2;
      const int r = (ib & 3) * 16 + sr4;
      const int gs = sg ^ ((r >> 2) & 3);
      async16(B + (size_t)(n0 + r) * K + kb + s * 32 + gs * 8,
              smem + 32768 + db * 8192 + ib * 1024);
    }
  };

  auto compute = [&](int db) {
    const char* ab = smem + db * 16384;
    const char* bb = smem + 32768 + db * 8192;
    s16x8 bfr[2][2];
#pragma unroll
    for (int nf = 0; nf < 2; ++nf) {
      const int r = wc * 32 + nf * 16 + lrow;
      const int gsw = kg ^ ((r >> 2) & 3);
      bfr[nf][0] = *reinterpret_cast<const s16x8*>(bb + r * 64 + gsw * 16);
      bfr[nf][1] = *reinterpret_cast<const s16x8*>(bb + 4096 + r * 64 + gsw * 16);
    }
#pragma unroll
    for (int mf = 0; mf < 4; ++mf) {
      const int r = wr * 64 + mf * 16 + lrow;
      const int gsw = kg ^ ((r >> 2) & 3);
      const s16x8 a0 = *reinterpret_cast<const s16x8*>(ab + r * 64 + gsw * 16);
      const s16x8 a1 = *reinterpret_cast<const s16x8*>(ab + 8192 + r * 64 + gsw * 16);
#pragma unroll
      for (int nf = 0; nf < 2; ++nf) {
        acc[mf][nf] = __builtin_amdgcn_mfma_f32_16x16x32_bf16(a0, bfr[nf][0], acc[mf][nf], 0, 0, 0);
        acc[mf][nf] = __builtin_amdgcn_mfma_f32_16x16x32_bf16(a1, bfr[nf][1], acc[mf][nf], 0, 0, 0);
      }
    }
  };

  stage(0, 0);
  __syncthreads();
  for (int t = 0; t < NT; ++t) {
    const int db = t & 1;
    if (t + 1 < NT) stage(t + 1, db ^ 1);
    compute(db);
    __syncthreads();
  }

#pragma unroll
  for (int mf = 0; mf < 4; ++mf) {
    const int row0 = m0 + wr * 64 + mf * 16 + kg * 4;
#pragma unroll
    for (int nf = 0; nf < 2; ++nf) {
      const int col = n0 + wc * 32 + nf * 16 + lrow;
      const f32x4 v = acc[mf][nf];
      float* p = C + (size_t)row0 * N + col;
#pragma unroll
      for (int r = 0; r < 4; ++r) p[(size_t)r * N] = v[r];
    }
  }
}

// ---------------------------------------------------------------------------
// gemm2: x_dbl partials = ubf (BLx2048) * wpad(128x2048)^T, split-K 8x256.
// ---------------------------------------------------------------------------
__global__ __launch_bounds__(256) void gemm2_mfma(
    const bf16* __restrict__ A, const bf16* __restrict__ B,
    float* __restrict__ Cpart)
{
  __shared__ __align__(16) bf16 As[128 * 32];
  __shared__ __align__(16) bf16 Bs[128 * 32];
  const int tid  = threadIdx.x;
  const int lane = tid & 63;
  const int wave = tid >> 6;
  const int wr = wave >> 1, wc = wave & 1;
  const int kz = blockIdx.x, by = blockIdx.y;

  const int srow = lane >> 2;
  const int scol = (lane & 3) * 8;
  const int c0 = wave * 2, c1 = wave * 2 + 1;
  const int kbase = kz * G2_KLEN;
  const bf16* gA0 = A + (size_t)(by * 128 + c0 * 16 + srow) * D_INNER + kbase + scol;
  const bf16* gA1 = A + (size_t)(by * 128 + c1 * 16 + srow) * D_INNER + kbase + scol;
  const bf16* gB0 = B + (size_t)(c0 * 16 + srow) * D_INNER + kbase + scol;
  const bf16* gB1 = B + (size_t)(c1 * 16 + srow) * D_INNER + kbase + scol;
  bf16* lA0 = &As[c0 * 512];
  bf16* lA1 = &As[c1 * 512];
  bf16* lB0 = &Bs[c0 * 512];
  bf16* lB1 = &Bs[c1 * 512];

  f32x4 acc[4][4] = {};
  const int lrow = lane & 15;
  const int lkb  = (lane >> 4) * 8;

  for (int ks = 0; ks < G2_KLEN; ks += 32) {
    async16(gA0 + ks, lA0);
    async16(gA1 + ks, lA1);
    async16(gB0 + ks, lB0);
    async16(gB1 + ks, lB1);
    __syncthreads();
    s16x8 af[4], bfr[4];
#pragma unroll
    for (int i = 0; i < 4; ++i) {
      af[i]  = *reinterpret_cast<const s16x8*>(&As[(wr * 64 + i * 16 + lrow) * 32 + lkb]);
      bfr[i] = *reinterpret_cast<const s16x8*>(&Bs[(wc * 64 + i * 16 + lrow) * 32 + lkb]);
    }
#pragma unroll
    for (int i = 0; i < 4; ++i)
#pragma unroll
      for (int j = 0; j < 4; ++j)
        acc[i][j] = __builtin_amdgcn_mfma_f32_16x16x32_bf16(af[i], bfr[j], acc[i][j], 0, 0, 0);
    __syncthreads();
  }

  float* Cz = Cpart + (size_t)kz * BL * 128;
#pragma unroll
  for (int i = 0; i < 4; ++i) {
    const int row0 = by * 128 + wr * 64 + i * 16 + (lane >> 4) * 4;
#pragma unroll
    for (int j = 0; j < 4; ++j) {
      const int col = wc * 64 + j * 16 + (lane & 15);
      const f32x4 v = acc[i][j];
      float* p = Cz + (size_t)row0 * 128 + col;
#pragma unroll
      for (int r = 0; r < 4; ++r) p[(size_t)r * 128] = v[r];
    }
  }
}

// xdbl reduce; also emits bf16 dt_r (cols 0..63) for the MFMA delta GEMM
__global__ __launch_bounds__(256) void reduce_xdbl(
    const float* __restrict__ Cpart, float* __restrict__ xdbl,
    bf16* __restrict__ dtrbf)
{
  const int i = blockIdx.x * 256 + threadIdx.x;   // over BL*24
  const int m = i / 24;
  const int g = i - m * 24;
  f32x4 s = {};
#pragma unroll
  for (int z = 0; z < G2_KSLICE; ++z)
    s += *reinterpret_cast<const f32x4*>(&Cpart[((size_t)z * BL + m) * 128 + g * 4]);
  *reinterpret_cast<f32x4*>(&xdbl[(size_t)m * NPROJ + g * 4]) = s;
  if (g < 16) {
    ushort4 o;
    o.x = f2bf(s[0]); o.y = f2bf(s[1]); o.z = f2bf(s[2]); o.w = f2bf(s[3]);
    *reinterpret_cast<ushort4*>(&dtrbf[(size_t)m * DT_RANK + g * 4]) = o;
  }
}

// ---------------------------------------------------------------------------
// causal depthwise conv (width 4) + bias + SiLU -> bf16 u
// ---------------------------------------------------------------------------
__global__ __launch_bounds__(256) void conv_silu_k(
    const float* __restrict__ x, const float* __restrict__ cw,
    const float* __restrict__ cb, bf16* __restrict__ ubf)
{
  const int idx = blockIdx.x * 256 + threadIdx.x;
  const int d  = idx & (D_INNER - 1);
  const int bl = idx >> 11;
  const int l  = bl & (SEQLEN - 1);
  const float4 w = *reinterpret_cast<const float4*>(&cw[d * 4]);
  const float* xp = x + (size_t)bl * D_INNER + d;
  float acc = cb[d] + w.w * xp[0];
  if (l >= 1) acc += w.z * xp[-D_INNER];
  if (l >= 2) acc += w.y * xp[-2 * D_INNER];
  if (l >= 3) acc += w.x * xp[-3 * D_INNER];
  const float val = acc / (1.f + __expf(-acc));
  reinterpret_cast<unsigned short*>(ubf)[idx] = f2bf(val);
}

// ---------------------------------------------------------------------------
// delta = softplus( dtr_bf (BLx64) * wdt_bf (2048x64)^T + b )  — MFMA (r8).
// K=64 single-stage (no loop), 128x128 tile, 4 waves 2x2, fused epilogue.
// (r7 failure: fp32 VALU version = 21 TF effective, 51us; this op is
//  write-bound ~7us as MFMA.)
// ---------------------------------------------------------------------------
__device__ __forceinline__ float softplusf(float x) {
  return (x > 20.f) ? x : log1pf(__expf(x));
}

__global__ __launch_bounds__(256) void gemm3_mfma(
    const bf16* __restrict__ A, const bf16* __restrict__ B,
    const float* __restrict__ bdt, float* __restrict__ delta)
{
  __shared__ __align__(16) char smem[32768];  // A: [2ks][128r][64B]; B same +16384
  const int tid  = threadIdx.x;
  const int lane = tid & 63;
  const int wid  = tid >> 6;       // 0..3
  const int wr   = wid >> 1;       // 0..1
  const int wc   = wid & 1;        // 0..1
  const int n0 = blockIdx.x * 128;
  const int m0 = blockIdx.y * 128;
  const int lrow = lane & 15;
  const int kg   = lane >> 4;
  const int sr4  = lane >> 2;
  const int sg   = lane & 3;

#pragma unroll
  for (int j = 0; j < 4; ++j) {
    const int ia = wid * 4 + j;            // 0..15
    const int s = ia >> 3;
    const int r = (ia & 7) * 16 + sr4;
    const int gs = sg ^ ((r >> 2) & 3);
    async16(A + (size_t)(m0 + r) * DT_RANK + s * 32 + gs * 8,
            smem + ia * 1024);
    async16(B + (size_t)(n0 + r) * DT_RANK + s * 32 + gs * 8,
            smem + 16384 + ia * 1024);
  }
  __syncthreads();

  f32x4 acc[4][4] = {};
  const char* ab = smem;
  const char* bb = smem + 16384;
  s16x8 bfr[4][2];
#pragma unroll
  for (int nf = 0; nf < 4; ++nf) {
    const int r = wc * 64 + nf * 16 + lrow;
    const int gsw = kg ^ ((r >> 2) & 3);
    bfr[nf][0] = *reinterpret_cast<const s16x8*>(bb + r * 64 + gsw * 16);
    bfr[nf][1] = *reinterpret_cast<const s16x8*>(bb + 8192 + r * 64 + gsw * 16);
  }
#pragma unroll
  for (int mf = 0; mf < 4; ++mf) {
    const int r = wr * 64 + mf * 16 + lrow;
    const int gsw = kg ^ ((r >> 2) & 3);
    const s16x8 a0 = *reinterpret_cast<const s16x8*>(ab + r * 64 + gsw * 16);
    const s16x8 a1 = *reinterpret_cast<const s16x8*>(ab + 8192 + r * 64 + gsw * 16);
#pragma unroll
    for (int nf = 0; nf < 4; ++nf) {
      acc[mf][nf] = __builtin_amdgcn_mfma_f32_16x16x32_bf16(a0, bfr[nf][0], acc[mf][nf], 0, 0, 0);
      acc[mf][nf] = __builtin_amdgcn_mfma_f32_16x16x32_bf16(a1, bfr[nf][1], acc[mf][nf], 0, 0, 0);
    }
  }

#pragma unroll
  for (int nf = 0; nf < 4; ++nf) {
    const int col = n0 + wc * 64 + nf * 16 + lrow;
    const float bias = bdt[col];
#pragma unroll
    for (int mf = 0; mf < 4; ++mf) {
      const int row0 = m0 + wr * 64 + mf * 16 + kg * 4;
      const f32x4 v = acc[mf][nf];
      float* p = delta + (size_t)row0 * D_INNER + col;
      p[0]                    = softplusf(v[0] + bias);
      p[D_INNER]              = softplusf(v[1] + bias);
      p[2 * (size_t)D_INNER]  = softplusf(v[2] + bias);
      p[3 * (size_t)D_INNER]  = softplusf(v[3] + bias);
    }
  }
}

// ---------------------------------------------------------------------------
// Chunked selective scan, 3 phases — lane = d, 16 states in VGPRs.
// ---------------------------------------------------------------------------
__global__ __launch_bounds__(256) void scan_p1(
    const float* __restrict__ delta, const bf16* __restrict__ ubf,
    const float* __restrict__ xdbl, const float* __restrict__ A_log,
    float* __restrict__ P, float* __restrict__ S)
{
  const int t = threadIdx.x;
  const int d = ((blockIdx.x & 7) << 8) + t;
  const int c = (blockIdx.x >> 3) & (NCHUNK - 1);
  const int b = blockIdx.x >> 9;

  float a[D_STATE];
  {
    const f32x4* ap = reinterpret_cast<const f32x4*>(&A_log[d * D_STATE]);
#pragma unroll
    for (int q = 0; q < 4; ++q) {
      const f32x4 v = ap[q];
      a[4 * q + 0] = -__expf(v.x); a[4 * q + 1] = -__expf(v.y);
      a[4 * q + 2] = -__expf(v.z); a[4 * q + 3] = -__expf(v.w);
    }
  }

  float s[D_STATE] = {};
  float sumdl = 0.f;

  const size_t rbase = (size_t)(b * SEQLEN + c * CLEN);
  const float* dp = delta + rbase * D_INNER + d;
  const unsigned short* up = reinterpret_cast<const unsigned short*>(ubf) + rbase * D_INNER + d;
  const float* xr = xdbl  + rbase * NPROJ + DT_RANK;

  for (int l = 0; l < CLEN; ++l) {
    const float dl = dp[(size_t)l * D_INNER];
    const float ul = bf2f(up[(size_t)l * D_INNER]);
    const float du = dl * ul;
    sumdl += dl;
    const float* Brow = xr + (size_t)l * NPROJ;
#pragma unroll
    for (int n = 0; n < D_STATE; ++n)
      s[n] = s[n] * __expf(dl * a[n]) + du * Brow[n];
  }

  const size_t plane = (size_t)BATCH * NCHUNK * D_INNER;
  const size_t pbase = ((size_t)b * NCHUNK + c) * D_INNER + d;
#pragma unroll
  for (int n = 0; n < D_STATE; ++n) {
    P[n * plane + pbase] = __expf(sumdl * a[n]);
    S[n * plane + pbase] = s[n];
  }
}

__global__ __launch_bounds__(256) void scan_p2(
    const float* __restrict__ P, const float* __restrict__ S,
    float* __restrict__ init)
{
  const int gid = blockIdx.x * 256 + threadIdx.x;
  const int d  = gid & (D_INNER - 1);
  const int nb = gid >> 11;

  float carry = 0.f;
#pragma unroll 8
  for (int c = 0; c < NCHUNK; ++c) {
    const size_t o = ((size_t)nb * NCHUNK + c) * D_INNER + d;
    init[o] = carry;
    carry = carry * P[o] + S[o];
  }
}

__global__ __launch_bounds__(256) void scan_p3(
    const float* __restrict__ delta, const bf16* __restrict__ ubf,
    const float* __restrict__ z, const float* __restrict__ xdbl,
    const float* __restrict__ A_log, const float* __restrict__ Dvec,
    const float* __restrict__ init, bf16* __restrict__ y)
{
  const int t = threadIdx.x;
  const int d = ((blockIdx.x & 7) << 8) + t;
  const int c = (blockIdx.x >> 3) & (NCHUNK - 1);
  const int b = blockIdx.x >> 9;

  float a[D_STATE];
  {
    const f32x4* ap = reinterpret_cast<const f32x4*>(&A_log[d * D_STATE]);
#pragma unroll
    for (int q = 0; q < 4; ++q) {
      const f32x4 v = ap[q];
      a[4 * q + 0] = -__expf(v.x); a[4 * q + 1] = -__expf(v.y);
      a[4 * q + 2] = -__expf(v.z); a[4 * q + 3] = -__expf(v.w);
    }
  }
  const float Dd = Dvec[d];

  const size_t plane = (size_t)BATCH * NCHUNK * D_INNER;
  const size_t pbase = ((size_t)b * NCHUNK + c) * D_INNER + d;
  float s[D_STATE];
#pragma unroll
  for (int n = 0; n < D_STATE; ++n)
    s[n] = init[n * plane + pbase];

  const size_t rbase = (size_t)(b * SEQLEN + c * CLEN);
  const float* dp = delta + rbase * D_INNER + d;
  const unsigned short* up = reinterpret_cast<const unsigned short*>(ubf) + rbase * D_INNER + d;
  const float* zp = z     + rbase * D_INNER + d;
  const float* xr = xdbl  + rbase * NPROJ + DT_RANK;
  unsigned short* yp = reinterpret_cast<unsigned short*>(y) + rbase * D_INNER + d;

  for (int l = 0; l < CLEN; ++l) {
    const float dl = dp[(size_t)l * D_INNER];
    const float ul = bf2f(up[(size_t)l * D_INNER]);
    const float zl = zp[(size_t)l * D_INNER];
    const float du = dl * ul;
    const float* Brow = xr + (size_t)l * NPROJ;
    float y0 = 0.f, y1 = 0.f, y2 = 0.f, y3 = 0.f;
#pragma unroll
    for (int q = 0; q < 4; ++q) {
      float p0 = 0.f;
#pragma unroll
      for (int j = 0; j < 4; ++j) {
        const int n = q * 4 + j;
        s[n] = s[n] * __expf(dl * a[n]) + du * Brow[n];
        p0 += s[n] * Brow[D_STATE + n];
      }
      if (q == 0) y0 = p0; else if (q == 1) y1 = p0;
      else if (q == 2) y2 = p0; else y3 = p0;
    }
    const float yv = ((y0 + y1) + (y2 + y3) + Dd * ul) * (zl / (1.f + __expf(-zl)));
    yp[(size_t)l * D_INNER] = f2bf(yv);
  }
}

// ---------------------------------------------------------------------------
extern "C" void kernel_launch(void* const* d_in, const int* in_sizes, int n_in,
                              void* d_out, int out_size, void* d_ws, size_t ws_size,
                              hipStream_t stream)
{
  (void)in_sizes; (void)n_in; (void)out_size; (void)ws_size;
  const float* hidden    = (const float*)d_in[0];
  const float* in_projw  = (const float*)d_in[1];
  const float* conv_w    = (const float*)d_in[2];
  const float* conv_b    = (const float*)d_in[3];
  const float* x_projw   = (const float*)d_in[4];
  const float* dt_projw  = (const float*)d_in[5];
  const float* dt_projb  = (const float*)d_in[6];
  const float* A_log     = (const float*)d_in[7];
  const float* Dvec      = (const float*)d_in[8];
  const float* out_projw = (const float*)d_in[9];
  float* out = (float*)d_out;

  char* ws = (char*)d_ws;
  size_t off = 0;
  auto alloc = [&](size_t bytes) -> void* {
    void* p = ws + off;
    off += (bytes + 255) & ~(size_t)255;
    return p;
  };
  float* x    = (float*)alloc((size_t)BL * D_INNER * 4);
  float* zbuf = (float*)alloc((size_t)BL * D_INNER * 4);
  float* dbuf = (float*)alloc((size_t)BL * D_INNER * 4);
  float* xdbl = (float*)alloc((size_t)BL * NPROJ * 4);
  bf16* hbf   = (bf16*)alloc((size_t)BL * D_MODEL * 2);
  bf16* w1bf  = (bf16*)alloc((size_t)2 * D_INNER * D_MODEL * 2);
  bf16* w4bf  = (bf16*)alloc((size_t)D_MODEL * D_INNER * 2);
  float* Sbuf = (float*)alloc((size_t)D_STATE * BATCH * NCHUNK * D_INNER * 4);
  bf16* ubf   = (bf16*)alloc((size_t)BL * D_INNER * 2);
  bf16* wpad  = (bf16*)alloc((size_t)128 * D_INNER * 2);
  bf16* wdtbf = (bf16*)alloc((size_t)D_INNER * DT_RANK * 2);
  bf16* dtrbf = (bf16*)alloc((size_t)BL * DT_RANK * 2);
  bf16* ybf   = (bf16*)x;       // x dead after conv; scan_p3 writes y here
  float* Cpart = (float*)hbf;   // hbf+w1bf dead after gemm1; exact fit
  float* Pbuf  = (float*)hbf;   // same region, reused after reduce
  float* init  = out;           // d_out dead until final GEMM overwrites it

  // merged casts
  cast_all<<<CAST_TOTAL / 256, 256, 0, stream>>>(
      hidden, in_projw, out_projw, x_projw, dt_projw,
      hbf, w1bf, w4bf, wpad, wdtbf);

  // in_proj: xz = hidden * in_proj_w^T -> x | z  (256^2 double-buffered)
  hipFuncSetAttribute(reinterpret_cast<const void*>(gemm1_256),
                      hipFuncAttributeMaxDynamicSharedMemorySize, 131072);
  gemm1_256<<<dim3((2 * D_INNER) / 256, BL / 256), 512, 131072, stream>>>(
      hbf, w1bf, x, zbuf, BL, 2 * D_INNER, D_MODEL, D_INNER);

  conv_silu_k<<<BL * D_INNER / 256, 256, 0, stream>>>(x, conv_w, conv_b, ubf);

  // x_proj: split-K MFMA + deterministic reduce (emits bf16 dt_r too)
  gemm2_mfma<<<dim3(G2_KSLICE, BL / 128), 256, 0, stream>>>(ubf, wpad, Cpart);
  reduce_xdbl<<<BL * 24 / 256, 256, 0, stream>>>(Cpart, xdbl, dtrbf);

  // delta: MFMA K=64 single-shot + fused bias/softplus
  gemm3_mfma<<<dim3(D_INNER / 128, BL / 128), 256, 0, stream>>>(
      dtrbf, wdtbf, dt_projb, dbuf);

  // chunked selective scan (lane-per-d layout); Pbuf reuses Cpart region
  const int nblk = BATCH * NCHUNK * (D_INNER / 256);     // 1024
  scan_p1<<<nblk, 256, 0, stream>>>(dbuf, ubf, xdbl, A_log, Pbuf, Sbuf);
  scan_p2<<<(BATCH * D_INNER * D_STATE) / 256, 256, 0, stream>>>(Pbuf, Sbuf, init);
  scan_p3<<<nblk, 256, 0, stream>>>(dbuf, ubf, zbuf, xdbl, A_log, Dvec, init, ybf);

  // out_proj: out = y_gated * out_proj_w^T  (dbuf 128x64, 512 blocks)
  hipFuncSetAttribute(reinterpret_cast<const void*>(gemm_out_128x64),
                      hipFuncAttributeMaxDynamicSharedMemorySize, 49152);
  gemm_out_128x64<<<dim3(D_MODEL / 64, BL / 128), 256, 49152, stream>>>(
      ybf, w4bf, out, BL, D_MODEL, D_INNER);
}

// Round 9
// 236.998 us; speedup vs baseline: 7.5461x; 1.0083x over previous
//
#include <hip/hip_runtime.h>
#include <hip/hip_bf16.h>
#include <cstdint>
#include <cstddef>

#define D_MODEL 1024
#define D_STATE 16
#define D_INNER 2048
#define DT_RANK 64
#define BATCH 2
#define SEQLEN 2048
#define BL (BATCH*SEQLEN)
#define NPROJ 96
#define NCHUNK 64
#define CLEN 32   // NCHUNK * CLEN == SEQLEN
#define G2_KSLICE 8
#define G2_KLEN (D_INNER / G2_KSLICE)   // 256

static_assert(NCHUNK * CLEN == SEQLEN, "chunking");
static_assert((size_t)D_STATE * BATCH * NCHUNK * D_INNER == (size_t)BL * D_MODEL,
              "init aliases d_out exactly");
static_assert((size_t)G2_KSLICE * BL * 128 * 4 ==
              (size_t)BL * D_MODEL * 2 + (size_t)2 * D_INNER * D_MODEL * 2,
              "Cpart alias fits exactly");

typedef __hip_bfloat16 bf16;
using f32x4 = __attribute__((ext_vector_type(4))) float;
using s16x8 = __attribute__((ext_vector_type(8))) short;

__device__ __forceinline__ unsigned short f2bf(float f) {
  union { float f; unsigned int u; } v; v.f = f;
  unsigned int r = v.u + 0x7fffu + ((v.u >> 16) & 1u);
  return (unsigned short)(r >> 16);
}

__device__ __forceinline__ float bf2f(unsigned short u) {
  return __uint_as_float(((unsigned int)u) << 16);
}

__device__ __forceinline__ void async16(const void* g, void* l) {
  __builtin_amdgcn_global_load_lds(
      (const __attribute__((address_space(1))) void*)g,
      (__attribute__((address_space(3))) void*)l,
      16, 0, 0);
}

// ---------------------------------------------------------------------------
// merged fp32->bf16 casts: hidden, in_proj_w, out_proj_w, x_proj_w (pad 128),
// dt_proj_w
// ---------------------------------------------------------------------------
__device__ __forceinline__ void cvt4(const float* __restrict__ in,
                                     bf16* __restrict__ out, int i) {
  const float4 v = *reinterpret_cast<const float4*>(&in[(size_t)i * 4]);
  ushort4 o;
  o.x = f2bf(v.x); o.y = f2bf(v.y); o.z = f2bf(v.z); o.w = f2bf(v.w);
  *reinterpret_cast<ushort4*>(&out[(size_t)i * 4]) = o;
}

#define CAST_NH  (BL * D_MODEL / 4)
#define CAST_NW1 (2 * D_INNER * D_MODEL / 4)
#define CAST_NW4 (D_MODEL * D_INNER / 4)
#define CAST_NWP (128 * D_INNER / 4)
#define CAST_NDT (D_INNER * DT_RANK / 4)
#define CAST_TOTAL (CAST_NH + CAST_NW1 + CAST_NW4 + CAST_NWP + CAST_NDT)
static_assert(CAST_TOTAL % 256 == 0, "cast grid");

__global__ __launch_bounds__(256) void cast_all(
    const float* __restrict__ hidden, const float* __restrict__ w1,
    const float* __restrict__ w4, const float* __restrict__ xpw,
    const float* __restrict__ wdt,
    bf16* __restrict__ hbf, bf16* __restrict__ w1bf,
    bf16* __restrict__ w4bf, bf16* __restrict__ wpad,
    bf16* __restrict__ wdtbf)
{
  const int i = blockIdx.x * 256 + threadIdx.x;
  if (i < CAST_NH) {
    cvt4(hidden, hbf, i);
  } else if (i < CAST_NH + CAST_NW1) {
    cvt4(w1, w1bf, i - CAST_NH);
  } else if (i < CAST_NH + CAST_NW1 + CAST_NW4) {
    cvt4(w4, w4bf, i - CAST_NH - CAST_NW1);
  } else if (i < CAST_NH + CAST_NW1 + CAST_NW4 + CAST_NWP) {
    const int j = i - CAST_NH - CAST_NW1 - CAST_NW4;   // < 65536
    const int n = j >> 9;          // padded row (0..127)
    const int k4 = j & 511;
    ushort4 o = {0, 0, 0, 0};
    if (n < NPROJ) {
      const float4 v = *reinterpret_cast<const float4*>(&xpw[(size_t)n * D_INNER + k4 * 4]);
      o.x = f2bf(v.x); o.y = f2bf(v.y); o.z = f2bf(v.z); o.w = f2bf(v.w);
    }
    *reinterpret_cast<ushort4*>(&wpad[(size_t)n * D_INNER + k4 * 4]) = o;
  } else {
    cvt4(wdt, wdtbf, i - CAST_NH - CAST_NW1 - CAST_NW4 - CAST_NWP);
  }
}

// ---------------------------------------------------------------------------
// in_proj GEMM: 256x256 tile, 8 waves, BK=64, double-buffered 128KB LDS,
// issue-early staging, XOR-swizzled LDS (verified r6).
// r9: epilogue emits bf16 directly (x|z split) — halves write traffic; x/z
// were only ever consumed as bf16 downstream.
// ---------------------------------------------------------------------------
__global__ __launch_bounds__(512, 2) void gemm1_256(
    const bf16* __restrict__ A, const bf16* __restrict__ B,
    bf16* __restrict__ X, bf16* __restrict__ Z,
    int M, int N, int K, int N0)
{
  extern __shared__ char smem[];   // A: [2dbuf][2ksub][256r][64B] = 65536
                                   // B: same at +65536; total 131072
  const int tid  = threadIdx.x;
  const int lane = tid & 63;
  const int wid  = tid >> 6;       // 0..7
  const int wr   = wid >> 2;       // 0..1  (M half)
  const int wc   = wid & 3;        // 0..3  (N quarter)
  const int m0 = blockIdx.y * 256;
  const int n0 = blockIdx.x * 256;
  const int lrow = lane & 15;
  const int kg   = lane >> 4;      // 0..3 (16B k-group)
  const int sr4  = lane >> 2;      // staging row-within-16
  const int sg   = lane & 3;       // staging 16B unit
  const int NT = K >> 6;

  f32x4 acc[8][4] = {};

  auto stage = [&](int t, int db) {
    const int kb = t * 64;
#pragma unroll
    for (int j = 0; j < 4; ++j) {
      const int ia = wid * 4 + j;            // 0..31 (2 ksub x 16 row-blocks)
      const int s = ia >> 4;
      const int r = (ia & 15) * 16 + sr4;
      const int gs = sg ^ ((r >> 2) & 3);    // inverse-swizzled source col
      async16(A + (size_t)(m0 + r) * K + kb + s * 32 + gs * 8,
              smem + db * 32768 + ia * 1024);
      async16(B + (size_t)(n0 + r) * K + kb + s * 32 + gs * 8,
              smem + 65536 + db * 32768 + ia * 1024);
    }
  };

  auto compute = [&](int db) {
    const char* ab = smem + db * 32768;
    const char* bb = ab + 65536;
    s16x8 bfr[4][2];
#pragma unroll
    for (int nf = 0; nf < 4; ++nf) {
      const int r = wc * 64 + nf * 16 + lrow;
      const int gsw = kg ^ ((r >> 2) & 3);
#pragma unroll
      for (int s = 0; s < 2; ++s)
        bfr[nf][s] = *reinterpret_cast<const s16x8*>(bb + s * 16384 + r * 64 + gsw * 16);
    }
#pragma unroll
    for (int mf = 0; mf < 8; ++mf) {
      const int r = wr * 128 + mf * 16 + lrow;
      const int gsw = kg ^ ((r >> 2) & 3);
      const s16x8 a0 = *reinterpret_cast<const s16x8*>(ab + r * 64 + gsw * 16);
      const s16x8 a1 = *reinterpret_cast<const s16x8*>(ab + 16384 + r * 64 + gsw * 16);
#pragma unroll
      for (int nf = 0; nf < 4; ++nf) {
        acc[mf][nf] = __builtin_amdgcn_mfma_f32_16x16x32_bf16(a0, bfr[nf][0], acc[mf][nf], 0, 0, 0);
        acc[mf][nf] = __builtin_amdgcn_mfma_f32_16x16x32_bf16(a1, bfr[nf][1], acc[mf][nf], 0, 0, 0);
      }
    }
  };

  stage(0, 0);
  __syncthreads();
  for (int t = 0; t < NT; ++t) {
    const int db = t & 1;
    if (t + 1 < NT) stage(t + 1, db ^ 1);   // issue BEFORE compute (overlap)
    compute(db);
    __syncthreads();
  }

  const int N1 = N - N0;
  const bool inC0 = (n0 < N0);      // block-uniform (N0 % 256 == 0)
  unsigned short* Cb = reinterpret_cast<unsigned short*>(inC0 ? X : Z);
  const int stride = inC0 ? N0 : N1;
  const int cb = inC0 ? n0 : (n0 - N0);
#pragma unroll
  for (int mf = 0; mf < 8; ++mf) {
    const int row0 = m0 + wr * 128 + mf * 16 + kg * 4;
#pragma unroll
    for (int nf = 0; nf < 4; ++nf) {
      const int col = cb + wc * 64 + nf * 16 + lrow;
      const f32x4 v = acc[mf][nf];
      unsigned short* p = Cb + (size_t)row0 * stride + col;
#pragma unroll
      for (int r = 0; r < 4; ++r) p[(size_t)r * stride] = f2bf(v[r]);
    }
  }
}

// ---------------------------------------------------------------------------
// out_proj GEMM: 128x64 tile, 4 waves, BK=64, double-buffered 48KB LDS,
// issue-early staging + XOR swizzle (verified r7).
// ---------------------------------------------------------------------------
__global__ __launch_bounds__(256, 2) void gemm_out_128x64(
    const bf16* __restrict__ A, const bf16* __restrict__ B,
    float* __restrict__ C, int M, int N, int K)
{
  extern __shared__ char smem[];   // A: [2db][2ks][128r][64B] = 32768
                                   // B: [2db][2ks][ 64r][64B] = 16384 at +32768
  const int tid  = threadIdx.x;
  const int lane = tid & 63;
  const int wid  = tid >> 6;       // 0..3
  const int wr   = wid >> 1;       // 0..1 (M half: 64 rows)
  const int wc   = wid & 1;        // 0..1 (N half: 32 cols)
  const int m0 = blockIdx.y * 128;
  const int n0 = blockIdx.x * 64;
  const int lrow = lane & 15;
  const int kg   = lane >> 4;      // 0..3
  const int sr4  = lane >> 2;      // 0..15
  const int sg   = lane & 3;       // 0..3
  const int NT = K >> 6;

  f32x4 acc[4][2] = {};

  auto stage = [&](int t, int db) {
    const int kb = t * 64;
#pragma unroll
    for (int j = 0; j < 4; ++j) {
      const int ia = wid * 4 + j;            // 0..15
      const int s = ia >> 3;
      const int r = (ia & 7) * 16 + sr4;
      const int gs = sg ^ ((r >> 2) & 3);
      async16(A + (size_t)(m0 + r) * K + kb + s * 32 + gs * 8,
              smem + db * 16384 + ia * 1024);
    }
#pragma unroll
    for (int j = 0; j < 2; ++j) {
      const int ib = wid * 2 + j;            // 0..7
      const int s = ib >> 2;
      const int r = (ib & 3) * 16 + sr4;
      const int gs = sg ^ ((r >> 2) & 3);
      async16(B + (size_t)(n0 + r) * K + kb + s * 32 + gs * 8,
              smem + 32768 + db * 8192 + ib * 1024);
    }
  };

  auto compute = [&](int db) {
    const char* ab = smem + db * 16384;
    const char* bb = smem + 32768 + db * 8192;
    s16x8 bfr[2][2];
#pragma unroll
    for (int nf = 0; nf < 2; ++nf) {
      const int r = wc * 32 + nf * 16 + lrow;
      const int gsw = kg ^ ((r >> 2) & 3);
      bfr[nf][0] = *reinterpret_cast<const s16x8*>(bb + r * 64 + gsw * 16);
      bfr[nf][1] = *reinterpret_cast<const s16x8*>(bb + 4096 + r * 64 + gsw * 16);
    }
#pragma unroll
    for (int mf = 0; mf < 4; ++mf) {
      const int r = wr * 64 + mf * 16 + lrow;
      const int gsw = kg ^ ((r >> 2) & 3);
      const s16x8 a0 = *reinterpret_cast<const s16x8*>(ab + r * 64 + gsw * 16);
      const s16x8 a1 = *reinterpret_cast<const s16x8*>(ab + 8192 + r * 64 + gsw * 16);
#pragma unroll
      for (int nf = 0; nf < 2; ++nf) {
        acc[mf][nf] = __builtin_amdgcn_mfma_f32_16x16x32_bf16(a0, bfr[nf][0], acc[mf][nf], 0, 0, 0);
        acc[mf][nf] = __builtin_amdgcn_mfma_f32_16x16x32_bf16(a1, bfr[nf][1], acc[mf][nf], 0, 0, 0);
      }
    }
  };

  stage(0, 0);
  __syncthreads();
  for (int t = 0; t < NT; ++t) {
    const int db = t & 1;
    if (t + 1 < NT) stage(t + 1, db ^ 1);
    compute(db);
    __syncthreads();
  }

#pragma unroll
  for (int mf = 0; mf < 4; ++mf) {
    const int row0 = m0 + wr * 64 + mf * 16 + kg * 4;
#pragma unroll
    for (int nf = 0; nf < 2; ++nf) {
      const int col = n0 + wc * 32 + nf * 16 + lrow;
      const f32x4 v = acc[mf][nf];
      float* p = C + (size_t)row0 * N + col;
#pragma unroll
      for (int r = 0; r < 4; ++r) p[(size_t)r * N] = v[r];
    }
  }
}

// ---------------------------------------------------------------------------
// gemm2: x_dbl partials = ubf (BLx2048) * wpad(128x2048)^T, split-K 8x256.
// ---------------------------------------------------------------------------
__global__ __launch_bounds__(256) void gemm2_mfma(
    const bf16* __restrict__ A, const bf16* __restrict__ B,
    float* __restrict__ Cpart)
{
  __shared__ __align__(16) bf16 As[128 * 32];
  __shared__ __align__(16) bf16 Bs[128 * 32];
  const int tid  = threadIdx.x;
  const int lane = tid & 63;
  const int wave = tid >> 6;
  const int wr = wave >> 1, wc = wave & 1;
  const int kz = blockIdx.x, by = blockIdx.y;

  const int srow = lane >> 2;
  const int scol = (lane & 3) * 8;
  const int c0 = wave * 2, c1 = wave * 2 + 1;
  const int kbase = kz * G2_KLEN;
  const bf16* gA0 = A + (size_t)(by * 128 + c0 * 16 + srow) * D_INNER + kbase + scol;
  const bf16* gA1 = A + (size_t)(by * 128 + c1 * 16 + srow) * D_INNER + kbase + scol;
  const bf16* gB0 = B + (size_t)(c0 * 16 + srow) * D_INNER + kbase + scol;
  const bf16* gB1 = B + (size_t)(c1 * 16 + srow) * D_INNER + kbase + scol;
  bf16* lA0 = &As[c0 * 512];
  bf16* lA1 = &As[c1 * 512];
  bf16* lB0 = &Bs[c0 * 512];
  bf16* lB1 = &Bs[c1 * 512];

  f32x4 acc[4][4] = {};
  const int lrow = lane & 15;
  const int lkb  = (lane >> 4) * 8;

  for (int ks = 0; ks < G2_KLEN; ks += 32) {
    async16(gA0 + ks, lA0);
    async16(gA1 + ks, lA1);
    async16(gB0 + ks, lB0);
    async16(gB1 + ks, lB1);
    __syncthreads();
    s16x8 af[4], bfr[4];
#pragma unroll
    for (int i = 0; i < 4; ++i) {
      af[i]  = *reinterpret_cast<const s16x8*>(&As[(wr * 64 + i * 16 + lrow) * 32 + lkb]);
      bfr[i] = *reinterpret_cast<const s16x8*>(&Bs[(wc * 64 + i * 16 + lrow) * 32 + lkb]);
    }
#pragma unroll
    for (int i = 0; i < 4; ++i)
#pragma unroll
      for (int j = 0; j < 4; ++j)
        acc[i][j] = __builtin_amdgcn_mfma_f32_16x16x32_bf16(af[i], bfr[j], acc[i][j], 0, 0, 0);
    __syncthreads();
  }

  float* Cz = Cpart + (size_t)kz * BL * 128;
#pragma unroll
  for (int i = 0; i < 4; ++i) {
    const int row0 = by * 128 + wr * 64 + i * 16 + (lane >> 4) * 4;
#pragma unroll
    for (int j = 0; j < 4; ++j) {
      const int col = wc * 64 + j * 16 + (lane & 15);
      const f32x4 v = acc[i][j];
      float* p = Cz + (size_t)row0 * 128 + col;
#pragma unroll
      for (int r = 0; r < 4; ++r) p[(size_t)r * 128] = v[r];
    }
  }
}

// xdbl reduce; also emits bf16 dt_r (cols 0..63) for the MFMA delta GEMM
__global__ __launch_bounds__(256) void reduce_xdbl(
    const float* __restrict__ Cpart, float* __restrict__ xdbl,
    bf16* __restrict__ dtrbf)
{
  const int i = blockIdx.x * 256 + threadIdx.x;   // over BL*24
  const int m = i / 24;
  const int g = i - m * 24;
  f32x4 s = {};
#pragma unroll
  for (int z = 0; z < G2_KSLICE; ++z)
    s += *reinterpret_cast<const f32x4*>(&Cpart[((size_t)z * BL + m) * 128 + g * 4]);
  *reinterpret_cast<f32x4*>(&xdbl[(size_t)m * NPROJ + g * 4]) = s;
  if (g < 16) {
    ushort4 o;
    o.x = f2bf(s[0]); o.y = f2bf(s[1]); o.z = f2bf(s[2]); o.w = f2bf(s[3]);
    *reinterpret_cast<ushort4*>(&dtrbf[(size_t)m * DT_RANK + g * 4]) = o;
  }
}

// ---------------------------------------------------------------------------
// causal depthwise conv (width 4) + bias + SiLU; bf16 in (r9), bf16 out
// ---------------------------------------------------------------------------
__global__ __launch_bounds__(256) void conv_silu_k(
    const bf16* __restrict__ xbf, const float* __restrict__ cw,
    const float* __restrict__ cb, bf16* __restrict__ ubf)
{
  const int idx = blockIdx.x * 256 + threadIdx.x;
  const int d  = idx & (D_INNER - 1);
  const int bl = idx >> 11;
  const int l  = bl & (SEQLEN - 1);
  const float4 w = *reinterpret_cast<const float4*>(&cw[d * 4]);
  const unsigned short* xp = reinterpret_cast<const unsigned short*>(xbf) + (size_t)bl * D_INNER + d;
  float acc = cb[d] + w.w * bf2f(xp[0]);
  if (l >= 1) acc += w.z * bf2f(xp[-D_INNER]);
  if (l >= 2) acc += w.y * bf2f(xp[-2 * D_INNER]);
  if (l >= 3) acc += w.x * bf2f(xp[-3 * D_INNER]);
  const float val = acc / (1.f + __expf(-acc));
  reinterpret_cast<unsigned short*>(ubf)[idx] = f2bf(val);
}

// ---------------------------------------------------------------------------
// delta = softplus( dtr_bf (BLx64) * wdt_bf (2048x64)^T + b )  — MFMA (r8).
// ---------------------------------------------------------------------------
__device__ __forceinline__ float softplusf(float x) {
  return (x > 20.f) ? x : log1pf(__expf(x));
}

__global__ __launch_bounds__(256) void gemm3_mfma(
    const bf16* __restrict__ A, const bf16* __restrict__ B,
    const float* __restrict__ bdt, float* __restrict__ delta)
{
  __shared__ __align__(16) char smem[32768];  // A: [2ks][128r][64B]; B same +16384
  const int tid  = threadIdx.x;
  const int lane = tid & 63;
  const int wid  = tid >> 6;       // 0..3
  const int wr   = wid >> 1;       // 0..1
  const int wc   = wid & 1;        // 0..1
  const int n0 = blockIdx.x * 128;
  const int m0 = blockIdx.y * 128;
  const int lrow = lane & 15;
  const int kg   = lane >> 4;
  const int sr4  = lane >> 2;
  const int sg   = lane & 3;

#pragma unroll
  for (int j = 0; j < 4; ++j) {
    const int ia = wid * 4 + j;            // 0..15
    const int s = ia >> 3;
    const int r = (ia & 7) * 16 + sr4;
    const int gs = sg ^ ((r >> 2) & 3);
    async16(A + (size_t)(m0 + r) * DT_RANK + s * 32 + gs * 8,
            smem + ia * 1024);
    async16(B + (size_t)(n0 + r) * DT_RANK + s * 32 + gs * 8,
            smem + 16384 + ia * 1024);
  }
  __syncthreads();

  f32x4 acc[4][4] = {};
  const char* ab = smem;
  const char* bb = smem + 16384;
  s16x8 bfr[4][2];
#pragma unroll
  for (int nf = 0; nf < 4; ++nf) {
    const int r = wc * 64 + nf * 16 + lrow;
    const int gsw = kg ^ ((r >> 2) & 3);
    bfr[nf][0] = *reinterpret_cast<const s16x8*>(bb + r * 64 + gsw * 16);
    bfr[nf][1] = *reinterpret_cast<const s16x8*>(bb + 8192 + r * 64 + gsw * 16);
  }
#pragma unroll
  for (int mf = 0; mf < 4; ++mf) {
    const int r = wr * 64 + mf * 16 + lrow;
    const int gsw = kg ^ ((r >> 2) & 3);
    const s16x8 a0 = *reinterpret_cast<const s16x8*>(ab + r * 64 + gsw * 16);
    const s16x8 a1 = *reinterpret_cast<const s16x8*>(ab + 8192 + r * 64 + gsw * 16);
#pragma unroll
    for (int nf = 0; nf < 4; ++nf) {
      acc[mf][nf] = __builtin_amdgcn_mfma_f32_16x16x32_bf16(a0, bfr[nf][0], acc[mf][nf], 0, 0, 0);
      acc[mf][nf] = __builtin_amdgcn_mfma_f32_16x16x32_bf16(a1, bfr[nf][1], acc[mf][nf], 0, 0, 0);
    }
  }

#pragma unroll
  for (int nf = 0; nf < 4; ++nf) {
    const int col = n0 + wc * 64 + nf * 16 + lrow;
    const float bias = bdt[col];
#pragma unroll
    for (int mf = 0; mf < 4; ++mf) {
      const int row0 = m0 + wr * 64 + mf * 16 + kg * 4;
      const f32x4 v = acc[mf][nf];
      float* p = delta + (size_t)row0 * D_INNER + col;
      p[0]                    = softplusf(v[0] + bias);
      p[D_INNER]              = softplusf(v[1] + bias);
      p[2 * (size_t)D_INNER]  = softplusf(v[2] + bias);
      p[3 * (size_t)D_INNER]  = softplusf(v[3] + bias);
    }
  }
}

// ---------------------------------------------------------------------------
// Chunked selective scan, 3 phases — lane = d, 16 states in VGPRs.
// ---------------------------------------------------------------------------
__global__ __launch_bounds__(256) void scan_p1(
    const float* __restrict__ delta, const bf16* __restrict__ ubf,
    const float* __restrict__ xdbl, const float* __restrict__ A_log,
    float* __restrict__ P, float* __restrict__ S)
{
  const int t = threadIdx.x;
  const int d = ((blockIdx.x & 7) << 8) + t;
  const int c = (blockIdx.x >> 3) & (NCHUNK - 1);
  const int b = blockIdx.x >> 9;

  float a[D_STATE];
  {
    const f32x4* ap = reinterpret_cast<const f32x4*>(&A_log[d * D_STATE]);
#pragma unroll
    for (int q = 0; q < 4; ++q) {
      const f32x4 v = ap[q];
      a[4 * q + 0] = -__expf(v.x); a[4 * q + 1] = -__expf(v.y);
      a[4 * q + 2] = -__expf(v.z); a[4 * q + 3] = -__expf(v.w);
    }
  }

  float s[D_STATE] = {};
  float sumdl = 0.f;

  const size_t rbase = (size_t)(b * SEQLEN + c * CLEN);
  const float* dp = delta + rbase * D_INNER + d;
  const unsigned short* up = reinterpret_cast<const unsigned short*>(ubf) + rbase * D_INNER + d;
  const float* xr = xdbl  + rbase * NPROJ + DT_RANK;

  for (int l = 0; l < CLEN; ++l) {
    const float dl = dp[(size_t)l * D_INNER];
    const float ul = bf2f(up[(size_t)l * D_INNER]);
    const float du = dl * ul;
    sumdl += dl;
    const float* Brow = xr + (size_t)l * NPROJ;
#pragma unroll
    for (int n = 0; n < D_STATE; ++n)
      s[n] = s[n] * __expf(dl * a[n]) + du * Brow[n];
  }

  const size_t plane = (size_t)BATCH * NCHUNK * D_INNER;
  const size_t pbase = ((size_t)b * NCHUNK + c) * D_INNER + d;
#pragma unroll
  for (int n = 0; n < D_STATE; ++n) {
    P[n * plane + pbase] = __expf(sumdl * a[n]);
    S[n * plane + pbase] = s[n];
  }
}

__global__ __launch_bounds__(256) void scan_p2(
    const float* __restrict__ P, const float* __restrict__ S,
    float* __restrict__ init)
{
  const int gid = blockIdx.x * 256 + threadIdx.x;
  const int d  = gid & (D_INNER - 1);
  const int nb = gid >> 11;

  float carry = 0.f;
#pragma unroll 8
  for (int c = 0; c < NCHUNK; ++c) {
    const size_t o = ((size_t)nb * NCHUNK + c) * D_INNER + d;
    init[o] = carry;
    carry = carry * P[o] + S[o];
  }
}

__global__ __launch_bounds__(256) void scan_p3(
    const float* __restrict__ delta, const bf16* __restrict__ ubf,
    const bf16* __restrict__ zbf, const float* __restrict__ xdbl,
    const float* __restrict__ A_log, const float* __restrict__ Dvec,
    const float* __restrict__ init, bf16* __restrict__ y)
{
  const int t = threadIdx.x;
  const int d = ((blockIdx.x & 7) << 8) + t;
  const int c = (blockIdx.x >> 3) & (NCHUNK - 1);
  const int b = blockIdx.x >> 9;

  float a[D_STATE];
  {
    const f32x4* ap = reinterpret_cast<const f32x4*>(&A_log[d * D_STATE]);
#pragma unroll
    for (int q = 0; q < 4; ++q) {
      const f32x4 v = ap[q];
      a[4 * q + 0] = -__expf(v.x); a[4 * q + 1] = -__expf(v.y);
      a[4 * q + 2] = -__expf(v.z); a[4 * q + 3] = -__expf(v.w);
    }
  }
  const float Dd = Dvec[d];

  const size_t plane = (size_t)BATCH * NCHUNK * D_INNER;
  const size_t pbase = ((size_t)b * NCHUNK + c) * D_INNER + d;
  float s[D_STATE];
#pragma unroll
  for (int n = 0; n < D_STATE; ++n)
    s[n] = init[n * plane + pbase];

  const size_t rbase = (size_t)(b * SEQLEN + c * CLEN);
  const float* dp = delta + rbase * D_INNER + d;
  const unsigned short* up = reinterpret_cast<const unsigned short*>(ubf) + rbase * D_INNER + d;
  const unsigned short* zp = reinterpret_cast<const unsigned short*>(zbf) + rbase * D_INNER + d;
  const float* xr = xdbl  + rbase * NPROJ + DT_RANK;
  unsigned short* yp = reinterpret_cast<unsigned short*>(y) + rbase * D_INNER + d;

  for (int l = 0; l < CLEN; ++l) {
    const float dl = dp[(size_t)l * D_INNER];
    const float ul = bf2f(up[(size_t)l * D_INNER]);
    const float zl = bf2f(zp[(size_t)l * D_INNER]);
    const float du = dl * ul;
    const float* Brow = xr + (size_t)l * NPROJ;
    float y0 = 0.f, y1 = 0.f, y2 = 0.f, y3 = 0.f;
#pragma unroll
    for (int q = 0; q < 4; ++q) {
      float p0 = 0.f;
#pragma unroll
      for (int j = 0; j < 4; ++j) {
        const int n = q * 4 + j;
        s[n] = s[n] * __expf(dl * a[n]) + du * Brow[n];
        p0 += s[n] * Brow[D_STATE + n];
      }
      if (q == 0) y0 = p0; else if (q == 1) y1 = p0;
      else if (q == 2) y2 = p0; else y3 = p0;
    }
    const float yv = ((y0 + y1) + (y2 + y3) + Dd * ul) * (zl / (1.f + __expf(-zl)));
    yp[(size_t)l * D_INNER] = f2bf(yv);
  }
}

// ---------------------------------------------------------------------------
extern "C" void kernel_launch(void* const* d_in, const int* in_sizes, int n_in,
                              void* d_out, int out_size, void* d_ws, size_t ws_size,
                              hipStream_t stream)
{
  (void)in_sizes; (void)n_in; (void)out_size; (void)ws_size;
  const float* hidden    = (const float*)d_in[0];
  const float* in_projw  = (const float*)d_in[1];
  const float* conv_w    = (const float*)d_in[2];
  const float* conv_b    = (const float*)d_in[3];
  const float* x_projw   = (const float*)d_in[4];
  const float* dt_projw  = (const float*)d_in[5];
  const float* dt_projb  = (const float*)d_in[6];
  const float* A_log     = (const float*)d_in[7];
  const float* Dvec      = (const float*)d_in[8];
  const float* out_projw = (const float*)d_in[9];
  float* out = (float*)d_out;

  char* ws = (char*)d_ws;
  size_t off = 0;
  auto alloc = [&](size_t bytes) -> void* {
    void* p = ws + off;
    off += (bytes + 255) & ~(size_t)255;
    return p;
  };
  bf16* xbf   = (bf16*)alloc((size_t)BL * D_INNER * 2);
  bf16* zbf   = (bf16*)alloc((size_t)BL * D_INNER * 2);
  float* dbuf = (float*)alloc((size_t)BL * D_INNER * 4);
  float* xdbl = (float*)alloc((size_t)BL * NPROJ * 4);
  bf16* hbf   = (bf16*)alloc((size_t)BL * D_MODEL * 2);
  bf16* w1bf  = (bf16*)alloc((size_t)2 * D_INNER * D_MODEL * 2);
  bf16* w4bf  = (bf16*)alloc((size_t)D_MODEL * D_INNER * 2);
  float* Sbuf = (float*)alloc((size_t)D_STATE * BATCH * NCHUNK * D_INNER * 4);
  bf16* ubf   = (bf16*)alloc((size_t)BL * D_INNER * 2);
  bf16* wpad  = (bf16*)alloc((size_t)128 * D_INNER * 2);
  bf16* wdtbf = (bf16*)alloc((size_t)D_INNER * DT_RANK * 2);
  bf16* dtrbf = (bf16*)alloc((size_t)BL * DT_RANK * 2);
  bf16* ybf   = xbf;            // xbf dead after conv; scan_p3 writes y here
  float* Cpart = (float*)hbf;   // hbf+w1bf dead after gemm1; exact fit
  float* Pbuf  = (float*)hbf;   // same region, reused after reduce
  float* init  = out;           // d_out dead until final GEMM overwrites it

  // merged casts
  cast_all<<<CAST_TOTAL / 256, 256, 0, stream>>>(
      hidden, in_projw, out_projw, x_projw, dt_projw,
      hbf, w1bf, w4bf, wpad, wdtbf);

  // in_proj: xz = hidden * in_proj_w^T -> bf16 x | z  (256^2 double-buffered)
  hipFuncSetAttribute(reinterpret_cast<const void*>(gemm1_256),
                      hipFuncAttributeMaxDynamicSharedMemorySize, 131072);
  gemm1_256<<<dim3((2 * D_INNER) / 256, BL / 256), 512, 131072, stream>>>(
      hbf, w1bf, xbf, zbf, BL, 2 * D_INNER, D_MODEL, D_INNER);

  conv_silu_k<<<BL * D_INNER / 256, 256, 0, stream>>>(xbf, conv_w, conv_b, ubf);

  // x_proj: split-K MFMA + deterministic reduce (emits bf16 dt_r too)
  gemm2_mfma<<<dim3(G2_KSLICE, BL / 128), 256, 0, stream>>>(ubf, wpad, Cpart);
  reduce_xdbl<<<BL * 24 / 256, 256, 0, stream>>>(Cpart, xdbl, dtrbf);

  // delta: MFMA K=64 single-shot + fused bias/softplus
  gemm3_mfma<<<dim3(D_INNER / 128, BL / 128), 256, 0, stream>>>(
      dtrbf, wdtbf, dt_projb, dbuf);

  // chunked selective scan (lane-per-d layout); Pbuf reuses Cpart region
  const int nblk = BATCH * NCHUNK * (D_INNER / 256);     // 1024
  scan_p1<<<nblk, 256, 0, stream>>>(dbuf, ubf, xdbl, A_log, Pbuf, Sbuf);
  scan_p2<<<(BATCH * D_INNER * D_STATE) / 256, 256, 0, stream>>>(Pbuf, Sbuf, init);
  scan_p3<<<nblk, 256, 0, stream>>>(dbuf, ubf, zbf, xdbl, A_log, Dvec, init, ybf);

  // out_proj: out = y_gated * out_proj_w^T  (dbuf 128x64, 512 blocks)
  hipFuncSetAttribute(reinterpret_cast<const void*>(gemm_out_128x64),
                      hipFuncAttributeMaxDynamicSharedMemorySize, 49152);
  gemm_out_128x64<<<dim3(D_MODEL / 64, BL / 128), 256, 49152, stream>>>(
      ybf, w4bf, out, BL, D_MODEL, D_INNER);
}